// Round 1
// baseline (8104.983 us; speedup 1.0000x reference)
//
#include <hip/hip_runtime.h>
#include <math.h>

// ---------------- constants ----------------
#define B_   64
#define S_   256
#define D_   256
#define H_   8
#define DH_  32
#define FF_  1024
#define MEM_ 200000
#define ROWS_ (B_ * S_)   // 16384

// ---------------- helpers ----------------
__device__ __forceinline__ float blockReduceSum256(float v, float* sh) {
  #pragma unroll
  for (int o = 32; o; o >>= 1) v += __shfl_down(v, o);
  int lane = threadIdx.x & 63, w = threadIdx.x >> 6;
  __syncthreads();
  if (lane == 0) sh[w] = v;
  __syncthreads();
  return sh[0] + sh[1] + sh[2] + sh[3];
}

// ---------------- embedding + positional encoding ----------------
__global__ __launch_bounds__(256) void embed_kernel(const int* __restrict__ ids,
                                                    const float* __restrict__ emb,
                                                    float* __restrict__ x) {
  int row = blockIdx.x;            // 0..16383
  int d = threadIdx.x;             // 0..255
  int s = row & (S_ - 1);
  int tok = ids[row];
  int d2 = d & ~1;
  float div = expf((float)d2 * (-9.210340371976184f / 256.0f)); // -ln(10000)/256
  float ang = (float)s * div;
  float pe = (d & 1) ? cosf(ang) : sinf(ang);
  x[(size_t)row * D_ + d] = emb[(size_t)tok * D_ + d] * 16.0f + pe;
}

// ---------------- generic fp32 GEMM: C = act(A[M,K] @ W[K,N] + bias[N]) ----------------
// act: 0 = none, 1 = exact gelu
__global__ __launch_bounds__(256) void gemm_kernel(const float* __restrict__ A,
                                                   const float* __restrict__ W,
                                                   const float* __restrict__ bias,
                                                   float* __restrict__ C,
                                                   int M, int N, int K, int act) {
  __shared__ float As[16][64];
  __shared__ float Bs[16][64];
  int tid = threadIdx.x;
  int tx = tid & 15, ty = tid >> 4;
  int m0 = blockIdx.y * 64, n0 = blockIdx.x * 64;
  float c[4][4] = {};
  for (int k0 = 0; k0 < K; k0 += 16) {
    {
      int m = tid >> 2, kk4 = (tid & 3) << 2;
      const float4 av = *reinterpret_cast<const float4*>(A + (size_t)(m0 + m) * K + k0 + kk4);
      As[kk4 + 0][m] = av.x; As[kk4 + 1][m] = av.y; As[kk4 + 2][m] = av.z; As[kk4 + 3][m] = av.w;
    }
    {
      int kk = tid >> 4, n4 = (tid & 15) << 2;
      *reinterpret_cast<float4*>(&Bs[kk][n4]) =
          *reinterpret_cast<const float4*>(W + (size_t)(k0 + kk) * N + n0 + n4);
    }
    __syncthreads();
    #pragma unroll
    for (int kk = 0; kk < 16; ++kk) {
      float a[4], bb[4];
      #pragma unroll
      for (int i = 0; i < 4; ++i) a[i] = As[kk][ty * 4 + i];
      #pragma unroll
      for (int j = 0; j < 4; ++j) bb[j] = Bs[kk][tx * 4 + j];
      #pragma unroll
      for (int i = 0; i < 4; ++i)
        #pragma unroll
        for (int j = 0; j < 4; ++j) c[i][j] += a[i] * bb[j];
    }
    __syncthreads();
  }
  #pragma unroll
  for (int i = 0; i < 4; ++i) {
    int row = m0 + ty * 4 + i;
    #pragma unroll
    for (int j = 0; j < 4; ++j) {
      int col = n0 + tx * 4 + j;
      float v = c[i][j] + bias[col];
      if (act == 1) v = 0.5f * v * (1.0f + erff(v * 0.7071067811865476f));
      C[(size_t)row * N + col] = v;
    }
  }
}

// ---------------- fused attention (flash-style, fp32) ----------------
__global__ __launch_bounds__(256) void attn_kernel(const float* __restrict__ qkv,
                                                   float* __restrict__ ctx) {
  __shared__ float Ks[S_][DH_];
  __shared__ float Vs[S_][DH_];
  int bh = blockIdx.x;
  int b = bh >> 3, h = bh & 7;
  int t = threadIdx.x;
  const float* base = qkv + (size_t)(b * S_) * 768;
  for (int idx = t; idx < S_ * DH_; idx += 256) {
    int s = idx >> 5, i = idx & 31;
    Ks[s][i] = base[(size_t)s * 768 + 256 + h * 32 + i];
    Vs[s][i] = base[(size_t)s * 768 + 512 + h * 32 + i];
  }
  float q[DH_];
  {
    const float* qp = base + (size_t)t * 768 + h * 32;
    #pragma unroll
    for (int i = 0; i < DH_; ++i) q[i] = qp[i];
  }
  __syncthreads();
  float m = -1e30f, l = 0.0f, acc[DH_];
  #pragma unroll
  for (int i = 0; i < DH_; ++i) acc[i] = 0.0f;
  for (int k = 0; k < S_; ++k) {
    float sc = 0.0f;
    #pragma unroll
    for (int i = 0; i < DH_; ++i) sc += q[i] * Ks[k][i];
    sc /= 5.656854249492381f;  // sqrt(32)
    float mn = fmaxf(m, sc);
    float scale = expf(m - mn);
    float p = expf(sc - mn);
    l = l * scale + p;
    #pragma unroll
    for (int i = 0; i < DH_; ++i) acc[i] = acc[i] * scale + p * Vs[k][i];
    m = mn;
  }
  float inv = 1.0f / l;
  float* cp = ctx + (size_t)(b * S_ + t) * D_ + h * 32;
  #pragma unroll
  for (int i = 0; i < DH_; ++i) cp[i] = acc[i] * inv;
}

// ---------------- residual add + layernorm (y may be null) ----------------
__global__ __launch_bounds__(256) void addln_kernel(const float* __restrict__ x,
                                                    const float* __restrict__ y,
                                                    const float* __restrict__ gam,
                                                    const float* __restrict__ bet,
                                                    float* __restrict__ out) {
  __shared__ float sh[8];
  int row = blockIdx.x, d = threadIdx.x;
  float v = x[(size_t)row * D_ + d];
  if (y) v += y[(size_t)row * D_ + d];
  float mean = blockReduceSum256(v, sh) * (1.0f / D_);
  float diff = v - mean;
  float var = blockReduceSum256(diff * diff, sh) * (1.0f / D_);
  out[(size_t)row * D_ + d] = diff * rsqrtf(var + 1e-5f) * gam[d] + bet[d];
}

// ---------------- masked mean pool ----------------
__global__ __launch_bounds__(256) void pooled_kernel(const float* __restrict__ hidden,
                                                     const float* __restrict__ mask,
                                                     float* __restrict__ pooled) {
  int b = blockIdx.x, d = threadIdx.x;
  float s = 0.0f, msum = 0.0f;
  for (int t = 0; t < S_; ++t) {
    float mk = mask[b * S_ + t];
    s += hidden[(size_t)(b * S_ + t) * D_ + d] * mk;
    msum += mk;
  }
  pooled[b * D_ + d] = s / (msum + 1e-8f);
}

// ---------------- normalize pooled queries ----------------
__global__ __launch_bounds__(256) void qnorm_kernel(const float* __restrict__ pooled,
                                                    float* __restrict__ qn) {
  __shared__ float sh[8];
  int b = blockIdx.x, d = threadIdx.x;
  float v = pooled[b * D_ + d];
  float ss = blockReduceSum256(v * v, sh);
  qn[b * D_ + d] = v / fmaxf(sqrtf(ss), 1e-8f);
}

// ---------------- per-key inverse norms ----------------
__global__ __launch_bounds__(64) void invnorm_kernel(const float* __restrict__ keys,
                                                     float* __restrict__ invn) {
  int row = blockIdx.x, t = threadIdx.x;  // 64 threads
  float4 v = *reinterpret_cast<const float4*>(keys + (size_t)row * D_ + t * 4);
  float ss = v.x * v.x + v.y * v.y + v.z * v.z + v.w * v.w;
  #pragma unroll
  for (int o = 32; o; o >>= 1) ss += __shfl_down(ss, o);
  if (t == 0) invn[row] = 1.0f / fmaxf(sqrtf(ss), 1e-8f);
}

// ---------------- sims[64, MEM] = qn @ (keys/|keys|)^T ----------------
__global__ __launch_bounds__(256) void sims_kernel(const float* __restrict__ qn,
                                                   const float* __restrict__ keys,
                                                   const float* __restrict__ invn,
                                                   float* __restrict__ sims) {
  __shared__ float As[16][64];
  __shared__ float Bs[16][64];
  int tid = threadIdx.x;
  int tx = tid & 15, ty = tid >> 4;
  int n0 = blockIdx.x * 64;
  float c[4][4] = {};
  for (int k0 = 0; k0 < D_; k0 += 16) {
    {
      int m = tid >> 2, kk4 = (tid & 3) << 2;
      const float4 av = *reinterpret_cast<const float4*>(qn + (size_t)m * D_ + k0 + kk4);
      As[kk4 + 0][m] = av.x; As[kk4 + 1][m] = av.y; As[kk4 + 2][m] = av.z; As[kk4 + 3][m] = av.w;
    }
    {
      int n = tid & 63, kk4 = (tid >> 6) << 2;
      const float4 bv = *reinterpret_cast<const float4*>(keys + (size_t)(n0 + n) * D_ + k0 + kk4);
      Bs[kk4 + 0][n] = bv.x; Bs[kk4 + 1][n] = bv.y; Bs[kk4 + 2][n] = bv.z; Bs[kk4 + 3][n] = bv.w;
    }
    __syncthreads();
    #pragma unroll
    for (int kk = 0; kk < 16; ++kk) {
      float a[4], bb[4];
      #pragma unroll
      for (int i = 0; i < 4; ++i) a[i] = As[kk][ty * 4 + i];
      #pragma unroll
      for (int j = 0; j < 4; ++j) bb[j] = Bs[kk][tx * 4 + j];
      #pragma unroll
      for (int i = 0; i < 4; ++i)
        #pragma unroll
        for (int j = 0; j < 4; ++j) c[i][j] += a[i] * bb[j];
    }
    __syncthreads();
  }
  #pragma unroll
  for (int i = 0; i < 4; ++i) {
    int q = ty * 4 + i;
    #pragma unroll
    for (int j = 0; j < 4; ++j) {
      int col = n0 + tx * 4 + j;
      sims[(size_t)q * MEM_ + col] = c[i][j] * invn[col];
    }
  }
}

// ---------------- iterative top-k (k extractions of argmax; ties -> lower index) ----------------
__global__ __launch_bounds__(256) void topk_kernel(float* __restrict__ sims,
                                                   const int* __restrict__ topk,
                                                   float* __restrict__ topv,
                                                   int* __restrict__ topi) {
  __shared__ float sv[256];
  __shared__ int si[256];
  int b = blockIdx.x, t = threadIdx.x;
  int k = *topk; if (k > 64) k = 64;
  float* row = sims + (size_t)b * MEM_;
  for (int iter = 0; iter < k; ++iter) {
    float bv = -1e30f; int bi = 2147483647;
    for (int i = t; i < MEM_; i += 256) {
      float v = row[i];
      if (v > bv) { bv = v; bi = i; }   // first (lowest) index kept on ties
    }
    sv[t] = bv; si[t] = bi;
    __syncthreads();
    for (int off = 128; off; off >>= 1) {
      if (t < off) {
        if (sv[t + off] > sv[t] || (sv[t + off] == sv[t] && si[t + off] < si[t])) {
          sv[t] = sv[t + off]; si[t] = si[t + off];
        }
      }
      __syncthreads();
    }
    if (t == 0) {
      topv[b * 64 + iter] = sv[0];
      topi[b * 64 + iter] = si[0];
      row[si[0]] = -1e30f;
    }
    __syncthreads();
  }
}

// ---------------- weighted aggregate of retrieved values ----------------
__global__ __launch_bounds__(256) void retrieve_kernel(const float* __restrict__ topv,
                                                       const int* __restrict__ topi,
                                                       const int* __restrict__ topk,
                                                       const float* __restrict__ vals,
                                                       const float* __restrict__ conf,
                                                       float* __restrict__ retr) {
  int b = blockIdx.x, d = threadIdx.x;
  int k = *topk; if (k > 64) k = 64;
  float acc = 0.0f, wsum = 0.0f;
  for (int i = 0; i < k; ++i) {
    int idx = topi[b * 64 + i];
    float w = fmaxf(conf[idx], 1e-4f) * topv[b * 64 + i];
    wsum += w;
    acc += w * vals[(size_t)idx * D_ + d];
  }
  retr[b * D_ + d] = acc / (wsum + 1e-8f);
}

// ---------------- gate MLP + fuse + classifier ----------------
__global__ __launch_bounds__(256) void head_kernel(const float* __restrict__ pooled,
                                                   const float* __restrict__ retr,
                                                   const float* __restrict__ gw1,
                                                   const float* __restrict__ gb1,
                                                   const float* __restrict__ gw2,
                                                   const float* __restrict__ gb2,
                                                   const float* __restrict__ cw,
                                                   const float* __restrict__ cb,
                                                   float* __restrict__ out) {
  __shared__ float pl[D_], hh[D_], fu[D_], sh[8];
  int b = blockIdx.x, d = threadIdx.x;
  pl[d] = pooled[b * D_ + d];
  __syncthreads();
  float a = gb1[d];
  for (int e = 0; e < D_; ++e) a += pl[e] * gw1[e * D_ + d];
  hh[d] = fmaxf(a, 0.0f);
  float gsum = blockReduceSum256(hh[d] * gw2[d], sh);
  float g = 1.0f / (1.0f + expf(-(gsum + gb2[0])));
  fu[d] = g * retr[b * D_ + d] + (1.0f - g) * pl[d];
  __syncthreads();
  if (d < 16) {
    float o = cb[d];
    for (int e = 0; e < D_; ++e) o += fu[e] * cw[e * 16 + d];
    out[b * 16 + d] = o;
  }
}

// ---------------- launcher ----------------
extern "C" void kernel_launch(void* const* d_in, const int* in_sizes, int n_in,
                              void* d_out, int out_size, void* d_ws, size_t ws_size,
                              hipStream_t stream) {
  const int*   ids   = (const int*)d_in[0];
  const float* mask  = (const float*)d_in[1];
  const int*   topk  = (const int*)d_in[2];
  const float* emb   = (const float*)d_in[3];
  const float* qkv_w = (const float*)d_in[4];
  const float* qkv_b = (const float*)d_in[5];
  const float* out_w = (const float*)d_in[6];
  const float* out_b = (const float*)d_in[7];
  const float* ln1_s = (const float*)d_in[8];
  const float* ln1_b = (const float*)d_in[9];
  const float* ff_w1 = (const float*)d_in[10];
  const float* ff_b1 = (const float*)d_in[11];
  const float* ff_w2 = (const float*)d_in[12];
  const float* ff_b2 = (const float*)d_in[13];
  const float* ln2_s = (const float*)d_in[14];
  const float* ln2_b = (const float*)d_in[15];
  const float* lnf_s = (const float*)d_in[16];
  const float* lnf_b = (const float*)d_in[17];
  const float* gw1   = (const float*)d_in[18];
  const float* gb1   = (const float*)d_in[19];
  const float* gw2   = (const float*)d_in[20];
  const float* gb2   = (const float*)d_in[21];
  const float* cw    = (const float*)d_in[22];
  const float* cb    = (const float*)d_in[23];
  const float* mkeys = (const float*)d_in[24];
  const float* mvals = (const float*)d_in[25];
  const float* mconf = (const float*)d_in[26];
  float* out = (float*)d_out;

  float* ws   = (float*)d_ws;
  float* X    = ws;                   // 16384*256           = 4,194,304 f
  float* Y    = X + 4194304;          // 4,194,304 f
  float* CTX  = Y + 4194304;          // 4,194,304 f
  float* BIG  = CTX + 4194304;        // 16,777,216 f (qkv / ffn-hidden / sims)
  float* POOL = BIG + 16777216;       // 16384 f
  float* QN   = POOL + 16384;         // 16384 f
  float* INVN = QN + 16384;           // 200000 f
  float* TOPV = INVN + 200000;        // 4096 f
  int*   TOPI = (int*)(TOPV + 4096);  // 4096 i
  float* RETR = (float*)(TOPI + 4096);// 16384 f

  embed_kernel<<<ROWS_, 256, 0, stream>>>(ids, emb, X);

  for (int l = 0; l < 2; ++l) {
    gemm_kernel<<<dim3(768 / 64, ROWS_ / 64), 256, 0, stream>>>(
        X, qkv_w + (size_t)l * 256 * 768, qkv_b + l * 768, BIG, ROWS_, 768, 256, 0);
    attn_kernel<<<B_ * H_, 256, 0, stream>>>(BIG, CTX);
    gemm_kernel<<<dim3(256 / 64, ROWS_ / 64), 256, 0, stream>>>(
        CTX, out_w + (size_t)l * 256 * 256, out_b + l * 256, Y, ROWS_, 256, 256, 0);
    addln_kernel<<<ROWS_, 256, 0, stream>>>(X, Y, ln1_s + l * 256, ln1_b + l * 256, X);
    gemm_kernel<<<dim3(1024 / 64, ROWS_ / 64), 256, 0, stream>>>(
        X, ff_w1 + (size_t)l * 256 * 1024, ff_b1 + l * 1024, BIG, ROWS_, 1024, 256, 1);
    gemm_kernel<<<dim3(256 / 64, ROWS_ / 64), 256, 0, stream>>>(
        BIG, ff_w2 + (size_t)l * 1024 * 256, ff_b2 + l * 256, Y, ROWS_, 256, 1024, 0);
    addln_kernel<<<ROWS_, 256, 0, stream>>>(X, Y, ln2_s + l * 256, ln2_b + l * 256, X);
  }

  addln_kernel<<<ROWS_, 256, 0, stream>>>(X, nullptr, lnf_s, lnf_b, Y);
  pooled_kernel<<<B_, 256, 0, stream>>>(Y, mask, POOL);
  qnorm_kernel<<<B_, 256, 0, stream>>>(POOL, QN);
  invnorm_kernel<<<MEM_, 64, 0, stream>>>(mkeys, INVN);
  sims_kernel<<<MEM_ / 64, 256, 0, stream>>>(QN, mkeys, INVN, BIG);
  topk_kernel<<<B_, 256, 0, stream>>>(BIG, topk, TOPV, TOPI);
  retrieve_kernel<<<B_, 256, 0, stream>>>(TOPV, TOPI, topk, mvals, mconf, RETR);
  head_kernel<<<B_, 256, 0, stream>>>(POOL, RETR, gw1, gb1, gw2, gb2, cw, cb, out);
}

// Round 2
// 1417.430 us; speedup vs baseline: 5.7181x; 5.7181x over previous
//
#include <hip/hip_runtime.h>
#include <math.h>

// ---------------- constants ----------------
#define B_   64
#define S_   256
#define D_   256
#define H_   8
#define DH_  32
#define FF_  1024
#define MEM_ 200000
#define ROWS_ (B_ * S_)   // 16384
#define NCHUNK_ 32
#define CHUNK_  6250      // MEM_ / NCHUNK_

// ---------------- helpers ----------------
__device__ __forceinline__ float blockReduceSum256(float v, float* sh) {
  #pragma unroll
  for (int o = 32; o; o >>= 1) v += __shfl_down(v, o);
  int lane = threadIdx.x & 63, w = threadIdx.x >> 6;
  __syncthreads();
  if (lane == 0) sh[w] = v;
  __syncthreads();
  return sh[0] + sh[1] + sh[2] + sh[3];
}

// float -> order-preserving uint (larger float => larger uint)
__device__ __forceinline__ unsigned int f2key(float f) {
  unsigned int b = __float_as_uint(f);
  return (b & 0x80000000u) ? ~b : (b | 0x80000000u);
}
__device__ __forceinline__ float key2f(unsigned int u) {
  unsigned int b = (u & 0x80000000u) ? (u & 0x7FFFFFFFu) : ~u;
  return __uint_as_float(b);
}
__device__ __forceinline__ unsigned long long ullmax(unsigned long long a, unsigned long long b) {
  return a > b ? a : b;
}

// ---------------- embedding + positional encoding ----------------
__global__ __launch_bounds__(256) void embed_kernel(const int* __restrict__ ids,
                                                    const float* __restrict__ emb,
                                                    float* __restrict__ x) {
  int row = blockIdx.x;            // 0..16383
  int d = threadIdx.x;             // 0..255
  int s = row & (S_ - 1);
  int tok = ids[row];
  int d2 = d & ~1;
  float div = expf((float)d2 * (-9.210340371976184f / 256.0f)); // -ln(10000)/256
  float ang = (float)s * div;
  float pe = (d & 1) ? cosf(ang) : sinf(ang);
  x[(size_t)row * D_ + d] = emb[(size_t)tok * D_ + d] * 16.0f + pe;
}

// ---------------- generic fp32 GEMM: C = act(A[M,K] @ W[K,N] + bias[N]) ----------------
// act: 0 = none, 1 = exact gelu
__global__ __launch_bounds__(256) void gemm_kernel(const float* __restrict__ A,
                                                   const float* __restrict__ W,
                                                   const float* __restrict__ bias,
                                                   float* __restrict__ C,
                                                   int M, int N, int K, int act) {
  __shared__ float As[16][64];
  __shared__ float Bs[16][64];
  int tid = threadIdx.x;
  int tx = tid & 15, ty = tid >> 4;
  int m0 = blockIdx.y * 64, n0 = blockIdx.x * 64;
  float c[4][4] = {};
  for (int k0 = 0; k0 < K; k0 += 16) {
    {
      int m = tid >> 2, kk4 = (tid & 3) << 2;
      const float4 av = *reinterpret_cast<const float4*>(A + (size_t)(m0 + m) * K + k0 + kk4);
      As[kk4 + 0][m] = av.x; As[kk4 + 1][m] = av.y; As[kk4 + 2][m] = av.z; As[kk4 + 3][m] = av.w;
    }
    {
      int kk = tid >> 4, n4 = (tid & 15) << 2;
      *reinterpret_cast<float4*>(&Bs[kk][n4]) =
          *reinterpret_cast<const float4*>(W + (size_t)(k0 + kk) * N + n0 + n4);
    }
    __syncthreads();
    #pragma unroll
    for (int kk = 0; kk < 16; ++kk) {
      float a[4], bb[4];
      #pragma unroll
      for (int i = 0; i < 4; ++i) a[i] = As[kk][ty * 4 + i];
      #pragma unroll
      for (int j = 0; j < 4; ++j) bb[j] = Bs[kk][tx * 4 + j];
      #pragma unroll
      for (int i = 0; i < 4; ++i)
        #pragma unroll
        for (int j = 0; j < 4; ++j) c[i][j] += a[i] * bb[j];
    }
    __syncthreads();
  }
  #pragma unroll
  for (int i = 0; i < 4; ++i) {
    int row = m0 + ty * 4 + i;
    #pragma unroll
    for (int j = 0; j < 4; ++j) {
      int col = n0 + tx * 4 + j;
      float v = c[i][j] + bias[col];
      if (act == 1) v = 0.5f * v * (1.0f + erff(v * 0.7071067811865476f));
      C[(size_t)row * N + col] = v;
    }
  }
}

// ---------------- fused attention (flash-style, fp32) ----------------
__global__ __launch_bounds__(256) void attn_kernel(const float* __restrict__ qkv,
                                                   float* __restrict__ ctx) {
  __shared__ float Ks[S_][DH_];
  __shared__ float Vs[S_][DH_];
  int bh = blockIdx.x;
  int b = bh >> 3, h = bh & 7;
  int t = threadIdx.x;
  const float* base = qkv + (size_t)(b * S_) * 768;
  for (int idx = t; idx < S_ * DH_; idx += 256) {
    int s = idx >> 5, i = idx & 31;
    Ks[s][i] = base[(size_t)s * 768 + 256 + h * 32 + i];
    Vs[s][i] = base[(size_t)s * 768 + 512 + h * 32 + i];
  }
  float q[DH_];
  {
    const float* qp = base + (size_t)t * 768 + h * 32;
    #pragma unroll
    for (int i = 0; i < DH_; ++i) q[i] = qp[i];
  }
  __syncthreads();
  float m = -1e30f, l = 0.0f, acc[DH_];
  #pragma unroll
  for (int i = 0; i < DH_; ++i) acc[i] = 0.0f;
  for (int k = 0; k < S_; ++k) {
    float sc = 0.0f;
    #pragma unroll
    for (int i = 0; i < DH_; ++i) sc += q[i] * Ks[k][i];
    sc /= 5.656854249492381f;  // sqrt(32)
    float mn = fmaxf(m, sc);
    float scale = expf(m - mn);
    float p = expf(sc - mn);
    l = l * scale + p;
    #pragma unroll
    for (int i = 0; i < DH_; ++i) acc[i] = acc[i] * scale + p * Vs[k][i];
    m = mn;
  }
  float inv = 1.0f / l;
  float* cp = ctx + (size_t)(b * S_ + t) * D_ + h * 32;
  #pragma unroll
  for (int i = 0; i < DH_; ++i) cp[i] = acc[i] * inv;
}

// ---------------- residual add + layernorm (y may be null) ----------------
__global__ __launch_bounds__(256) void addln_kernel(const float* __restrict__ x,
                                                    const float* __restrict__ y,
                                                    const float* __restrict__ gam,
                                                    const float* __restrict__ bet,
                                                    float* __restrict__ out) {
  __shared__ float sh[8];
  int row = blockIdx.x, d = threadIdx.x;
  float v = x[(size_t)row * D_ + d];
  if (y) v += y[(size_t)row * D_ + d];
  float mean = blockReduceSum256(v, sh) * (1.0f / D_);
  float diff = v - mean;
  float var = blockReduceSum256(diff * diff, sh) * (1.0f / D_);
  out[(size_t)row * D_ + d] = diff * rsqrtf(var + 1e-5f) * gam[d] + bet[d];
}

// ---------------- masked mean pool ----------------
__global__ __launch_bounds__(256) void pooled_kernel(const float* __restrict__ hidden,
                                                     const float* __restrict__ mask,
                                                     float* __restrict__ pooled) {
  int b = blockIdx.x, d = threadIdx.x;
  float s = 0.0f, msum = 0.0f;
  for (int t = 0; t < S_; ++t) {
    float mk = mask[b * S_ + t];
    s += hidden[(size_t)(b * S_ + t) * D_ + d] * mk;
    msum += mk;
  }
  pooled[b * D_ + d] = s / (msum + 1e-8f);
}

// ---------------- normalize pooled queries ----------------
__global__ __launch_bounds__(256) void qnorm_kernel(const float* __restrict__ pooled,
                                                    float* __restrict__ qn) {
  __shared__ float sh[8];
  int b = blockIdx.x, d = threadIdx.x;
  float v = pooled[b * D_ + d];
  float ss = blockReduceSum256(v * v, sh);
  qn[b * D_ + d] = v / fmaxf(sqrtf(ss), 1e-8f);
}

// ---------------- per-key inverse norms ----------------
__global__ __launch_bounds__(64) void invnorm_kernel(const float* __restrict__ keys,
                                                     float* __restrict__ invn) {
  int row = blockIdx.x, t = threadIdx.x;  // 64 threads
  float4 v = *reinterpret_cast<const float4*>(keys + (size_t)row * D_ + t * 4);
  float ss = v.x * v.x + v.y * v.y + v.z * v.z + v.w * v.w;
  #pragma unroll
  for (int o = 32; o; o >>= 1) ss += __shfl_down(ss, o);
  if (t == 0) invn[row] = 1.0f / fmaxf(sqrtf(ss), 1e-8f);
}

// ---------------- sims[64, MEM] = qn @ (keys/|keys|)^T ----------------
__global__ __launch_bounds__(256) void sims_kernel(const float* __restrict__ qn,
                                                   const float* __restrict__ keys,
                                                   const float* __restrict__ invn,
                                                   float* __restrict__ sims) {
  __shared__ float As[16][64];
  __shared__ float Bs[16][64];
  int tid = threadIdx.x;
  int tx = tid & 15, ty = tid >> 4;
  int n0 = blockIdx.x * 64;
  float c[4][4] = {};
  for (int k0 = 0; k0 < D_; k0 += 16) {
    {
      int m = tid >> 2, kk4 = (tid & 3) << 2;
      const float4 av = *reinterpret_cast<const float4*>(qn + (size_t)m * D_ + k0 + kk4);
      As[kk4 + 0][m] = av.x; As[kk4 + 1][m] = av.y; As[kk4 + 2][m] = av.z; As[kk4 + 3][m] = av.w;
    }
    {
      int n = tid & 63, kk4 = (tid >> 6) << 2;
      const float4 bv = *reinterpret_cast<const float4*>(keys + (size_t)(n0 + n) * D_ + k0 + kk4);
      Bs[kk4 + 0][n] = bv.x; Bs[kk4 + 1][n] = bv.y; Bs[kk4 + 2][n] = bv.z; Bs[kk4 + 3][n] = bv.w;
    }
    __syncthreads();
    #pragma unroll
    for (int kk = 0; kk < 16; ++kk) {
      float a[4], bb[4];
      #pragma unroll
      for (int i = 0; i < 4; ++i) a[i] = As[kk][ty * 4 + i];
      #pragma unroll
      for (int j = 0; j < 4; ++j) bb[j] = Bs[kk][tx * 4 + j];
      #pragma unroll
      for (int i = 0; i < 4; ++i)
        #pragma unroll
        for (int j = 0; j < 4; ++j) c[i][j] += a[i] * bb[j];
    }
    __syncthreads();
  }
  #pragma unroll
  for (int i = 0; i < 4; ++i) {
    int q = ty * 4 + i;
    #pragma unroll
    for (int j = 0; j < 4; ++j) {
      int col = n0 + tx * 4 + j;
      sims[(size_t)q * MEM_ + col] = c[i][j] * invn[col];
    }
  }
}

// ---------------- top-k stage 1: per-chunk top-k via in-LDS iterative argmax ----------------
// grid: 64 rows * 32 chunks. Packed key = (sortable(value) << 32) | ~global_index
// -> max key == max value, ties broken by LOWEST index (matches jax.lax.top_k).
__global__ __launch_bounds__(256) void topk_stage1(const float* __restrict__ sims,
                                                   const int* __restrict__ topk,
                                                   unsigned long long* __restrict__ candk) {
  __shared__ float buf[CHUNK_];
  __shared__ unsigned long long wk[4];
  int row = blockIdx.x >> 5, chunk = blockIdx.x & 31;
  int t = threadIdx.x;
  int k = *topk; if (k > 64) k = 64; if (k < 1) k = 1;
  const float* src = sims + (size_t)row * MEM_ + (size_t)chunk * CHUNK_;
  for (int i = t; i < CHUNK_; i += 256) buf[i] = src[i];
  __syncthreads();
  int gbase = chunk * CHUNK_;
  int lane = t & 63, w = t >> 6;
  for (int iter = 0; iter < k; ++iter) {
    unsigned long long best = 0ull;
    for (int i = t; i < CHUNK_; i += 256) {
      unsigned long long key =
          ((unsigned long long)f2key(buf[i]) << 32) | (unsigned int)~(unsigned int)(gbase + i);
      best = ullmax(best, key);
    }
    #pragma unroll
    for (int o = 32; o; o >>= 1) best = ullmax(best, __shfl_down(best, o));
    if (lane == 0) wk[w] = best;
    __syncthreads();
    best = ullmax(ullmax(wk[0], wk[1]), ullmax(wk[2], wk[3]));
    if (t == 0) {
      int gi = (int)~(unsigned int)best;
      candk[(size_t)blockIdx.x * 64 + iter] = best;
      buf[gi - gbase] = -INFINITY;   // remove winner
    }
    __syncthreads();
  }
}

// ---------------- top-k stage 2: reduce 32*k candidates per row to final top-k ----------------
__global__ __launch_bounds__(256) void topk_stage2(const unsigned long long* __restrict__ candk,
                                                   const int* __restrict__ topk,
                                                   float* __restrict__ topv,
                                                   int* __restrict__ topi) {
  __shared__ unsigned long long buf[NCHUNK_ * 64];
  __shared__ unsigned long long wk[4];
  int row = blockIdx.x, t = threadIdx.x;
  int k = *topk; if (k > 64) k = 64; if (k < 1) k = 1;
  int ncand = NCHUNK_ * k;
  const unsigned long long* src = candk + (size_t)row * NCHUNK_ * 64;
  for (int i = t; i < ncand; i += 256) {
    int chunk = i / k, iter = i - chunk * k;
    buf[i] = src[chunk * 64 + iter];
  }
  __syncthreads();
  int lane = t & 63, w = t >> 6;
  for (int iter = 0; iter < k; ++iter) {
    unsigned long long best = 0ull;
    for (int i = t; i < ncand; i += 256) best = ullmax(best, buf[i]);
    #pragma unroll
    for (int o = 32; o; o >>= 1) best = ullmax(best, __shfl_down(best, o));
    if (lane == 0) wk[w] = best;
    __syncthreads();
    best = ullmax(ullmax(wk[0], wk[1]), ullmax(wk[2], wk[3]));
    if (t == 0) {
      topv[row * 64 + iter] = key2f((unsigned int)(best >> 32));
      topi[row * 64 + iter] = (int)~(unsigned int)best;
    }
    // keys are unique (distinct indices) -> zero out the winner; each i owned by one thread
    for (int i = t; i < ncand; i += 256) if (buf[i] == best) buf[i] = 0ull;
    __syncthreads();
  }
}

// ---------------- weighted aggregate of retrieved values ----------------
__global__ __launch_bounds__(256) void retrieve_kernel(const float* __restrict__ topv,
                                                       const int* __restrict__ topi,
                                                       const int* __restrict__ topk,
                                                       const float* __restrict__ vals,
                                                       const float* __restrict__ conf,
                                                       float* __restrict__ retr) {
  int b = blockIdx.x, d = threadIdx.x;
  int k = *topk; if (k > 64) k = 64; if (k < 1) k = 1;
  float acc = 0.0f, wsum = 0.0f;
  for (int i = 0; i < k; ++i) {
    int idx = topi[b * 64 + i];
    float w = fmaxf(conf[idx], 1e-4f) * topv[b * 64 + i];
    wsum += w;
    acc += w * vals[(size_t)idx * D_ + d];
  }
  retr[b * D_ + d] = acc / (wsum + 1e-8f);
}

// ---------------- gate MLP + fuse + classifier ----------------
__global__ __launch_bounds__(256) void head_kernel(const float* __restrict__ pooled,
                                                   const float* __restrict__ retr,
                                                   const float* __restrict__ gw1,
                                                   const float* __restrict__ gb1,
                                                   const float* __restrict__ gw2,
                                                   const float* __restrict__ gb2,
                                                   const float* __restrict__ cw,
                                                   const float* __restrict__ cb,
                                                   float* __restrict__ out) {
  __shared__ float pl[D_], hh[D_], fu[D_], sh[8];
  int b = blockIdx.x, d = threadIdx.x;
  pl[d] = pooled[b * D_ + d];
  __syncthreads();
  float a = gb1[d];
  for (int e = 0; e < D_; ++e) a += pl[e] * gw1[e * D_ + d];
  hh[d] = fmaxf(a, 0.0f);
  float gsum = blockReduceSum256(hh[d] * gw2[d], sh);
  float g = 1.0f / (1.0f + expf(-(gsum + gb2[0])));
  fu[d] = g * retr[b * D_ + d] + (1.0f - g) * pl[d];
  __syncthreads();
  if (d < 16) {
    float o = cb[d];
    for (int e = 0; e < D_; ++e) o += fu[e] * cw[e * 16 + d];
    out[b * 16 + d] = o;
  }
}

// ---------------- launcher ----------------
extern "C" void kernel_launch(void* const* d_in, const int* in_sizes, int n_in,
                              void* d_out, int out_size, void* d_ws, size_t ws_size,
                              hipStream_t stream) {
  const int*   ids   = (const int*)d_in[0];
  const float* mask  = (const float*)d_in[1];
  const int*   topk  = (const int*)d_in[2];
  const float* emb   = (const float*)d_in[3];
  const float* qkv_w = (const float*)d_in[4];
  const float* qkv_b = (const float*)d_in[5];
  const float* out_w = (const float*)d_in[6];
  const float* out_b = (const float*)d_in[7];
  const float* ln1_s = (const float*)d_in[8];
  const float* ln1_b = (const float*)d_in[9];
  const float* ff_w1 = (const float*)d_in[10];
  const float* ff_b1 = (const float*)d_in[11];
  const float* ff_w2 = (const float*)d_in[12];
  const float* ff_b2 = (const float*)d_in[13];
  const float* ln2_s = (const float*)d_in[14];
  const float* ln2_b = (const float*)d_in[15];
  const float* lnf_s = (const float*)d_in[16];
  const float* lnf_b = (const float*)d_in[17];
  const float* gw1   = (const float*)d_in[18];
  const float* gb1   = (const float*)d_in[19];
  const float* gw2   = (const float*)d_in[20];
  const float* gb2   = (const float*)d_in[21];
  const float* cw    = (const float*)d_in[22];
  const float* cb    = (const float*)d_in[23];
  const float* mkeys = (const float*)d_in[24];
  const float* mvals = (const float*)d_in[25];
  const float* mconf = (const float*)d_in[26];
  float* out = (float*)d_out;

  float* ws   = (float*)d_ws;
  float* X    = ws;                   // 4,194,304 f
  float* Y    = X + 4194304;          // 4,194,304 f
  float* CTX  = Y + 4194304;          // 4,194,304 f (reused as CANDK after layers)
  float* BIG  = CTX + 4194304;        // 16,777,216 f (qkv / ffn-hidden / sims)
  float* POOL = BIG + 16777216;       // 16384 f
  float* QN   = POOL + 16384;         // 16384 f
  float* INVN = QN + 16384;           // 200000 f
  float* TOPV = INVN + 200000;        // 4096 f
  int*   TOPI = (int*)(TOPV + 4096);  // 4096 i
  float* RETR = (float*)(TOPI + 4096);// 16384 f
  unsigned long long* CANDK = (unsigned long long*)CTX;  // 64*32*64*8 B = 1 MB

  embed_kernel<<<ROWS_, 256, 0, stream>>>(ids, emb, X);

  for (int l = 0; l < 2; ++l) {
    gemm_kernel<<<dim3(768 / 64, ROWS_ / 64), 256, 0, stream>>>(
        X, qkv_w + (size_t)l * 256 * 768, qkv_b + l * 768, BIG, ROWS_, 768, 256, 0);
    attn_kernel<<<B_ * H_, 256, 0, stream>>>(BIG, CTX);
    gemm_kernel<<<dim3(256 / 64, ROWS_ / 64), 256, 0, stream>>>(
        CTX, out_w + (size_t)l * 256 * 256, out_b + l * 256, Y, ROWS_, 256, 256, 0);
    addln_kernel<<<ROWS_, 256, 0, stream>>>(X, Y, ln1_s + l * 256, ln1_b + l * 256, X);
    gemm_kernel<<<dim3(1024 / 64, ROWS_ / 64), 256, 0, stream>>>(
        X, ff_w1 + (size_t)l * 256 * 1024, ff_b1 + l * 1024, BIG, ROWS_, 1024, 256, 1);
    gemm_kernel<<<dim3(256 / 64, ROWS_ / 64), 256, 0, stream>>>(
        BIG, ff_w2 + (size_t)l * 1024 * 256, ff_b2 + l * 256, Y, ROWS_, 256, 1024, 0);
    addln_kernel<<<ROWS_, 256, 0, stream>>>(X, Y, ln2_s + l * 256, ln2_b + l * 256, X);
  }

  addln_kernel<<<ROWS_, 256, 0, stream>>>(X, nullptr, lnf_s, lnf_b, Y);
  pooled_kernel<<<B_, 256, 0, stream>>>(Y, mask, POOL);
  qnorm_kernel<<<B_, 256, 0, stream>>>(POOL, QN);
  invnorm_kernel<<<MEM_, 64, 0, stream>>>(mkeys, INVN);
  sims_kernel<<<MEM_ / 64, 256, 0, stream>>>(QN, mkeys, INVN, BIG);
  topk_stage1<<<B_ * NCHUNK_, 256, 0, stream>>>(BIG, topk, CANDK);
  topk_stage2<<<B_, 256, 0, stream>>>(CANDK, topk, TOPV, TOPI);
  retrieve_kernel<<<B_, 256, 0, stream>>>(TOPV, TOPI, topk, mvals, mconf, RETR);
  head_kernel<<<B_, 256, 0, stream>>>(POOL, RETR, gw1, gb1, gw2, gb2, cw, cb, out);
}

// Round 3
// 1087.478 us; speedup vs baseline: 7.4530x; 1.3034x over previous
//
#include <hip/hip_runtime.h>
#include <math.h>

// ---------------- constants ----------------
#define B_   64
#define S_   256
#define D_   256
#define H_   8
#define DH_  32
#define FF_  1024
#define MEM_ 200000
#define ROWS_ (B_ * S_)   // 16384
#define NCHUNK_ 64
#define CHUNK_  3125      // MEM_ / NCHUNK_

typedef float f32x4 __attribute__((ext_vector_type(4)));
typedef __bf16 bf16x8 __attribute__((ext_vector_type(8)));

// ---------------- helpers ----------------
__device__ __forceinline__ float blockReduceSum256(float v, float* sh) {
  #pragma unroll
  for (int o = 32; o; o >>= 1) v += __shfl_down(v, o);
  int lane = threadIdx.x & 63, w = threadIdx.x >> 6;
  __syncthreads();
  if (lane == 0) sh[w] = v;
  __syncthreads();
  return sh[0] + sh[1] + sh[2] + sh[3];
}

__device__ __forceinline__ unsigned int f2key(float f) {
  unsigned int b = __float_as_uint(f);
  return (b & 0x80000000u) ? ~b : (b | 0x80000000u);
}
__device__ __forceinline__ float key2f(unsigned int u) {
  unsigned int b = (u & 0x80000000u) ? (u & 0x7FFFFFFFu) : ~u;
  return __uint_as_float(b);
}
__device__ __forceinline__ unsigned long long ullmax(unsigned long long a, unsigned long long b) {
  return a > b ? a : b;
}

__device__ __forceinline__ unsigned short f32_bf16_rn(float x) {
  unsigned int u = __float_as_uint(x);
  u += 0x7FFFu + ((u >> 16) & 1u);
  return (unsigned short)(u >> 16);
}
__device__ __forceinline__ float bf16_f32(unsigned short h) {
  return __uint_as_float((unsigned int)h << 16);
}

// swizzled byte offsets into a [R][32] bf16 LDS tile (row stride 64B, 4x16B slots,
// slot ^= (row>>1)&3 -> 2-way-max bank aliasing on ds_read_b128 frag reads)
__device__ __forceinline__ int swz8(int row, int kq) {   // 8B granule (4 bf16), kq = k/4
  return row * 64 + ((((kq >> 1) ^ ((row >> 1) & 3)) << 4)) + (kq & 1) * 8;
}
__device__ __forceinline__ int swz16(int row, int kg) {  // 16B granule (8 bf16), kg = k/8
  return row * 64 + (((kg ^ ((row >> 1) & 3)) << 4));
}

// stage a [NROWS x 32] f32 tile from global as bf16 hi/lo pair into LDS
template<int NITER>
__device__ __forceinline__ void stage_bf16x3(const float* __restrict__ G, int ldg,
                                             int base_row, int k0, int max_row,
                                             char* __restrict__ sh, char* __restrict__ sl,
                                             int t) {
  #pragma unroll
  for (int r = 0; r < NITER; ++r) {
    int idx = r * 256 + t;
    int row = idx >> 3, kq = idx & 7;
    int gr = base_row + row; if (gr > max_row) gr = max_row;
    const float4 v = *reinterpret_cast<const float4*>(G + (size_t)gr * ldg + k0 + kq * 4);
    float vv[4] = {v.x, v.y, v.z, v.w};
    unsigned short h[4], l[4];
    #pragma unroll
    for (int j = 0; j < 4; ++j) {
      h[j] = f32_bf16_rn(vv[j]);
      l[j] = f32_bf16_rn(vv[j] - bf16_f32(h[j]));
    }
    uint2 hp = make_uint2((unsigned)h[0] | ((unsigned)h[1] << 16),
                          (unsigned)h[2] | ((unsigned)h[3] << 16));
    uint2 lp = make_uint2((unsigned)l[0] | ((unsigned)l[1] << 16),
                          (unsigned)l[2] | ((unsigned)l[3] << 16));
    int b8 = swz8(row, kq);
    *reinterpret_cast<uint2*>(sh + b8) = hp;
    *reinterpret_cast<uint2*>(sl + b8) = lp;
  }
}

// ---------------- bf16x3 MFMA GEMM: C[M,N] = act(A[M,K] @ BT[N,K]^T + bias) * scale ----------------
// BROWS = WM*64 rows/block, BCOLS = WN*64 cols/block, 4 waves, each wave 64x64 out.
template<int BROWS, int WM, int WN, int ACT, bool HAS_BIAS, bool HAS_SCALE>
__global__ __launch_bounds__(256) void gemm_bt(const float* __restrict__ A,
                                               const float* __restrict__ BT,
                                               const float* __restrict__ bias,
                                               const float* __restrict__ scl,
                                               float* __restrict__ C,
                                               int M, int N, int K) {
  constexpr int BCOLS = WN * 64;
  __shared__ __align__(16) char sAh[BROWS * 64];
  __shared__ __align__(16) char sAl[BROWS * 64];
  __shared__ __align__(16) char sBh[BCOLS * 64];
  __shared__ __align__(16) char sBl[BCOLS * 64];
  int t = threadIdx.x;
  int m0 = blockIdx.y * BROWS, n0 = blockIdx.x * BCOLS;
  int wid = t >> 6, lane = t & 63;
  int wr = wid / WN, wc = wid % WN;
  int lr = lane & 15, kg = lane >> 4;
  f32x4 acc[4][4] = {};
  for (int k0 = 0; k0 < K; k0 += 32) {
    stage_bf16x3<BROWS / 32>(A, K, m0, k0, M - 1, sAh, sAl, t);
    stage_bf16x3<BCOLS / 32>(BT, K, n0, k0, N - 1, sBh, sBl, t);
    __syncthreads();
    bf16x8 ah[4], al[4];
    #pragma unroll
    for (int mi = 0; mi < 4; ++mi) {
      int row = wr * 64 + mi * 16 + lr;
      int ab = swz16(row, kg);
      ah[mi] = *reinterpret_cast<const bf16x8*>(sAh + ab);
      al[mi] = *reinterpret_cast<const bf16x8*>(sAl + ab);
    }
    #pragma unroll
    for (int ni = 0; ni < 4; ++ni) {
      int rb = wc * 64 + ni * 16 + lr;
      int bb = swz16(rb, kg);
      bf16x8 bh = *reinterpret_cast<const bf16x8*>(sBh + bb);
      bf16x8 bl = *reinterpret_cast<const bf16x8*>(sBl + bb);
      #pragma unroll
      for (int mi = 0; mi < 4; ++mi) {
        acc[mi][ni] = __builtin_amdgcn_mfma_f32_16x16x32_bf16(ah[mi], bh, acc[mi][ni], 0, 0, 0);
        acc[mi][ni] = __builtin_amdgcn_mfma_f32_16x16x32_bf16(al[mi], bh, acc[mi][ni], 0, 0, 0);
        acc[mi][ni] = __builtin_amdgcn_mfma_f32_16x16x32_bf16(ah[mi], bl, acc[mi][ni], 0, 0, 0);
      }
    }
    __syncthreads();
  }
  #pragma unroll
  for (int mi = 0; mi < 4; ++mi) {
    #pragma unroll
    for (int ni = 0; ni < 4; ++ni) {
      int row0 = m0 + wr * 64 + mi * 16 + kg * 4;
      int col  = n0 + wc * 64 + ni * 16 + lr;
      if (col < N) {
        float b = HAS_BIAS ? bias[col] : 0.0f;
        float s = HAS_SCALE ? scl[col] : 1.0f;
        #pragma unroll
        for (int i = 0; i < 4; ++i) {
          float v = acc[mi][ni][i];
          if (HAS_SCALE) v *= s;
          if (HAS_BIAS) v += b;
          if (ACT == 1) v = 0.5f * v * (1.0f + erff(v * 0.7071067811865476f));
          C[(size_t)(row0 + i) * N + col] = v;
        }
      }
    }
  }
}

// ---------------- weight transpose: dst[c][r] = src[r][c] ----------------
__global__ __launch_bounds__(256) void transpose_kernel(const float* __restrict__ src,
                                                        float* __restrict__ dst,
                                                        int R, int C) {
  __shared__ float tile[32][33];
  int c0 = blockIdx.x * 32, r0 = blockIdx.y * 32;
  int x = threadIdx.x & 31, y4 = (threadIdx.x >> 5) * 4;
  #pragma unroll
  for (int i = 0; i < 4; ++i) {
    int r = r0 + y4 + i;
    if (r < R && c0 + x < C) tile[y4 + i][x] = src[(size_t)r * C + c0 + x];
  }
  __syncthreads();
  #pragma unroll
  for (int i = 0; i < 4; ++i) {
    int c = c0 + y4 + i;
    if (c < C && r0 + x < R) dst[(size_t)c * R + r0 + x] = tile[x][y4 + i];
  }
}

// ---------------- embedding + positional encoding ----------------
__global__ __launch_bounds__(256) void embed_kernel(const int* __restrict__ ids,
                                                    const float* __restrict__ emb,
                                                    float* __restrict__ x) {
  int row = blockIdx.x;
  int d = threadIdx.x;
  int s = row & (S_ - 1);
  int tok = ids[row];
  int d2 = d & ~1;
  float div = expf((float)d2 * (-9.210340371976184f / 256.0f));
  float ang = (float)s * div;
  float pe = (d & 1) ? cosf(ang) : sinf(ang);
  x[(size_t)row * D_ + d] = emb[(size_t)tok * D_ + d] * 16.0f + pe;
}

// ---------------- fused attention (flash-style, fp32, skip-rescale) ----------------
__global__ __launch_bounds__(256) void attn_kernel(const float* __restrict__ qkv,
                                                   float* __restrict__ ctx) {
  __shared__ float Ks[S_][DH_];
  __shared__ float Vs[S_][DH_];
  int bh = blockIdx.x;
  int b = bh >> 3, h = bh & 7;
  int t = threadIdx.x;
  const float* base = qkv + (size_t)(b * S_) * 768;
  for (int idx = t; idx < S_ * DH_; idx += 256) {
    int s = idx >> 5, i = idx & 31;
    Ks[s][i] = base[(size_t)s * 768 + 256 + h * 32 + i];
    Vs[s][i] = base[(size_t)s * 768 + 512 + h * 32 + i];
  }
  float q[DH_];
  {
    const float* qp = base + (size_t)t * 768 + h * 32;
    #pragma unroll
    for (int i = 0; i < DH_; ++i) q[i] = qp[i] * 0.17677669529663687f;  // 1/sqrt(32)
  }
  __syncthreads();
  float m = -1e30f, l = 0.0f, acc[DH_];
  #pragma unroll
  for (int i = 0; i < DH_; ++i) acc[i] = 0.0f;
  for (int k = 0; k < S_; ++k) {
    float sc = 0.0f;
    #pragma unroll
    for (int i = 0; i < DH_; ++i) sc += q[i] * Ks[k][i];
    if (sc > m) {
      // new max: p = exp(0) = 1 exactly; rescale old state (bit-exact vs always-rescale)
      float scale = expf(m - sc);
      l = l * scale + 1.0f;
      #pragma unroll
      for (int i = 0; i < DH_; ++i) acc[i] = acc[i] * scale + Vs[k][i];
      m = sc;
    } else {
      // scale = exp(0) = 1: skipping the multiply is exact
      float p = expf(sc - m);
      l += p;
      #pragma unroll
      for (int i = 0; i < DH_; ++i) acc[i] += p * Vs[k][i];
    }
  }
  float inv = 1.0f / l;
  float* cp = ctx + (size_t)(b * S_ + t) * D_ + h * 32;
  #pragma unroll
  for (int i = 0; i < DH_; ++i) cp[i] = acc[i] * inv;
}

// ---------------- residual add + layernorm (y may be null) ----------------
__global__ __launch_bounds__(256) void addln_kernel(const float* __restrict__ x,
                                                    const float* __restrict__ y,
                                                    const float* __restrict__ gam,
                                                    const float* __restrict__ bet,
                                                    float* __restrict__ out) {
  __shared__ float sh[8];
  int row = blockIdx.x, d = threadIdx.x;
  float v = x[(size_t)row * D_ + d];
  if (y) v += y[(size_t)row * D_ + d];
  float mean = blockReduceSum256(v, sh) * (1.0f / D_);
  float diff = v - mean;
  float var = blockReduceSum256(diff * diff, sh) * (1.0f / D_);
  out[(size_t)row * D_ + d] = diff * rsqrtf(var + 1e-5f) * gam[d] + bet[d];
}

// ---------------- masked mean pool ----------------
__global__ __launch_bounds__(256) void pooled_kernel(const float* __restrict__ hidden,
                                                     const float* __restrict__ mask,
                                                     float* __restrict__ pooled) {
  int b = blockIdx.x, d = threadIdx.x;
  float s = 0.0f, msum = 0.0f;
  for (int t = 0; t < S_; ++t) {
    float mk = mask[b * S_ + t];
    s += hidden[(size_t)(b * S_ + t) * D_ + d] * mk;
    msum += mk;
  }
  pooled[b * D_ + d] = s / (msum + 1e-8f);
}

// ---------------- normalize pooled queries ----------------
__global__ __launch_bounds__(256) void qnorm_kernel(const float* __restrict__ pooled,
                                                    float* __restrict__ qn) {
  __shared__ float sh[8];
  int b = blockIdx.x, d = threadIdx.x;
  float v = pooled[b * D_ + d];
  float ss = blockReduceSum256(v * v, sh);
  qn[b * D_ + d] = v / fmaxf(sqrtf(ss), 1e-8f);
}

// ---------------- per-key inverse norms ----------------
__global__ __launch_bounds__(64) void invnorm_kernel(const float* __restrict__ keys,
                                                     float* __restrict__ invn) {
  int row = blockIdx.x, t = threadIdx.x;
  float4 v = *reinterpret_cast<const float4*>(keys + (size_t)row * D_ + t * 4);
  float ss = v.x * v.x + v.y * v.y + v.z * v.z + v.w * v.w;
  #pragma unroll
  for (int o = 32; o; o >>= 1) ss += __shfl_down(ss, o);
  if (t == 0) invn[row] = 1.0f / fmaxf(sqrtf(ss), 1e-8f);
}

// ---------------- top-k stage 1: per-chunk top-k, u64 keys precomputed in LDS ----------------
__global__ __launch_bounds__(256) void topk_stage1(const float* __restrict__ sims,
                                                   const int* __restrict__ topk,
                                                   unsigned long long* __restrict__ candk) {
  __shared__ unsigned long long kbuf[CHUNK_];
  __shared__ unsigned long long wk[4];
  int row = blockIdx.x >> 6, chunk = blockIdx.x & 63;
  int t = threadIdx.x;
  int k = *topk; if (k > 64) k = 64; if (k < 1) k = 1;
  const float* src = sims + (size_t)row * MEM_ + (size_t)chunk * CHUNK_;
  int gbase = chunk * CHUNK_;
  for (int i = t; i < CHUNK_; i += 256)
    kbuf[i] = ((unsigned long long)f2key(src[i]) << 32) | (unsigned int)~(unsigned int)(gbase + i);
  __syncthreads();
  int lane = t & 63, w = t >> 6;
  for (int iter = 0; iter < k; ++iter) {
    unsigned long long best = 0ull;
    for (int i = t; i < CHUNK_; i += 256) best = ullmax(best, kbuf[i]);
    #pragma unroll
    for (int o = 32; o; o >>= 1) best = ullmax(best, __shfl_down(best, o));
    if (lane == 0) wk[w] = best;
    __syncthreads();
    best = ullmax(ullmax(wk[0], wk[1]), ullmax(wk[2], wk[3]));
    if (t == 0) {
      candk[(size_t)blockIdx.x * 64 + iter] = best;
      int gi = (int)~(unsigned int)best;
      kbuf[gi - gbase] = 0ull;  // no legit key has hi32==0 (would require NaN)
    }
    __syncthreads();
  }
}

// ---------------- top-k stage 2: reduce NCHUNK_*k candidates per row ----------------
__global__ __launch_bounds__(256) void topk_stage2(const unsigned long long* __restrict__ candk,
                                                   const int* __restrict__ topk,
                                                   float* __restrict__ topv,
                                                   int* __restrict__ topi) {
  __shared__ unsigned long long buf[NCHUNK_ * 64];
  __shared__ unsigned long long wk[4];
  int row = blockIdx.x, t = threadIdx.x;
  int k = *topk; if (k > 64) k = 64; if (k < 1) k = 1;
  int ncand = NCHUNK_ * k;
  const unsigned long long* src = candk + (size_t)row * NCHUNK_ * 64;
  for (int i = t; i < ncand; i += 256) {
    int chunk = i / k, iter = i - chunk * k;
    buf[i] = src[chunk * 64 + iter];
  }
  __syncthreads();
  int lane = t & 63, w = t >> 6;
  for (int iter = 0; iter < k; ++iter) {
    unsigned long long best = 0ull;
    for (int i = t; i < ncand; i += 256) best = ullmax(best, buf[i]);
    #pragma unroll
    for (int o = 32; o; o >>= 1) best = ullmax(best, __shfl_down(best, o));
    if (lane == 0) wk[w] = best;
    __syncthreads();
    best = ullmax(ullmax(wk[0], wk[1]), ullmax(wk[2], wk[3]));
    if (t == 0) {
      topv[row * 64 + iter] = key2f((unsigned int)(best >> 32));
      topi[row * 64 + iter] = (int)~(unsigned int)best;
    }
    for (int i = t; i < ncand; i += 256) if (buf[i] == best) buf[i] = 0ull;
    __syncthreads();
  }
}

// ---------------- weighted aggregate of retrieved values ----------------
__global__ __launch_bounds__(256) void retrieve_kernel(const float* __restrict__ topv,
                                                       const int* __restrict__ topi,
                                                       const int* __restrict__ topk,
                                                       const float* __restrict__ vals,
                                                       const float* __restrict__ conf,
                                                       float* __restrict__ retr) {
  int b = blockIdx.x, d = threadIdx.x;
  int k = *topk; if (k > 64) k = 64; if (k < 1) k = 1;
  float acc = 0.0f, wsum = 0.0f;
  for (int i = 0; i < k; ++i) {
    int idx = topi[b * 64 + i];
    float w = fmaxf(conf[idx], 1e-4f) * topv[b * 64 + i];
    wsum += w;
    acc += w * vals[(size_t)idx * D_ + d];
  }
  retr[b * D_ + d] = acc / (wsum + 1e-8f);
}

// ---------------- gate MLP + fuse + classifier ----------------
__global__ __launch_bounds__(256) void head_kernel(const float* __restrict__ pooled,
                                                   const float* __restrict__ retr,
                                                   const float* __restrict__ gw1,
                                                   const float* __restrict__ gb1,
                                                   const float* __restrict__ gw2,
                                                   const float* __restrict__ gb2,
                                                   const float* __restrict__ cw,
                                                   const float* __restrict__ cb,
                                                   float* __restrict__ out) {
  __shared__ float pl[D_], hh[D_], fu[D_], sh[8];
  int b = blockIdx.x, d = threadIdx.x;
  pl[d] = pooled[b * D_ + d];
  __syncthreads();
  float a = gb1[d];
  for (int e = 0; e < D_; ++e) a += pl[e] * gw1[e * D_ + d];
  hh[d] = fmaxf(a, 0.0f);
  float gsum = blockReduceSum256(hh[d] * gw2[d], sh);
  float g = 1.0f / (1.0f + expf(-(gsum + gb2[0])));
  fu[d] = g * retr[b * D_ + d] + (1.0f - g) * pl[d];
  __syncthreads();
  if (d < 16) {
    float o = cb[d];
    for (int e = 0; e < D_; ++e) o += fu[e] * cw[e * 16 + d];
    out[b * 16 + d] = o;
  }
}

// ---------------- launcher ----------------
extern "C" void kernel_launch(void* const* d_in, const int* in_sizes, int n_in,
                              void* d_out, int out_size, void* d_ws, size_t ws_size,
                              hipStream_t stream) {
  const int*   ids   = (const int*)d_in[0];
  const float* mask  = (const float*)d_in[1];
  const int*   topk  = (const int*)d_in[2];
  const float* emb   = (const float*)d_in[3];
  const float* qkv_w = (const float*)d_in[4];
  const float* qkv_b = (const float*)d_in[5];
  const float* out_w = (const float*)d_in[6];
  const float* out_b = (const float*)d_in[7];
  const float* ln1_s = (const float*)d_in[8];
  const float* ln1_b = (const float*)d_in[9];
  const float* ff_w1 = (const float*)d_in[10];
  const float* ff_b1 = (const float*)d_in[11];
  const float* ff_w2 = (const float*)d_in[12];
  const float* ff_b2 = (const float*)d_in[13];
  const float* ln2_s = (const float*)d_in[14];
  const float* ln2_b = (const float*)d_in[15];
  const float* lnf_s = (const float*)d_in[16];
  const float* lnf_b = (const float*)d_in[17];
  const float* gw1   = (const float*)d_in[18];
  const float* gb1   = (const float*)d_in[19];
  const float* gw2   = (const float*)d_in[20];
  const float* gb2   = (const float*)d_in[21];
  const float* cw    = (const float*)d_in[22];
  const float* cb    = (const float*)d_in[23];
  const float* mkeys = (const float*)d_in[24];
  const float* mvals = (const float*)d_in[25];
  const float* mconf = (const float*)d_in[26];
  float* out = (float*)d_out;

  float* ws   = (float*)d_ws;
  float* X    = ws;                    // 4,194,304 f
  float* Y    = X + 4194304;           // 4,194,304 f
  float* CTX  = Y + 4194304;           // 4,194,304 f (reused as CANDK post-layers)
  float* BIG  = CTX + 4194304;         // 16,777,216 f (qkv / ffn-hidden / sims)
  float* WT   = BIG + 16777216;        // 1,572,864 f (transposed weights; reused post-layers)
  // post-layer union over the WT region:
  float* POOL = WT;                    // 16384 f
  float* QN   = POOL + 16384;          // 16384 f
  float* INVN = QN + 16384;            // 200000 f
  float* TOPV = INVN + 200000;         // 4096 f
  int*   TOPI = (int*)(TOPV + 4096);   // 4096 i
  float* RETR = (float*)(TOPI + 4096); // 16384 f
  unsigned long long* CANDK = (unsigned long long*)CTX;  // 4096*64*8B = 2 MB

  const size_t WSTRIDE = 786432;  // per-layer transposed weights

  // transpose all weights up front (they must persist across both layers)
  for (int l = 0; l < 2; ++l) {
    float* qkvWT = WT + l * WSTRIDE;
    float* outWT = qkvWT + 196608;
    float* ff1WT = outWT + 65536;
    float* ff2WT = ff1WT + 262144;
    transpose_kernel<<<dim3(768 / 32, 256 / 32), 256, 0, stream>>>(qkv_w + (size_t)l * 196608, qkvWT, 256, 768);
    transpose_kernel<<<dim3(256 / 32, 256 / 32), 256, 0, stream>>>(out_w + (size_t)l * 65536, outWT, 256, 256);
    transpose_kernel<<<dim3(1024 / 32, 256 / 32), 256, 0, stream>>>(ff_w1 + (size_t)l * 262144, ff1WT, 256, 1024);
    transpose_kernel<<<dim3(256 / 32, 1024 / 32), 256, 0, stream>>>(ff_w2 + (size_t)l * 262144, ff2WT, 1024, 256);
  }

  embed_kernel<<<ROWS_, 256, 0, stream>>>(ids, emb, X);

  for (int l = 0; l < 2; ++l) {
    float* qkvWT = WT + l * WSTRIDE;
    float* outWT = qkvWT + 196608;
    float* ff1WT = outWT + 65536;
    float* ff2WT = ff1WT + 262144;
    gemm_bt<128, 2, 2, 0, true, false><<<dim3(6, 128), 256, 0, stream>>>(
        X, qkvWT, qkv_b + l * 768, nullptr, BIG, ROWS_, 768, 256);
    attn_kernel<<<B_ * H_, 256, 0, stream>>>(BIG, CTX);
    gemm_bt<128, 2, 2, 0, true, false><<<dim3(2, 128), 256, 0, stream>>>(
        CTX, outWT, out_b + l * 256, nullptr, Y, ROWS_, 256, 256);
    addln_kernel<<<ROWS_, 256, 0, stream>>>(X, Y, ln1_s + l * 256, ln1_b + l * 256, X);
    gemm_bt<128, 2, 2, 1, true, false><<<dim3(8, 128), 256, 0, stream>>>(
        X, ff1WT, ff_b1 + l * 1024, nullptr, BIG, ROWS_, 1024, 256);
    gemm_bt<128, 2, 2, 0, true, false><<<dim3(2, 128), 256, 0, stream>>>(
        BIG, ff2WT, ff_b2 + l * 256, nullptr, Y, ROWS_, 256, 1024);
    addln_kernel<<<ROWS_, 256, 0, stream>>>(X, Y, ln2_s + l * 256, ln2_b + l * 256, X);
  }

  addln_kernel<<<ROWS_, 256, 0, stream>>>(X, nullptr, lnf_s, lnf_b, Y);
  pooled_kernel<<<B_, 256, 0, stream>>>(Y, mask, POOL);
  qnorm_kernel<<<B_, 256, 0, stream>>>(POOL, QN);
  invnorm_kernel<<<MEM_, 64, 0, stream>>>(mkeys, INVN);
  // sims[64, MEM] = QN @ keys^T, scaled by invn (keys already row-major [N][K])
  gemm_bt<64, 1, 4, 0, false, true><<<dim3((MEM_ + 255) / 256, 1), 256, 0, stream>>>(
      QN, mkeys, nullptr, INVN, BIG, 64, MEM_, 256);
  topk_stage1<<<B_ * NCHUNK_, 256, 0, stream>>>(BIG, topk, CANDK);
  topk_stage2<<<B_, 256, 0, stream>>>(CANDK, topk, TOPV, TOPI);
  retrieve_kernel<<<B_, 256, 0, stream>>>(TOPV, TOPI, topk, mvals, mconf, RETR);
  head_kernel<<<B_, 256, 0, stream>>>(POOL, RETR, gw1, gb1, gw2, gb2, cw, cb, out);
}

// Round 4
// 1073.166 us; speedup vs baseline: 7.5524x; 1.0133x over previous
//
#include <hip/hip_runtime.h>
#include <math.h>

// ---------------- constants ----------------
#define B_   64
#define S_   256
#define D_   256
#define H_   8
#define DH_  32
#define FF_  1024
#define MEM_ 200000
#define ROWS_ (B_ * S_)   // 16384
#define NCHUNK_ 64
#define CHUNK_  3125      // MEM_ / NCHUNK_
#define ELEMS_  13        // ceil(CHUNK_/256)

typedef float f32x4 __attribute__((ext_vector_type(4)));
typedef __bf16 bf16x8 __attribute__((ext_vector_type(8)));
typedef unsigned short ushort_t;

// ---------------- helpers ----------------
__device__ __forceinline__ float blockReduceSum256(float v, float* sh) {
  #pragma unroll
  for (int o = 32; o; o >>= 1) v += __shfl_down(v, o);
  int lane = threadIdx.x & 63, w = threadIdx.x >> 6;
  __syncthreads();
  if (lane == 0) sh[w] = v;
  __syncthreads();
  return sh[0] + sh[1] + sh[2] + sh[3];
}

__device__ __forceinline__ unsigned int f2key(float f) {
  unsigned int b = __float_as_uint(f);
  return (b & 0x80000000u) ? ~b : (b | 0x80000000u);
}
__device__ __forceinline__ float key2f(unsigned int u) {
  unsigned int b = (u & 0x80000000u) ? (u & 0x7FFFFFFFu) : ~u;
  return __uint_as_float(b);
}
__device__ __forceinline__ unsigned long long ullmax(unsigned long long a, unsigned long long b) {
  return a > b ? a : b;
}

__device__ __forceinline__ ushort_t f32_bf16_rn(float x) {
  unsigned int u = __float_as_uint(x);
  u += 0x7FFFu + ((u >> 16) & 1u);
  return (ushort_t)(u >> 16);
}
__device__ __forceinline__ float bf16_f32(ushort_t h) {
  return __uint_as_float((unsigned int)h << 16);
}
__device__ __forceinline__ void split_bf16(float v, ushort_t& h, ushort_t& l) {
  h = f32_bf16_rn(v);
  l = f32_bf16_rn(v - bf16_f32(h));
}

// swizzled byte offsets into a [R][32] bf16 LDS tile (row stride 64B, 4x16B granules,
// granule ^= (row>>1)&3 -> at most 2-way bank aliasing on ds_read_b128 frag reads)
__device__ __forceinline__ int swz8(int row, int kq) {   // 8B granule (4 bf16), kq = k/4
  return row * 64 + ((((kq >> 1) ^ ((row >> 1) & 3)) << 4)) + (kq & 1) * 8;
}
__device__ __forceinline__ int swz16(int row, int kg) {  // 16B granule (8 bf16), kg = k/8
  return row * 64 + (((kg ^ ((row >> 1) & 3)) << 4));
}

// direct global->LDS 16B copy (CK-style addrspace casts): LDS dest is
// wave-uniform base (+ lane*16 added by HW); global source is per-lane.
__device__ __forceinline__ void gload_lds16(const void* gsrc, void* ldst) {
  __builtin_amdgcn_global_load_lds(
      (const __attribute__((address_space(1))) unsigned int*)gsrc,
      (__attribute__((address_space(3))) unsigned int*)(unsigned int)(unsigned long long)ldst,
      16, 0, 0);
}

// stage a [128 x 32] bf16 tile (8KB) from a linear global [row][ldg] buffer into
// swizzled LDS. Inverse-swizzle is applied to the global SOURCE address; LDS dest
// stays linear per-lane (rule: both-sides-or-neither).
__device__ __forceinline__ void stage16(const ushort_t* __restrict__ G, int ldg,
                                        int base_row, int k0, char* lds, int t) {
  #pragma unroll
  for (int r = 0; r < 2; ++r) {
    int idx = r * 256 + t;                 // granule slot 0..511
    int row = idx >> 2, kg = idx & 3;
    int kg_g = kg ^ ((row >> 1) & 3);      // involution: source granule for this slot
    const void* src = G + (size_t)(base_row + row) * ldg + k0 + kg_g * 8;
    void* dst = lds + (size_t)(idx & ~63) * 16;  // wave-uniform base
    gload_lds16(src, dst);
  }
}

// legacy f32 staging (used only by the sims GEMM, whose B is single-use)
template<int NITER>
__device__ __forceinline__ void stage_bf16x3(const float* __restrict__ G, int ldg,
                                             int base_row, int k0, int max_row,
                                             char* __restrict__ sh, char* __restrict__ sl,
                                             int t) {
  #pragma unroll
  for (int r = 0; r < NITER; ++r) {
    int idx = r * 256 + t;
    int row = idx >> 3, kq = idx & 7;
    int gr = base_row + row; if (gr > max_row) gr = max_row;
    const float4 v = *reinterpret_cast<const float4*>(G + (size_t)gr * ldg + k0 + kq * 4);
    float vv[4] = {v.x, v.y, v.z, v.w};
    ushort_t h[4], l[4];
    #pragma unroll
    for (int j = 0; j < 4; ++j) split_bf16(vv[j], h[j], l[j]);
    uint2 hp = make_uint2((unsigned)h[0] | ((unsigned)h[1] << 16),
                          (unsigned)h[2] | ((unsigned)h[3] << 16));
    uint2 lp = make_uint2((unsigned)l[0] | ((unsigned)l[1] << 16),
                          (unsigned)l[2] | ((unsigned)l[3] << 16));
    int b8 = swz8(row, kq);
    *reinterpret_cast<uint2*>(sh + b8) = hp;
    *reinterpret_cast<uint2*>(sl + b8) = lp;
  }
}

// ---------------- bf16x3 MFMA GEMM on pre-split hi/lo inputs ----------------
// A[M,K] as AH/AL, B^T[N,K] as BH/BL. 128x128 tile, 4 waves, K_STEP=32.
// OUTMODE 0: C f32. OUTMODE 1: CH/CL bf16 pair only.
template<int ACT, bool HAS_BIAS, int OUTMODE>
__global__ __launch_bounds__(256) void gemm16(const ushort_t* __restrict__ AH,
                                              const ushort_t* __restrict__ AL,
                                              const ushort_t* __restrict__ BH,
                                              const ushort_t* __restrict__ BL,
                                              const float* __restrict__ bias,
                                              float* __restrict__ C,
                                              ushort_t* __restrict__ CH,
                                              ushort_t* __restrict__ CL,
                                              int M, int N, int K) {
  __shared__ __align__(16) char sAh[128 * 64];
  __shared__ __align__(16) char sAl[128 * 64];
  __shared__ __align__(16) char sBh[128 * 64];
  __shared__ __align__(16) char sBl[128 * 64];
  int t = threadIdx.x;
  int m0 = blockIdx.y * 128, n0 = blockIdx.x * 128;
  int wid = t >> 6, lane = t & 63;
  int wr = wid >> 1, wc = wid & 1;
  int lr = lane & 15, kg = lane >> 4;
  f32x4 acc[4][4] = {};
  for (int k0 = 0; k0 < K; k0 += 32) {
    stage16(AH, K, m0, k0, sAh, t);
    stage16(AL, K, m0, k0, sAl, t);
    stage16(BH, K, n0, k0, sBh, t);
    stage16(BL, K, n0, k0, sBl, t);
    __syncthreads();   // compiler emits vmcnt(0) drain for the global_load_lds queue
    bf16x8 ah[4], al[4];
    #pragma unroll
    for (int mi = 0; mi < 4; ++mi) {
      int row = wr * 64 + mi * 16 + lr;
      int ab = swz16(row, kg);
      ah[mi] = *reinterpret_cast<const bf16x8*>(sAh + ab);
      al[mi] = *reinterpret_cast<const bf16x8*>(sAl + ab);
    }
    #pragma unroll
    for (int ni = 0; ni < 4; ++ni) {
      int rb = wc * 64 + ni * 16 + lr;
      int bb = swz16(rb, kg);
      bf16x8 bh = *reinterpret_cast<const bf16x8*>(sBh + bb);
      bf16x8 bl = *reinterpret_cast<const bf16x8*>(sBl + bb);
      #pragma unroll
      for (int mi = 0; mi < 4; ++mi) {
        acc[mi][ni] = __builtin_amdgcn_mfma_f32_16x16x32_bf16(ah[mi], bh, acc[mi][ni], 0, 0, 0);
        acc[mi][ni] = __builtin_amdgcn_mfma_f32_16x16x32_bf16(al[mi], bh, acc[mi][ni], 0, 0, 0);
        acc[mi][ni] = __builtin_amdgcn_mfma_f32_16x16x32_bf16(ah[mi], bl, acc[mi][ni], 0, 0, 0);
      }
    }
    __syncthreads();
  }
  #pragma unroll
  for (int mi = 0; mi < 4; ++mi) {
    #pragma unroll
    for (int ni = 0; ni < 4; ++ni) {
      int row0 = m0 + wr * 64 + mi * 16 + kg * 4;
      int col  = n0 + wc * 64 + ni * 16 + lr;
      float b = HAS_BIAS ? bias[col] : 0.0f;
      #pragma unroll
      for (int i = 0; i < 4; ++i) {
        float v = acc[mi][ni][i] + b;
        if (ACT == 1) v = 0.5f * v * (1.0f + erff(v * 0.7071067811865476f));
        size_t o = (size_t)(row0 + i) * N + col;
        if (OUTMODE == 0) {
          C[o] = v;
        } else {
          ushort_t h, l;
          split_bf16(v, h, l);
          CH[o] = h; CL[o] = l;
        }
      }
    }
  }
}

// ---------------- legacy bf16x3 GEMM with in-kernel f32 conversion (sims only) ----------------
template<int BROWS, int WM, int WN, int ACT, bool HAS_BIAS, bool HAS_SCALE>
__global__ __launch_bounds__(256) void gemm_bt(const float* __restrict__ A,
                                               const float* __restrict__ BT,
                                               const float* __restrict__ bias,
                                               const float* __restrict__ scl,
                                               float* __restrict__ C,
                                               int M, int N, int K) {
  constexpr int BCOLS = WN * 64;
  __shared__ __align__(16) char sAh[BROWS * 64];
  __shared__ __align__(16) char sAl[BROWS * 64];
  __shared__ __align__(16) char sBh[BCOLS * 64];
  __shared__ __align__(16) char sBl[BCOLS * 64];
  int t = threadIdx.x;
  int m0 = blockIdx.y * BROWS, n0 = blockIdx.x * BCOLS;
  int wid = t >> 6, lane = t & 63;
  int wr = wid / WN, wc = wid % WN;
  int lr = lane & 15, kg = lane >> 4;
  f32x4 acc[4][4] = {};
  for (int k0 = 0; k0 < K; k0 += 32) {
    stage_bf16x3<BROWS / 32>(A, K, m0, k0, M - 1, sAh, sAl, t);
    stage_bf16x3<BCOLS / 32>(BT, K, n0, k0, N - 1, sBh, sBl, t);
    __syncthreads();
    bf16x8 ah[4], al[4];
    #pragma unroll
    for (int mi = 0; mi < 4; ++mi) {
      int row = wr * 64 + mi * 16 + lr;
      int ab = swz16(row, kg);
      ah[mi] = *reinterpret_cast<const bf16x8*>(sAh + ab);
      al[mi] = *reinterpret_cast<const bf16x8*>(sAl + ab);
    }
    #pragma unroll
    for (int ni = 0; ni < 4; ++ni) {
      int rb = wc * 64 + ni * 16 + lr;
      int bb = swz16(rb, kg);
      bf16x8 bh = *reinterpret_cast<const bf16x8*>(sBh + bb);
      bf16x8 bl = *reinterpret_cast<const bf16x8*>(sBl + bb);
      #pragma unroll
      for (int mi = 0; mi < 4; ++mi) {
        acc[mi][ni] = __builtin_amdgcn_mfma_f32_16x16x32_bf16(ah[mi], bh, acc[mi][ni], 0, 0, 0);
        acc[mi][ni] = __builtin_amdgcn_mfma_f32_16x16x32_bf16(al[mi], bh, acc[mi][ni], 0, 0, 0);
        acc[mi][ni] = __builtin_amdgcn_mfma_f32_16x16x32_bf16(ah[mi], bl, acc[mi][ni], 0, 0, 0);
      }
    }
    __syncthreads();
  }
  #pragma unroll
  for (int mi = 0; mi < 4; ++mi) {
    #pragma unroll
    for (int ni = 0; ni < 4; ++ni) {
      int row0 = m0 + wr * 64 + mi * 16 + kg * 4;
      int col  = n0 + wc * 64 + ni * 16 + lr;
      if (col < N) {
        float b = HAS_BIAS ? bias[col] : 0.0f;
        float s = HAS_SCALE ? scl[col] : 1.0f;
        #pragma unroll
        for (int i = 0; i < 4; ++i) {
          float v = acc[mi][ni][i];
          if (HAS_SCALE) v *= s;
          if (HAS_BIAS) v += b;
          if (ACT == 1) v = 0.5f * v * (1.0f + erff(v * 0.7071067811865476f));
          C[(size_t)(row0 + i) * N + col] = v;
        }
      }
    }
  }
}

// ---------------- weight transpose + bf16 hi/lo split: dst[c][r] = split(src[r][c]) ----------------
__global__ __launch_bounds__(256) void transcvt_kernel(const float* __restrict__ src,
                                                       ushort_t* __restrict__ dh,
                                                       ushort_t* __restrict__ dl,
                                                       int R, int C) {
  __shared__ float tile[32][33];
  int c0 = blockIdx.x * 32, r0 = blockIdx.y * 32;
  int x = threadIdx.x & 31, y4 = (threadIdx.x >> 5) * 4;
  #pragma unroll
  for (int i = 0; i < 4; ++i) {
    tile[y4 + i][x] = src[(size_t)(r0 + y4 + i) * C + c0 + x];
  }
  __syncthreads();
  #pragma unroll
  for (int i = 0; i < 4; ++i) {
    float v = tile[x][y4 + i];
    ushort_t h, l;
    split_bf16(v, h, l);
    size_t o = (size_t)(c0 + y4 + i) * R + r0 + x;
    dh[o] = h; dl[o] = l;
  }
}

// ---------------- embedding + positional encoding (f32 + bf16 pair outputs) ----------------
__global__ __launch_bounds__(256) void embed_kernel(const int* __restrict__ ids,
                                                    const float* __restrict__ emb,
                                                    float* __restrict__ x,
                                                    ushort_t* __restrict__ xh,
                                                    ushort_t* __restrict__ xl) {
  int row = blockIdx.x;
  int d = threadIdx.x;
  int s = row & (S_ - 1);
  int tok = ids[row];
  int d2 = d & ~1;
  float div = expf((float)d2 * (-9.210340371976184f / 256.0f));
  float ang = (float)s * div;
  float pe = (d & 1) ? cosf(ang) : sinf(ang);
  float v = emb[(size_t)tok * D_ + d] * 16.0f + pe;
  size_t o = (size_t)row * D_ + d;
  x[o] = v;
  ushort_t h, l;
  split_bf16(v, h, l);
  xh[o] = h; xl[o] = l;
}

// ---------------- fused attention (flash-style, fp32, skip-rescale; bf16-pair output) ----------------
__global__ __launch_bounds__(256) void attn_kernel(const float* __restrict__ qkv,
                                                   ushort_t* __restrict__ ctxh,
                                                   ushort_t* __restrict__ ctxl) {
  __shared__ float Ks[S_][DH_];
  __shared__ float Vs[S_][DH_];
  int bh = blockIdx.x;
  int b = bh >> 3, h = bh & 7;
  int t = threadIdx.x;
  const float* base = qkv + (size_t)(b * S_) * 768;
  for (int idx = t; idx < S_ * DH_; idx += 256) {
    int s = idx >> 5, i = idx & 31;
    Ks[s][i] = base[(size_t)s * 768 + 256 + h * 32 + i];
    Vs[s][i] = base[(size_t)s * 768 + 512 + h * 32 + i];
  }
  float q[DH_];
  {
    const float* qp = base + (size_t)t * 768 + h * 32;
    #pragma unroll
    for (int i = 0; i < DH_; ++i) q[i] = qp[i] * 0.17677669529663687f;  // 1/sqrt(32)
  }
  __syncthreads();
  float m = -1e30f, l = 0.0f, acc[DH_];
  #pragma unroll
  for (int i = 0; i < DH_; ++i) acc[i] = 0.0f;
  for (int k = 0; k < S_; ++k) {
    float sc = 0.0f;
    #pragma unroll
    for (int i = 0; i < DH_; ++i) sc += q[i] * Ks[k][i];
    if (sc > m) {
      float scale = expf(m - sc);
      l = l * scale + 1.0f;
      #pragma unroll
      for (int i = 0; i < DH_; ++i) acc[i] = acc[i] * scale + Vs[k][i];
      m = sc;
    } else {
      float p = expf(sc - m);
      l += p;
      #pragma unroll
      for (int i = 0; i < DH_; ++i) acc[i] += p * Vs[k][i];
    }
  }
  float inv = 1.0f / l;
  size_t cp = (size_t)(b * S_ + t) * D_ + h * 32;
  #pragma unroll
  for (int i = 0; i < DH_; ++i) {
    float v = acc[i] * inv;
    ushort_t hh, ll;
    split_bf16(v, hh, ll);
    ctxh[cp + i] = hh; ctxl[cp + i] = ll;
  }
}

// ---------------- residual add + layernorm (y may be null; optional bf16 pair out) ----------------
template<bool PAIRS>
__global__ __launch_bounds__(256) void addln_kernel(const float* __restrict__ x,
                                                    const float* __restrict__ y,
                                                    const float* __restrict__ gam,
                                                    const float* __restrict__ bet,
                                                    float* __restrict__ out,
                                                    ushort_t* __restrict__ oh,
                                                    ushort_t* __restrict__ ol) {
  __shared__ float sh[8];
  int row = blockIdx.x, d = threadIdx.x;
  float v = x[(size_t)row * D_ + d];
  if (y) v += y[(size_t)row * D_ + d];
  float mean = blockReduceSum256(v, sh) * (1.0f / D_);
  float diff = v - mean;
  float var = blockReduceSum256(diff * diff, sh) * (1.0f / D_);
  float r = diff * rsqrtf(var + 1e-5f) * gam[d] + bet[d];
  size_t o = (size_t)row * D_ + d;
  out[o] = r;
  if (PAIRS) {
    ushort_t h, l;
    split_bf16(r, h, l);
    oh[o] = h; ol[o] = l;
  }
}

// ---------------- masked mean pool ----------------
__global__ __launch_bounds__(256) void pooled_kernel(const float* __restrict__ hidden,
                                                     const float* __restrict__ mask,
                                                     float* __restrict__ pooled) {
  int b = blockIdx.x, d = threadIdx.x;
  float s = 0.0f, msum = 0.0f;
  for (int t = 0; t < S_; ++t) {
    float mk = mask[b * S_ + t];
    s += hidden[(size_t)(b * S_ + t) * D_ + d] * mk;
    msum += mk;
  }
  pooled[b * D_ + d] = s / (msum + 1e-8f);
}

// ---------------- normalize pooled queries ----------------
__global__ __launch_bounds__(256) void qnorm_kernel(const float* __restrict__ pooled,
                                                    float* __restrict__ qn) {
  __shared__ float sh[8];
  int b = blockIdx.x, d = threadIdx.x;
  float v = pooled[b * D_ + d];
  float ss = blockReduceSum256(v * v, sh);
  qn[b * D_ + d] = v / fmaxf(sqrtf(ss), 1e-8f);
}

// ---------------- per-key inverse norms ----------------
__global__ __launch_bounds__(64) void invnorm_kernel(const float* __restrict__ keys,
                                                     float* __restrict__ invn) {
  int row = blockIdx.x, t = threadIdx.x;
  float4 v = *reinterpret_cast<const float4*>(keys + (size_t)row * D_ + t * 4);
  float ss = v.x * v.x + v.y * v.y + v.z * v.z + v.w * v.w;
  #pragma unroll
  for (int o = 32; o; o >>= 1) ss += __shfl_down(ss, o);
  if (t == 0) invn[row] = 1.0f / fmaxf(sqrtf(ss), 1e-8f);
}

// ---------------- top-k stage 1: register-cached iterative argmax ----------------
// Each thread keeps its ~13 chunk elements in registers plus a cached local max.
// Per extraction: block-reduce cached maxima; only the winner rescans its registers.
__global__ __launch_bounds__(256) void topk_stage1(const float* __restrict__ sims,
                                                   const int* __restrict__ topk,
                                                   unsigned long long* __restrict__ candk) {
  __shared__ unsigned long long wk[4];
  int row = blockIdx.x >> 6, chunk = blockIdx.x & 63;
  int t = threadIdx.x;
  int k = *topk; if (k > 64) k = 64; if (k < 1) k = 1;
  const float* src = sims + (size_t)row * MEM_ + (size_t)chunk * CHUNK_;
  int gbase = chunk * CHUNK_;
  unsigned long long e[ELEMS_];
  #pragma unroll
  for (int r = 0; r < ELEMS_; ++r) {
    int i = r * 256 + t;
    e[r] = (i < CHUNK_)
        ? (((unsigned long long)f2key(src[i]) << 32) | (unsigned int)~(unsigned int)(gbase + i))
        : 0ull;
  }
  unsigned long long mloc = 0ull;
  #pragma unroll
  for (int r = 0; r < ELEMS_; ++r) mloc = ullmax(mloc, e[r]);
  int lane = t & 63, w = t >> 6;
  for (int iter = 0; iter < k; ++iter) {
    unsigned long long m = mloc;
    #pragma unroll
    for (int o = 32; o; o >>= 1) m = ullmax(m, __shfl_xor(m, o));  // all-lanes wave max
    if (lane == 0) wk[w] = m;
    __syncthreads();
    unsigned long long best = ullmax(ullmax(wk[0], wk[1]), ullmax(wk[2], wk[3]));
    if (t == 0) candk[(size_t)blockIdx.x * 64 + iter] = best;
    if (mloc == best) {           // exactly one thread (keys unique by index bits)
      #pragma unroll
      for (int r = 0; r < ELEMS_; ++r) if (e[r] == best) e[r] = 0ull;
      mloc = 0ull;
      #pragma unroll
      for (int r = 0; r < ELEMS_; ++r) mloc = ullmax(mloc, e[r]);
    }
    __syncthreads();              // protect wk before next iteration
  }
}

// ---------------- top-k stage 2: reduce NCHUNK_*k candidates per row ----------------
__global__ __launch_bounds__(256) void topk_stage2(const unsigned long long* __restrict__ candk,
                                                   const int* __restrict__ topk,
                                                   float* __restrict__ topv,
                                                   int* __restrict__ topi) {
  __shared__ unsigned long long buf[NCHUNK_ * 64];
  __shared__ unsigned long long wk[4];
  int row = blockIdx.x, t = threadIdx.x;
  int k = *topk; if (k > 64) k = 64; if (k < 1) k = 1;
  int ncand = NCHUNK_ * k;
  const unsigned long long* src = candk + (size_t)row * NCHUNK_ * 64;
  for (int i = t; i < ncand; i += 256) {
    int chunk = i / k, iter = i - chunk * k;
    buf[i] = src[chunk * 64 + iter];
  }
  __syncthreads();
  int lane = t & 63, w = t >> 6;
  for (int iter = 0; iter < k; ++iter) {
    unsigned long long best = 0ull;
    for (int i = t; i < ncand; i += 256) best = ullmax(best, buf[i]);
    #pragma unroll
    for (int o = 32; o; o >>= 1) best = ullmax(best, __shfl_down(best, o));
    if (lane == 0) wk[w] = best;
    __syncthreads();
    best = ullmax(ullmax(wk[0], wk[1]), ullmax(wk[2], wk[3]));
    if (t == 0) {
      topv[row * 64 + iter] = key2f((unsigned int)(best >> 32));
      topi[row * 64 + iter] = (int)~(unsigned int)best;
    }
    for (int i = t; i < ncand; i += 256) if (buf[i] == best) buf[i] = 0ull;
    __syncthreads();
  }
}

// ---------------- weighted aggregate of retrieved values ----------------
__global__ __launch_bounds__(256) void retrieve_kernel(const float* __restrict__ topv,
                                                       const int* __restrict__ topi,
                                                       const int* __restrict__ topk,
                                                       const float* __restrict__ vals,
                                                       const float* __restrict__ conf,
                                                       float* __restrict__ retr) {
  int b = blockIdx.x, d = threadIdx.x;
  int k = *topk; if (k > 64) k = 64; if (k < 1) k = 1;
  float acc = 0.0f, wsum = 0.0f;
  for (int i = 0; i < k; ++i) {
    int idx = topi[b * 64 + i];
    float w = fmaxf(conf[idx], 1e-4f) * topv[b * 64 + i];
    wsum += w;
    acc += w * vals[(size_t)idx * D_ + d];
  }
  retr[b * D_ + d] = acc / (wsum + 1e-8f);
}

// ---------------- gate MLP + fuse + classifier ----------------
__global__ __launch_bounds__(256) void head_kernel(const float* __restrict__ pooled,
                                                   const float* __restrict__ retr,
                                                   const float* __restrict__ gw1,
                                                   const float* __restrict__ gb1,
                                                   const float* __restrict__ gw2,
                                                   const float* __restrict__ gb2,
                                                   const float* __restrict__ cw,
                                                   const float* __restrict__ cb,
                                                   float* __restrict__ out) {
  __shared__ float pl[D_], hh[D_], fu[D_], sh[8];
  int b = blockIdx.x, d = threadIdx.x;
  pl[d] = pooled[b * D_ + d];
  __syncthreads();
  float a = gb1[d];
  for (int e = 0; e < D_; ++e) a += pl[e] * gw1[e * D_ + d];
  hh[d] = fmaxf(a, 0.0f);
  float gsum = blockReduceSum256(hh[d] * gw2[d], sh);
  float g = 1.0f / (1.0f + expf(-(gsum + gb2[0])));
  fu[d] = g * retr[b * D_ + d] + (1.0f - g) * pl[d];
  __syncthreads();
  if (d < 16) {
    float o = cb[d];
    for (int e = 0; e < D_; ++e) o += fu[e] * cw[e * 16 + d];
    out[b * 16 + d] = o;
  }
}

// ---------------- launcher ----------------
extern "C" void kernel_launch(void* const* d_in, const int* in_sizes, int n_in,
                              void* d_out, int out_size, void* d_ws, size_t ws_size,
                              hipStream_t stream) {
  const int*   ids   = (const int*)d_in[0];
  const float* mask  = (const float*)d_in[1];
  const int*   topk  = (const int*)d_in[2];
  const float* emb   = (const float*)d_in[3];
  const float* qkv_w = (const float*)d_in[4];
  const float* qkv_b = (const float*)d_in[5];
  const float* out_w = (const float*)d_in[6];
  const float* out_b = (const float*)d_in[7];
  const float* ln1_s = (const float*)d_in[8];
  const float* ln1_b = (const float*)d_in[9];
  const float* ff_w1 = (const float*)d_in[10];
  const float* ff_b1 = (const float*)d_in[11];
  const float* ff_w2 = (const float*)d_in[12];
  const float* ff_b2 = (const float*)d_in[13];
  const float* ln2_s = (const float*)d_in[14];
  const float* ln2_b = (const float*)d_in[15];
  const float* lnf_s = (const float*)d_in[16];
  const float* lnf_b = (const float*)d_in[17];
  const float* gw1   = (const float*)d_in[18];
  const float* gb1   = (const float*)d_in[19];
  const float* gw2   = (const float*)d_in[20];
  const float* gb2   = (const float*)d_in[21];
  const float* cw    = (const float*)d_in[22];
  const float* cb    = (const float*)d_in[23];
  const float* mkeys = (const float*)d_in[24];
  const float* mvals = (const float*)d_in[25];
  const float* mconf = (const float*)d_in[26];
  float* out = (float*)d_out;

  // ---- workspace layout (f32 slots; ~143.6 MB total) ----
  float* ws   = (float*)d_ws;
  float* X    = ws;                                   //  4,194,304 f
  float* Y    = X + 4194304;                          //  4,194,304 f
  float* R    = Y + 4194304;                          // 16,777,216 f (qkv f32 / ff1 pairs / sims)
  ushort_t* XH   = (ushort_t*)(R + 16777216);         //  4,194,304 sh
  ushort_t* XL   = XH + 4194304;
  ushort_t* CTXH = XL + 4194304;
  ushort_t* CTXL = CTXH + 4194304;
  ushort_t* WP   = CTXL + 4194304;                    //  3,145,728 sh (weight pairs)
  float* POOL = (float*)(WP + 3145728);               //  16384 f
  float* QN   = POOL + 16384;
  float* INVN = QN + 16384;                           //  200,000 f
  float* TOPV = INVN + 200000;                        //  4096 f
  int*   TOPI = (int*)(TOPV + 4096);
  float* RETR = (float*)(TOPI + 4096);                //  16384 f
  unsigned long long* CANDK = (unsigned long long*)(RETR + 16384);  // 262,144 u64

  // aliases over R (lifetimes disjoint)
  float*    QKVOUT = R;                  // [16384][768] f32
  ushort_t* BIGH   = (ushort_t*)R;       // [16384][1024] bf16 hi
  ushort_t* BIGL   = BIGH + 16777216;    // [16384][1024] bf16 lo
  float*    SIMS   = R;                  // [64][200000] f32

  // per-layer weight-pair offsets (shorts)
  const size_t LW = 1572864;
  // [qkvH qkvL outH outL ff1H ff1L ff2H ff2L]
  #define WPTR(l, off) (WP + (size_t)(l) * LW + (off))

  // ---- weight prep: transpose + bf16 hi/lo split (once) ----
  for (int l = 0; l < 2; ++l) {
    transcvt_kernel<<<dim3(24, 8), 256, 0, stream>>>(qkv_w + (size_t)l * 196608,
                                                     WPTR(l, 0), WPTR(l, 196608), 256, 768);
    transcvt_kernel<<<dim3(8, 8), 256, 0, stream>>>(out_w + (size_t)l * 65536,
                                                    WPTR(l, 393216), WPTR(l, 458752), 256, 256);
    transcvt_kernel<<<dim3(32, 8), 256, 0, stream>>>(ff_w1 + (size_t)l * 262144,
                                                     WPTR(l, 524288), WPTR(l, 786432), 256, 1024);
    transcvt_kernel<<<dim3(8, 32), 256, 0, stream>>>(ff_w2 + (size_t)l * 262144,
                                                     WPTR(l, 1048576), WPTR(l, 1310720), 1024, 256);
  }

  embed_kernel<<<ROWS_, 256, 0, stream>>>(ids, emb, X, XH, XL);

  for (int l = 0; l < 2; ++l) {
    gemm16<0, true, 0><<<dim3(6, 128), 256, 0, stream>>>(
        XH, XL, WPTR(l, 0), WPTR(l, 196608), qkv_b + l * 768,
        QKVOUT, nullptr, nullptr, ROWS_, 768, 256);
    attn_kernel<<<B_ * H_, 256, 0, stream>>>(QKVOUT, CTXH, CTXL);
    gemm16<0, true, 0><<<dim3(2, 128), 256, 0, stream>>>(
        CTXH, CTXL, WPTR(l, 393216), WPTR(l, 458752), out_b + l * 256,
        Y, nullptr, nullptr, ROWS_, 256, 256);
    addln_kernel<true><<<ROWS_, 256, 0, stream>>>(X, Y, ln1_s + l * 256, ln1_b + l * 256,
                                                  X, XH, XL);
    gemm16<1, true, 1><<<dim3(8, 128), 256, 0, stream>>>(
        XH, XL, WPTR(l, 524288), WPTR(l, 786432), ff_b1 + l * 1024,
        nullptr, BIGH, BIGL, ROWS_, 1024, 256);
    gemm16<0, true, 0><<<dim3(2, 128), 256, 0, stream>>>(
        BIGH, BIGL, WPTR(l, 1048576), WPTR(l, 1310720), ff_b2 + l * 256,
        Y, nullptr, nullptr, ROWS_, 256, 1024);
    addln_kernel<true><<<ROWS_, 256, 0, stream>>>(X, Y, ln2_s + l * 256, ln2_b + l * 256,
                                                  X, XH, XL);
  }

  addln_kernel<false><<<ROWS_, 256, 0, stream>>>(X, nullptr, lnf_s, lnf_b, Y, nullptr, nullptr);
  pooled_kernel<<<B_, 256, 0, stream>>>(Y, mask, POOL);
  qnorm_kernel<<<B_, 256, 0, stream>>>(POOL, QN);
  invnorm_kernel<<<MEM_, 64, 0, stream>>>(mkeys, INVN);
  gemm_bt<64, 1, 4, 0, false, true><<<dim3((MEM_ + 255) / 256, 1), 256, 0, stream>>>(
      QN, mkeys, nullptr, INVN, SIMS, 64, MEM_, 256);
  topk_stage1<<<B_ * NCHUNK_, 256, 0, stream>>>(SIMS, topk, CANDK);
  topk_stage2<<<B_, 256, 0, stream>>>(CANDK, topk, TOPV, TOPI);
  retrieve_kernel<<<B_, 256, 0, stream>>>(TOPV, TOPI, topk, mvals, mconf, RETR);
  head_kernel<<<B_, 256, 0, stream>>>(POOL, RETR, gw1, gb1, gw2, gb2, cw, cb, out);
  #undef WPTR
}

// Round 5
// 1014.757 us; speedup vs baseline: 7.9871x; 1.0576x over previous
//
#include <hip/hip_runtime.h>
#include <math.h>

// ---------------- constants ----------------
#define B_   64
#define S_   256
#define D_   256
#define H_   8
#define DH_  32
#define FF_  1024
#define MEM_ 200000
#define ROWS_ (B_ * S_)   // 16384
#define NCHA_ 128         // chunks per row for threshold top-k
#define CHA_  1563        // ceil(MEM_/NCHA_)
#define CAP_  2048        // candidate cap per row

typedef float f32x4 __attribute__((ext_vector_type(4)));
typedef __bf16 bf16x8 __attribute__((ext_vector_type(8)));
typedef unsigned short ushort_t;

// ---------------- helpers ----------------
__device__ __forceinline__ float blockReduceSum256(float v, float* sh) {
  #pragma unroll
  for (int o = 32; o; o >>= 1) v += __shfl_down(v, o);
  int lane = threadIdx.x & 63, w = threadIdx.x >> 6;
  __syncthreads();
  if (lane == 0) sh[w] = v;
  __syncthreads();
  return sh[0] + sh[1] + sh[2] + sh[3];
}

__device__ __forceinline__ unsigned int f2key(float f) {
  unsigned int b = __float_as_uint(f);
  return (b & 0x80000000u) ? ~b : (b | 0x80000000u);
}
__device__ __forceinline__ float key2f(unsigned int u) {
  unsigned int b = (u & 0x80000000u) ? (u & 0x7FFFFFFFu) : ~u;
  return __uint_as_float(b);
}
__device__ __forceinline__ unsigned long long ullmax(unsigned long long a, unsigned long long b) {
  return a > b ? a : b;
}

__device__ __forceinline__ ushort_t f32_bf16_rn(float x) {
  unsigned int u = __float_as_uint(x);
  u += 0x7FFFu + ((u >> 16) & 1u);
  return (ushort_t)(u >> 16);
}
__device__ __forceinline__ float bf16_f32(ushort_t h) {
  return __uint_as_float((unsigned int)h << 16);
}
__device__ __forceinline__ void split_bf16(float v, ushort_t& h, ushort_t& l) {
  h = f32_bf16_rn(v);
  l = f32_bf16_rn(v - bf16_f32(h));
}

// swizzled byte offsets into a [R][32] bf16 LDS tile (row stride 64B, 4x16B granules,
// granule ^= (row>>1)&3 -> at most 2-way bank aliasing on ds_read_b128 frag reads)
__device__ __forceinline__ int swz8(int row, int kq) {   // 8B granule (4 bf16), kq = k/4
  return row * 64 + ((((kq >> 1) ^ ((row >> 1) & 3)) << 4)) + (kq & 1) * 8;
}
__device__ __forceinline__ int swz16(int row, int kg) {  // 16B granule (8 bf16), kg = k/8
  return row * 64 + (((kg ^ ((row >> 1) & 3)) << 4));
}

// direct global->LDS 16B copy (CK-style addrspace casts): LDS dest is
// wave-uniform base (+ lane*16 added by HW); global source is per-lane.
__device__ __forceinline__ void gload_lds16(const void* gsrc, void* ldst) {
  __builtin_amdgcn_global_load_lds(
      (const __attribute__((address_space(1))) unsigned int*)gsrc,
      (__attribute__((address_space(3))) unsigned int*)(unsigned int)(unsigned long long)ldst,
      16, 0, 0);
}

// stage a [128 x 32] bf16 tile (8KB) from a linear global [row][ldg] buffer into
// swizzled LDS. Inverse-swizzle applied to the global SOURCE; LDS dest linear.
__device__ __forceinline__ void stage16(const ushort_t* __restrict__ G, int ldg,
                                        int base_row, int k0, char* lds, int t) {
  #pragma unroll
  for (int r = 0; r < 2; ++r) {
    int idx = r * 256 + t;                 // granule slot 0..511
    int row = idx >> 2, kg = idx & 3;
    int kg_g = kg ^ ((row >> 1) & 3);      // involution: source granule for this slot
    const void* src = G + (size_t)(base_row + row) * ldg + k0 + kg_g * 8;
    void* dst = lds + (size_t)(idx & ~63) * 16;  // wave-uniform base
    gload_lds16(src, dst);
  }
}

// legacy f32 staging (used only by the sims GEMM, whose B is single-use)
template<int NITER>
__device__ __forceinline__ void stage_bf16x3(const float* __restrict__ G, int ldg,
                                             int base_row, int k0, int max_row,
                                             char* __restrict__ sh, char* __restrict__ sl,
                                             int t) {
  #pragma unroll
  for (int r = 0; r < NITER; ++r) {
    int idx = r * 256 + t;
    int row = idx >> 3, kq = idx & 7;
    int gr = base_row + row; if (gr > max_row) gr = max_row;
    const float4 v = *reinterpret_cast<const float4*>(G + (size_t)gr * ldg + k0 + kq * 4);
    float vv[4] = {v.x, v.y, v.z, v.w};
    ushort_t h[4], l[4];
    #pragma unroll
    for (int j = 0; j < 4; ++j) split_bf16(vv[j], h[j], l[j]);
    uint2 hp = make_uint2((unsigned)h[0] | ((unsigned)h[1] << 16),
                          (unsigned)h[2] | ((unsigned)h[3] << 16));
    uint2 lp = make_uint2((unsigned)l[0] | ((unsigned)l[1] << 16),
                          (unsigned)l[2] | ((unsigned)l[3] << 16));
    int b8 = swz8(row, kq);
    *reinterpret_cast<uint2*>(sh + b8) = hp;
    *reinterpret_cast<uint2*>(sl + b8) = lp;
  }
}

// ---------------- bf16x3 MFMA GEMM on pre-split hi/lo inputs ----------------
template<int ACT, bool HAS_BIAS, int OUTMODE>
__global__ __launch_bounds__(256) void gemm16(const ushort_t* __restrict__ AH,
                                              const ushort_t* __restrict__ AL,
                                              const ushort_t* __restrict__ BH,
                                              const ushort_t* __restrict__ BL,
                                              const float* __restrict__ bias,
                                              float* __restrict__ C,
                                              ushort_t* __restrict__ CH,
                                              ushort_t* __restrict__ CL,
                                              int M, int N, int K) {
  __shared__ __align__(16) char sAh[128 * 64];
  __shared__ __align__(16) char sAl[128 * 64];
  __shared__ __align__(16) char sBh[128 * 64];
  __shared__ __align__(16) char sBl[128 * 64];
  int t = threadIdx.x;
  int m0 = blockIdx.y * 128, n0 = blockIdx.x * 128;
  int wid = t >> 6, lane = t & 63;
  int wr = wid >> 1, wc = wid & 1;
  int lr = lane & 15, kg = lane >> 4;
  f32x4 acc[4][4] = {};
  for (int k0 = 0; k0 < K; k0 += 32) {
    stage16(AH, K, m0, k0, sAh, t);
    stage16(AL, K, m0, k0, sAl, t);
    stage16(BH, K, n0, k0, sBh, t);
    stage16(BL, K, n0, k0, sBl, t);
    __syncthreads();
    bf16x8 ah[4], al[4];
    #pragma unroll
    for (int mi = 0; mi < 4; ++mi) {
      int row = wr * 64 + mi * 16 + lr;
      int ab = swz16(row, kg);
      ah[mi] = *reinterpret_cast<const bf16x8*>(sAh + ab);
      al[mi] = *reinterpret_cast<const bf16x8*>(sAl + ab);
    }
    #pragma unroll
    for (int ni = 0; ni < 4; ++ni) {
      int rb = wc * 64 + ni * 16 + lr;
      int bb = swz16(rb, kg);
      bf16x8 bh = *reinterpret_cast<const bf16x8*>(sBh + bb);
      bf16x8 bl = *reinterpret_cast<const bf16x8*>(sBl + bb);
      #pragma unroll
      for (int mi = 0; mi < 4; ++mi) {
        acc[mi][ni] = __builtin_amdgcn_mfma_f32_16x16x32_bf16(ah[mi], bh, acc[mi][ni], 0, 0, 0);
        acc[mi][ni] = __builtin_amdgcn_mfma_f32_16x16x32_bf16(al[mi], bh, acc[mi][ni], 0, 0, 0);
        acc[mi][ni] = __builtin_amdgcn_mfma_f32_16x16x32_bf16(ah[mi], bl, acc[mi][ni], 0, 0, 0);
      }
    }
    __syncthreads();
  }
  #pragma unroll
  for (int mi = 0; mi < 4; ++mi) {
    #pragma unroll
    for (int ni = 0; ni < 4; ++ni) {
      int row0 = m0 + wr * 64 + mi * 16 + kg * 4;
      int col  = n0 + wc * 64 + ni * 16 + lr;
      float b = HAS_BIAS ? bias[col] : 0.0f;
      #pragma unroll
      for (int i = 0; i < 4; ++i) {
        float v = acc[mi][ni][i] + b;
        if (ACT == 1) v = 0.5f * v * (1.0f + erff(v * 0.7071067811865476f));
        size_t o = (size_t)(row0 + i) * N + col;
        if (OUTMODE == 0) {
          C[o] = v;
        } else {
          ushort_t h, l;
          split_bf16(v, h, l);
          CH[o] = h; CL[o] = l;
        }
      }
    }
  }
}

// ---------------- legacy bf16x3 GEMM with in-kernel f32 conversion (sims only) ----------------
template<int BROWS, int WM, int WN, int ACT, bool HAS_BIAS, bool HAS_SCALE>
__global__ __launch_bounds__(256) void gemm_bt(const float* __restrict__ A,
                                               const float* __restrict__ BT,
                                               const float* __restrict__ bias,
                                               const float* __restrict__ scl,
                                               float* __restrict__ C,
                                               int M, int N, int K) {
  constexpr int BCOLS = WN * 64;
  __shared__ __align__(16) char sAh[BROWS * 64];
  __shared__ __align__(16) char sAl[BROWS * 64];
  __shared__ __align__(16) char sBh[BCOLS * 64];
  __shared__ __align__(16) char sBl[BCOLS * 64];
  int t = threadIdx.x;
  int m0 = blockIdx.y * BROWS, n0 = blockIdx.x * BCOLS;
  int wid = t >> 6, lane = t & 63;
  int wr = wid / WN, wc = wid % WN;
  int lr = lane & 15, kg = lane >> 4;
  f32x4 acc[4][4] = {};
  for (int k0 = 0; k0 < K; k0 += 32) {
    stage_bf16x3<BROWS / 32>(A, K, m0, k0, M - 1, sAh, sAl, t);
    stage_bf16x3<BCOLS / 32>(BT, K, n0, k0, N - 1, sBh, sBl, t);
    __syncthreads();
    bf16x8 ah[4], al[4];
    #pragma unroll
    for (int mi = 0; mi < 4; ++mi) {
      int row = wr * 64 + mi * 16 + lr;
      int ab = swz16(row, kg);
      ah[mi] = *reinterpret_cast<const bf16x8*>(sAh + ab);
      al[mi] = *reinterpret_cast<const bf16x8*>(sAl + ab);
    }
    #pragma unroll
    for (int ni = 0; ni < 4; ++ni) {
      int rb = wc * 64 + ni * 16 + lr;
      int bb = swz16(rb, kg);
      bf16x8 bh = *reinterpret_cast<const bf16x8*>(sBh + bb);
      bf16x8 bl = *reinterpret_cast<const bf16x8*>(sBl + bb);
      #pragma unroll
      for (int mi = 0; mi < 4; ++mi) {
        acc[mi][ni] = __builtin_amdgcn_mfma_f32_16x16x32_bf16(ah[mi], bh, acc[mi][ni], 0, 0, 0);
        acc[mi][ni] = __builtin_amdgcn_mfma_f32_16x16x32_bf16(al[mi], bh, acc[mi][ni], 0, 0, 0);
        acc[mi][ni] = __builtin_amdgcn_mfma_f32_16x16x32_bf16(ah[mi], bl, acc[mi][ni], 0, 0, 0);
      }
    }
    __syncthreads();
  }
  #pragma unroll
  for (int mi = 0; mi < 4; ++mi) {
    #pragma unroll
    for (int ni = 0; ni < 4; ++ni) {
      int row0 = m0 + wr * 64 + mi * 16 + kg * 4;
      int col  = n0 + wc * 64 + ni * 16 + lr;
      if (col < N) {
        float b = HAS_BIAS ? bias[col] : 0.0f;
        float s = HAS_SCALE ? scl[col] : 1.0f;
        #pragma unroll
        for (int i = 0; i < 4; ++i) {
          float v = acc[mi][ni][i];
          if (HAS_SCALE) v *= s;
          if (HAS_BIAS) v += b;
          if (ACT == 1) v = 0.5f * v * (1.0f + erff(v * 0.7071067811865476f));
          C[(size_t)(row0 + i) * N + col] = v;
        }
      }
    }
  }
}

// ---------------- weight transpose + bf16 hi/lo split ----------------
__global__ __launch_bounds__(256) void transcvt_kernel(const float* __restrict__ src,
                                                       ushort_t* __restrict__ dh,
                                                       ushort_t* __restrict__ dl,
                                                       int R, int C) {
  __shared__ float tile[32][33];
  int c0 = blockIdx.x * 32, r0 = blockIdx.y * 32;
  int x = threadIdx.x & 31, y4 = (threadIdx.x >> 5) * 4;
  #pragma unroll
  for (int i = 0; i < 4; ++i) {
    tile[y4 + i][x] = src[(size_t)(r0 + y4 + i) * C + c0 + x];
  }
  __syncthreads();
  #pragma unroll
  for (int i = 0; i < 4; ++i) {
    float v = tile[x][y4 + i];
    ushort_t h, l;
    split_bf16(v, h, l);
    size_t o = (size_t)(c0 + y4 + i) * R + r0 + x;
    dh[o] = h; dl[o] = l;
  }
}

// ---------------- embedding + positional encoding ----------------
__global__ __launch_bounds__(256) void embed_kernel(const int* __restrict__ ids,
                                                    const float* __restrict__ emb,
                                                    float* __restrict__ x,
                                                    ushort_t* __restrict__ xh,
                                                    ushort_t* __restrict__ xl) {
  int row = blockIdx.x;
  int d = threadIdx.x;
  int s = row & (S_ - 1);
  int tok = ids[row];
  int d2 = d & ~1;
  float div = expf((float)d2 * (-9.210340371976184f / 256.0f));
  float ang = (float)s * div;
  float pe = (d & 1) ? cosf(ang) : sinf(ang);
  float v = emb[(size_t)tok * D_ + d] * 16.0f + pe;
  size_t o = (size_t)row * D_ + d;
  x[o] = v;
  ushort_t h, l;
  split_bf16(v, h, l);
  xh[o] = h; xl[o] = l;
}

// ---------------- attention: no-LDS, K/V rows via wave-uniform (scalar) loads ----------------
// Per block = one (b,h); thread = one query. K/V row addresses depend only on
// blockIdx + loop counter -> compiler scalarizes to s_load; v_fma uses SGPR operand.
// T13 defer-max: rescale only when running max grows by >8 (rare, exact in f32 range).
__global__ __launch_bounds__(256) void attn_kernel(const float* __restrict__ qkv,
                                                   ushort_t* __restrict__ ctxh,
                                                   ushort_t* __restrict__ ctxl) {
  int bh = blockIdx.x;
  int b = bh >> 3, h = bh & 7;
  int t = threadIdx.x;
  const float* __restrict__ base = qkv + (size_t)(b * S_) * 768;
  const float* __restrict__ kb = base + 256 + h * 32;
  const float* __restrict__ vb = base + 512 + h * 32;
  float q[DH_];
  {
    const float* qp = base + (size_t)t * 768 + h * 32;
    #pragma unroll
    for (int i = 0; i < DH_; ++i) q[i] = qp[i] * 0.17677669529663687f;  // 1/sqrt(32)
  }
  float mref = -3.0e38f, l = 0.0f, acc[DH_];
  #pragma unroll
  for (int i = 0; i < DH_; ++i) acc[i] = 0.0f;
  for (int s = 0; s < S_; ++s) {
    const float* __restrict__ kr = kb + (size_t)s * 768;
    float s0 = 0.f, s1 = 0.f, s2 = 0.f, s3 = 0.f;
    #pragma unroll
    for (int i = 0; i < DH_; i += 4) {
      s0 = fmaf(q[i + 0], kr[i + 0], s0);
      s1 = fmaf(q[i + 1], kr[i + 1], s1);
      s2 = fmaf(q[i + 2], kr[i + 2], s2);
      s3 = fmaf(q[i + 3], kr[i + 3], s3);
    }
    float sc = (s0 + s1) + (s2 + s3);
    if (sc > mref + 8.0f) {            // rare deferred rescale
      float r = __expf(mref - sc);     // first iter: exp(-huge) = 0 -> clean init
      l *= r;
      #pragma unroll
      for (int i = 0; i < DH_; ++i) acc[i] *= r;
      mref = sc;
    }
    float p = __expf(sc - mref);       // bounded by e^8, f32-safe
    l += p;
    const float* __restrict__ vr = vb + (size_t)s * 768;
    #pragma unroll
    for (int i = 0; i < DH_; ++i) acc[i] = fmaf(p, vr[i], acc[i]);
  }
  float inv = 1.0f / l;
  size_t cp = (size_t)(b * S_ + t) * D_ + h * 32;
  #pragma unroll
  for (int i = 0; i < DH_; ++i) {
    float v = acc[i] * inv;
    ushort_t hh, ll;
    split_bf16(v, hh, ll);
    ctxh[cp + i] = hh; ctxl[cp + i] = ll;
  }
}

// ---------------- residual add + layernorm ----------------
template<bool PAIRS>
__global__ __launch_bounds__(256) void addln_kernel(const float* __restrict__ x,
                                                    const float* __restrict__ y,
                                                    const float* __restrict__ gam,
                                                    const float* __restrict__ bet,
                                                    float* __restrict__ out,
                                                    ushort_t* __restrict__ oh,
                                                    ushort_t* __restrict__ ol) {
  __shared__ float sh[8];
  int row = blockIdx.x, d = threadIdx.x;
  float v = x[(size_t)row * D_ + d];
  if (y) v += y[(size_t)row * D_ + d];
  float mean = blockReduceSum256(v, sh) * (1.0f / D_);
  float diff = v - mean;
  float var = blockReduceSum256(diff * diff, sh) * (1.0f / D_);
  float r = diff * rsqrtf(var + 1e-5f) * gam[d] + bet[d];
  size_t o = (size_t)row * D_ + d;
  out[o] = r;
  if (PAIRS) {
    ushort_t h, l;
    split_bf16(r, h, l);
    oh[o] = h; ol[o] = l;
  }
}

// ---------------- masked mean pool ----------------
__global__ __launch_bounds__(256) void pooled_kernel(const float* __restrict__ hidden,
                                                     const float* __restrict__ mask,
                                                     float* __restrict__ pooled) {
  int b = blockIdx.x, d = threadIdx.x;
  float s = 0.0f, msum = 0.0f;
  for (int t = 0; t < S_; ++t) {
    float mk = mask[b * S_ + t];
    s += hidden[(size_t)(b * S_ + t) * D_ + d] * mk;
    msum += mk;
  }
  pooled[b * D_ + d] = s / (msum + 1e-8f);
}

// ---------------- normalize pooled queries ----------------
__global__ __launch_bounds__(256) void qnorm_kernel(const float* __restrict__ pooled,
                                                    float* __restrict__ qn) {
  __shared__ float sh[8];
  int b = blockIdx.x, d = threadIdx.x;
  float v = pooled[b * D_ + d];
  float ss = blockReduceSum256(v * v, sh);
  qn[b * D_ + d] = v / fmaxf(sqrtf(ss), 1e-8f);
}

// ---------------- per-key inverse norms ----------------
__global__ __launch_bounds__(64) void invnorm_kernel(const float* __restrict__ keys,
                                                     float* __restrict__ invn) {
  int row = blockIdx.x, t = threadIdx.x;
  float4 v = *reinterpret_cast<const float4*>(keys + (size_t)row * D_ + t * 4);
  float ss = v.x * v.x + v.y * v.y + v.z * v.z + v.w * v.w;
  #pragma unroll
  for (int o = 32; o; o >>= 1) ss += __shfl_down(ss, o);
  if (t == 0) invn[row] = 1.0f / fmaxf(sqrtf(ss), 1e-8f);
}

// ================= threshold top-k (exact, no iterative extraction over data) ==========
// chunkmax: per (row,chunk), max u64 key over ~1563 elements (single reduce).
__global__ __launch_bounds__(256) void chunkmax_kernel(const float* __restrict__ sims,
                                                       unsigned long long* __restrict__ chm) {
  __shared__ unsigned long long wk[4];
  int row = blockIdx.x >> 7, c = blockIdx.x & 127;
  int t = threadIdx.x;
  int base = c * CHA_;
  int end = base + CHA_; if (end > MEM_) end = MEM_;
  const float* src = sims + (size_t)row * MEM_;
  unsigned long long best = 0ull;
  for (int i = base + t; i < end; i += 256) {
    unsigned long long key =
        ((unsigned long long)f2key(src[i]) << 32) | (unsigned int)~(unsigned int)i;
    best = ullmax(best, key);
  }
  #pragma unroll
  for (int o = 32; o; o >>= 1) best = ullmax(best, __shfl_down(best, o));
  int lane = t & 63, w = t >> 6;
  if (lane == 0) wk[w] = best;
  __syncthreads();
  if (t == 0) chm[row * NCHA_ + c] = ullmax(ullmax(wk[0], wk[1]), ullmax(wk[2], wk[3]));
}

// tau: per row, k-th largest chunk max via all-pairs rank (keys distinct by index tag).
// Validity: the k largest chunk-maxima are k distinct elements >= tau, so the global
// k-th largest key >= tau, so every top-k element has key >= tau.
__global__ __launch_bounds__(128) void tau_kernel(const unsigned long long* __restrict__ chm,
                                                  const int* __restrict__ topk,
                                                  unsigned long long* __restrict__ tau,
                                                  unsigned int* __restrict__ cnt) {
  __shared__ unsigned long long keys[NCHA_];
  int row = blockIdx.x, t = threadIdx.x;
  int k = *topk; if (k > 64) k = 64; if (k < 1) k = 1;
  keys[t] = chm[row * NCHA_ + t];
  __syncthreads();
  unsigned long long mine = keys[t];
  int rank = 0;
  for (int j = 0; j < NCHA_; ++j) rank += (keys[j] > mine) ? 1 : 0;
  if (rank == k - 1) tau[row] = mine;
  if (t == 0) cnt[row] = 0u;
}

// collect: gather all keys >= tau (expected ~k + O(k), cap CAP_). Atomic order is
// irrelevant: final selection sorts by full u64 key.
__global__ __launch_bounds__(256) void collect_kernel(const float* __restrict__ sims,
                                                      const unsigned long long* __restrict__ tau,
                                                      unsigned long long* __restrict__ cand,
                                                      unsigned int* __restrict__ cnt) {
  int row = blockIdx.x >> 7, c = blockIdx.x & 127;
  int t = threadIdx.x;
  unsigned long long tv = tau[row];
  int base = c * CHA_;
  int end = base + CHA_; if (end > MEM_) end = MEM_;
  const float* src = sims + (size_t)row * MEM_;
  for (int i = base + t; i < end; i += 256) {
    unsigned long long key =
        ((unsigned long long)f2key(src[i]) << 32) | (unsigned int)~(unsigned int)i;
    if (key >= tv) {
      unsigned int pos = atomicAdd(&cnt[row], 1u);
      if (pos < CAP_) cand[(size_t)row * CAP_ + pos] = key;
    }
  }
}

// final: k extractions over the tiny candidate set (LDS-resident).
__global__ __launch_bounds__(256) void final_topk(const unsigned long long* __restrict__ cand,
                                                  const unsigned int* __restrict__ cnt,
                                                  const int* __restrict__ topk,
                                                  float* __restrict__ topv,
                                                  int* __restrict__ topi) {
  __shared__ unsigned long long buf[CAP_];
  __shared__ unsigned long long wk[4];
  int row = blockIdx.x, t = threadIdx.x;
  int k = *topk; if (k > 64) k = 64; if (k < 1) k = 1;
  int n = (int)cnt[row]; if (n > CAP_) n = CAP_;
  for (int i = t; i < n; i += 256) buf[i] = cand[(size_t)row * CAP_ + i];
  __syncthreads();
  int lane = t & 63, w = t >> 6;
  for (int iter = 0; iter < k; ++iter) {
    unsigned long long best = 0ull;
    for (int i = t; i < n; i += 256) best = ullmax(best, buf[i]);
    #pragma unroll
    for (int o = 32; o; o >>= 1) best = ullmax(best, __shfl_down(best, o));
    if (lane == 0) wk[w] = best;
    __syncthreads();
    best = ullmax(ullmax(wk[0], wk[1]), ullmax(wk[2], wk[3]));
    if (t == 0) {
      topv[row * 64 + iter] = key2f((unsigned int)(best >> 32));
      topi[row * 64 + iter] = (int)~(unsigned int)best;
    }
    for (int i = t; i < n; i += 256) if (buf[i] == best) buf[i] = 0ull;
    __syncthreads();
  }
}

// ---------------- weighted aggregate of retrieved values ----------------
__global__ __launch_bounds__(256) void retrieve_kernel(const float* __restrict__ topv,
                                                       const int* __restrict__ topi,
                                                       const int* __restrict__ topk,
                                                       const float* __restrict__ vals,
                                                       const float* __restrict__ conf,
                                                       float* __restrict__ retr) {
  int b = blockIdx.x, d = threadIdx.x;
  int k = *topk; if (k > 64) k = 64; if (k < 1) k = 1;
  float acc = 0.0f, wsum = 0.0f;
  for (int i = 0; i < k; ++i) {
    int idx = topi[b * 64 + i];
    float w = fmaxf(conf[idx], 1e-4f) * topv[b * 64 + i];
    wsum += w;
    acc += w * vals[(size_t)idx * D_ + d];
  }
  retr[b * D_ + d] = acc / (wsum + 1e-8f);
}

// ---------------- gate MLP + fuse + classifier ----------------
__global__ __launch_bounds__(256) void head_kernel(const float* __restrict__ pooled,
                                                   const float* __restrict__ retr,
                                                   const float* __restrict__ gw1,
                                                   const float* __restrict__ gb1,
                                                   const float* __restrict__ gw2,
                                                   const float* __restrict__ gb2,
                                                   const float* __restrict__ cw,
                                                   const float* __restrict__ cb,
                                                   float* __restrict__ out) {
  __shared__ float pl[D_], hh[D_], fu[D_], sh[8];
  int b = blockIdx.x, d = threadIdx.x;
  pl[d] = pooled[b * D_ + d];
  __syncthreads();
  float a = gb1[d];
  for (int e = 0; e < D_; ++e) a += pl[e] * gw1[e * D_ + d];
  hh[d] = fmaxf(a, 0.0f);
  float gsum = blockReduceSum256(hh[d] * gw2[d], sh);
  float g = 1.0f / (1.0f + expf(-(gsum + gb2[0])));
  fu[d] = g * retr[b * D_ + d] + (1.0f - g) * pl[d];
  __syncthreads();
  if (d < 16) {
    float o = cb[d];
    for (int e = 0; e < D_; ++e) o += fu[e] * cw[e * 16 + d];
    out[b * 16 + d] = o;
  }
}

// ---------------- launcher ----------------
extern "C" void kernel_launch(void* const* d_in, const int* in_sizes, int n_in,
                              void* d_out, int out_size, void* d_ws, size_t ws_size,
                              hipStream_t stream) {
  const int*   ids   = (const int*)d_in[0];
  const float* mask  = (const float*)d_in[1];
  const int*   topk  = (const int*)d_in[2];
  const float* emb   = (const float*)d_in[3];
  const float* qkv_w = (const float*)d_in[4];
  const float* qkv_b = (const float*)d_in[5];
  const float* out_w = (const float*)d_in[6];
  const float* out_b = (const float*)d_in[7];
  const float* ln1_s = (const float*)d_in[8];
  const float* ln1_b = (const float*)d_in[9];
  const float* ff_w1 = (const float*)d_in[10];
  const float* ff_b1 = (const float*)d_in[11];
  const float* ff_w2 = (const float*)d_in[12];
  const float* ff_b2 = (const float*)d_in[13];
  const float* ln2_s = (const float*)d_in[14];
  const float* ln2_b = (const float*)d_in[15];
  const float* lnf_s = (const float*)d_in[16];
  const float* lnf_b = (const float*)d_in[17];
  const float* gw1   = (const float*)d_in[18];
  const float* gb1   = (const float*)d_in[19];
  const float* gw2   = (const float*)d_in[20];
  const float* gb2   = (const float*)d_in[21];
  const float* cw    = (const float*)d_in[22];
  const float* cb    = (const float*)d_in[23];
  const float* mkeys = (const float*)d_in[24];
  const float* mvals = (const float*)d_in[25];
  const float* mconf = (const float*)d_in[26];
  float* out = (float*)d_out;

  // ---- workspace layout ----
  float* ws   = (float*)d_ws;
  float* X    = ws;                                   //  4,194,304 f
  float* Y    = X + 4194304;                          //  4,194,304 f
  float* R    = Y + 4194304;                          // 16,777,216 f (qkv f32 / ff1 pairs / sims)
  ushort_t* XH   = (ushort_t*)(R + 16777216);         //  4,194,304 sh
  ushort_t* XL   = XH + 4194304;
  ushort_t* CTXH = XL + 4194304;
  ushort_t* CTXL = CTXH + 4194304;
  ushort_t* WP   = CTXL + 4194304;                    //  3,145,728 sh (weight pairs)
  float* POOL = (float*)(WP + 3145728);               //  16384 f
  float* QN   = POOL + 16384;
  float* INVN = QN + 16384;                           //  200,000 f
  float* TOPV = INVN + 200000;                        //  4096 f
  int*   TOPI = (int*)(TOPV + 4096);
  float* RETR = (float*)(TOPI + 4096);                //  16384 f
  unsigned long long* CANDK = (unsigned long long*)(RETR + 16384);  // 64*2048 u64 = 1 MB
  unsigned long long* CHM   = CANDK + (size_t)B_ * CAP_;            // 64*128 u64
  unsigned long long* TAU   = CHM + B_ * NCHA_;                     // 64 u64
  unsigned int*       CNT   = (unsigned int*)(TAU + B_);            // 64 u32

  // aliases over R (lifetimes disjoint)
  float*    QKVOUT = R;                  // [16384][768] f32
  ushort_t* BIGH   = (ushort_t*)R;       // [16384][1024] bf16 hi
  ushort_t* BIGL   = BIGH + 16777216;    // [16384][1024] bf16 lo
  float*    SIMS   = R;                  // [64][200000] f32

  const size_t LW = 1572864;  // per-layer weight-pair stride (shorts)
  #define WPTR(l, off) (WP + (size_t)(l) * LW + (off))

  // ---- weight prep: transpose + bf16 hi/lo split (once) ----
  for (int l = 0; l < 2; ++l) {
    transcvt_kernel<<<dim3(24, 8), 256, 0, stream>>>(qkv_w + (size_t)l * 196608,
                                                     WPTR(l, 0), WPTR(l, 196608), 256, 768);
    transcvt_kernel<<<dim3(8, 8), 256, 0, stream>>>(out_w + (size_t)l * 65536,
                                                    WPTR(l, 393216), WPTR(l, 458752), 256, 256);
    transcvt_kernel<<<dim3(32, 8), 256, 0, stream>>>(ff_w1 + (size_t)l * 262144,
                                                     WPTR(l, 524288), WPTR(l, 786432), 256, 1024);
    transcvt_kernel<<<dim3(8, 32), 256, 0, stream>>>(ff_w2 + (size_t)l * 262144,
                                                     WPTR(l, 1048576), WPTR(l, 1310720), 1024, 256);
  }

  embed_kernel<<<ROWS_, 256, 0, stream>>>(ids, emb, X, XH, XL);

  for (int l = 0; l < 2; ++l) {
    gemm16<0, true, 0><<<dim3(6, 128), 256, 0, stream>>>(
        XH, XL, WPTR(l, 0), WPTR(l, 196608), qkv_b + l * 768,
        QKVOUT, nullptr, nullptr, ROWS_, 768, 256);
    attn_kernel<<<B_ * H_, 256, 0, stream>>>(QKVOUT, CTXH, CTXL);
    gemm16<0, true, 0><<<dim3(2, 128), 256, 0, stream>>>(
        CTXH, CTXL, WPTR(l, 393216), WPTR(l, 458752), out_b + l * 256,
        Y, nullptr, nullptr, ROWS_, 256, 256);
    addln_kernel<true><<<ROWS_, 256, 0, stream>>>(X, Y, ln1_s + l * 256, ln1_b + l * 256,
                                                  X, XH, XL);
    gemm16<1, true, 1><<<dim3(8, 128), 256, 0, stream>>>(
        XH, XL, WPTR(l, 524288), WPTR(l, 786432), ff_b1 + l * 1024,
        nullptr, BIGH, BIGL, ROWS_, 1024, 256);
    gemm16<0, true, 0><<<dim3(2, 128), 256, 0, stream>>>(
        BIGH, BIGL, WPTR(l, 1048576), WPTR(l, 1310720), ff_b2 + l * 256,
        Y, nullptr, nullptr, ROWS_, 256, 1024);
    addln_kernel<true><<<ROWS_, 256, 0, stream>>>(X, Y, ln2_s + l * 256, ln2_b + l * 256,
                                                  X, XH, XL);
  }

  addln_kernel<false><<<ROWS_, 256, 0, stream>>>(X, nullptr, lnf_s, lnf_b, Y, nullptr, nullptr);
  pooled_kernel<<<B_, 256, 0, stream>>>(Y, mask, POOL);
  qnorm_kernel<<<B_, 256, 0, stream>>>(POOL, QN);
  invnorm_kernel<<<MEM_, 64, 0, stream>>>(mkeys, INVN);
  gemm_bt<64, 1, 4, 0, false, true><<<dim3((MEM_ + 255) / 256, 1), 256, 0, stream>>>(
      QN, mkeys, nullptr, INVN, SIMS, 64, MEM_, 256);

  chunkmax_kernel<<<B_ * NCHA_, 256, 0, stream>>>(SIMS, CHM);
  tau_kernel<<<B_, 128, 0, stream>>>(CHM, topk, TAU, CNT);
  collect_kernel<<<B_ * NCHA_, 256, 0, stream>>>(SIMS, TAU, CANDK, CNT);
  final_topk<<<B_, 256, 0, stream>>>(CANDK, CNT, topk, TOPV, TOPI);

  retrieve_kernel<<<B_, 256, 0, stream>>>(TOPV, TOPI, topk, mvals, mconf, RETR);
  head_kernel<<<B_, 256, 0, stream>>>(POOL, RETR, gw1, gb1, gw2, gb2, cw, cb, out);
  #undef WPTR
}

// Round 6
// 732.522 us; speedup vs baseline: 11.0645x; 1.3853x over previous
//
#include <hip/hip_runtime.h>
#include <math.h>

// ---------------- constants ----------------
#define B_   64
#define S_   256
#define D_   256
#define H_   8
#define DH_  32
#define FF_  1024
#define MEM_ 200000
#define ROWS_ (B_ * S_)   // 16384
#define NCHA_ 128         // chunks per row for threshold top-k
#define CHA_  1563        // ceil(MEM_/NCHA_)
#define CAP_  2048        // candidate cap per row

typedef float f32x4 __attribute__((ext_vector_type(4)));
typedef __bf16 bf16x8 __attribute__((ext_vector_type(8)));
typedef unsigned short ushort_t;

// ---------------- helpers ----------------
__device__ __forceinline__ float blockReduceSum256(float v, float* sh) {
  #pragma unroll
  for (int o = 32; o; o >>= 1) v += __shfl_down(v, o);
  int lane = threadIdx.x & 63, w = threadIdx.x >> 6;
  __syncthreads();
  if (lane == 0) sh[w] = v;
  __syncthreads();
  return sh[0] + sh[1] + sh[2] + sh[3];
}

__device__ __forceinline__ unsigned int f2key(float f) {
  unsigned int b = __float_as_uint(f);
  return (b & 0x80000000u) ? ~b : (b | 0x80000000u);
}
__device__ __forceinline__ float key2f(unsigned int u) {
  unsigned int b = (u & 0x80000000u) ? (u & 0x7FFFFFFFu) : ~u;
  return __uint_as_float(b);
}
__device__ __forceinline__ unsigned long long ullmax(unsigned long long a, unsigned long long b) {
  return a > b ? a : b;
}

__device__ __forceinline__ ushort_t f32_bf16_rn(float x) {
  unsigned int u = __float_as_uint(x);
  u += 0x7FFFu + ((u >> 16) & 1u);
  return (ushort_t)(u >> 16);
}
__device__ __forceinline__ float bf16_f32(ushort_t h) {
  return __uint_as_float((unsigned int)h << 16);
}
__device__ __forceinline__ void split_bf16(float v, ushort_t& h, ushort_t& l) {
  h = f32_bf16_rn(v);
  l = f32_bf16_rn(v - bf16_f32(h));
}

// swizzled byte offsets into a [R][32] bf16 LDS tile (row stride 64B, 4x16B granules,
// granule ^= (row>>1)&3 -> at most 2-way bank aliasing on ds_read_b128 frag reads)
__device__ __forceinline__ int swz8(int row, int kq) {   // 8B granule (4 bf16), kq = k/4
  return row * 64 + ((((kq >> 1) ^ ((row >> 1) & 3)) << 4)) + (kq & 1) * 8;
}
__device__ __forceinline__ int swz16(int row, int kg) {  // 16B granule (8 bf16), kg = k/8
  return row * 64 + (((kg ^ ((row >> 1) & 3)) << 4));
}

// direct global->LDS 16B copy (CK-style addrspace casts): LDS dest is
// wave-uniform base (+ lane*16 added by HW); global source is per-lane.
__device__ __forceinline__ void gload_lds16(const void* gsrc, void* ldst) {
  __builtin_amdgcn_global_load_lds(
      (const __attribute__((address_space(1))) unsigned int*)gsrc,
      (__attribute__((address_space(3))) unsigned int*)(unsigned int)(unsigned long long)ldst,
      16, 0, 0);
}

// stage a [128 x 32] bf16 tile (8KB) from a linear global [row][ldg] buffer into
// swizzled LDS. Inverse-swizzle applied to the global SOURCE; LDS dest linear.
__device__ __forceinline__ void stage16(const ushort_t* __restrict__ G, int ldg,
                                        int base_row, int k0, char* lds, int t) {
  #pragma unroll
  for (int r = 0; r < 2; ++r) {
    int idx = r * 256 + t;                 // granule slot 0..511
    int row = idx >> 2, kg = idx & 3;
    int kg_g = kg ^ ((row >> 1) & 3);      // involution: source granule for this slot
    const void* src = G + (size_t)(base_row + row) * ldg + k0 + kg_g * 8;
    void* dst = lds + (size_t)(idx & ~63) * 16;  // wave-uniform base
    gload_lds16(src, dst);
  }
}

// legacy f32 staging (used only by the sims GEMM, whose B is single-use)
template<int NITER>
__device__ __forceinline__ void stage_bf16x3(const float* __restrict__ G, int ldg,
                                             int base_row, int k0, int max_row,
                                             char* __restrict__ sh, char* __restrict__ sl,
                                             int t) {
  #pragma unroll
  for (int r = 0; r < NITER; ++r) {
    int idx = r * 256 + t;
    int row = idx >> 3, kq = idx & 7;
    int gr = base_row + row; if (gr > max_row) gr = max_row;
    const float4 v = *reinterpret_cast<const float4*>(G + (size_t)gr * ldg + k0 + kq * 4);
    float vv[4] = {v.x, v.y, v.z, v.w};
    ushort_t h[4], l[4];
    #pragma unroll
    for (int j = 0; j < 4; ++j) split_bf16(vv[j], h[j], l[j]);
    uint2 hp = make_uint2((unsigned)h[0] | ((unsigned)h[1] << 16),
                          (unsigned)h[2] | ((unsigned)h[3] << 16));
    uint2 lp = make_uint2((unsigned)l[0] | ((unsigned)l[1] << 16),
                          (unsigned)l[2] | ((unsigned)l[3] << 16));
    int b8 = swz8(row, kq);
    *reinterpret_cast<uint2*>(sh + b8) = hp;
    *reinterpret_cast<uint2*>(sl + b8) = lp;
  }
}

// ---------------- bf16x3 MFMA GEMM on pre-split hi/lo inputs ----------------
template<int ACT, bool HAS_BIAS, int OUTMODE>
__global__ __launch_bounds__(256) void gemm16(const ushort_t* __restrict__ AH,
                                              const ushort_t* __restrict__ AL,
                                              const ushort_t* __restrict__ BH,
                                              const ushort_t* __restrict__ BL,
                                              const float* __restrict__ bias,
                                              float* __restrict__ C,
                                              ushort_t* __restrict__ CH,
                                              ushort_t* __restrict__ CL,
                                              int M, int N, int K) {
  __shared__ __align__(16) char sAh[128 * 64];
  __shared__ __align__(16) char sAl[128 * 64];
  __shared__ __align__(16) char sBh[128 * 64];
  __shared__ __align__(16) char sBl[128 * 64];
  int t = threadIdx.x;
  int m0 = blockIdx.y * 128, n0 = blockIdx.x * 128;
  int wid = t >> 6, lane = t & 63;
  int wr = wid >> 1, wc = wid & 1;
  int lr = lane & 15, kg = lane >> 4;
  f32x4 acc[4][4] = {};
  for (int k0 = 0; k0 < K; k0 += 32) {
    stage16(AH, K, m0, k0, sAh, t);
    stage16(AL, K, m0, k0, sAl, t);
    stage16(BH, K, n0, k0, sBh, t);
    stage16(BL, K, n0, k0, sBl, t);
    __syncthreads();
    bf16x8 ah[4], al[4];
    #pragma unroll
    for (int mi = 0; mi < 4; ++mi) {
      int row = wr * 64 + mi * 16 + lr;
      int ab = swz16(row, kg);
      ah[mi] = *reinterpret_cast<const bf16x8*>(sAh + ab);
      al[mi] = *reinterpret_cast<const bf16x8*>(sAl + ab);
    }
    #pragma unroll
    for (int ni = 0; ni < 4; ++ni) {
      int rb = wc * 64 + ni * 16 + lr;
      int bb = swz16(rb, kg);
      bf16x8 bh = *reinterpret_cast<const bf16x8*>(sBh + bb);
      bf16x8 bl = *reinterpret_cast<const bf16x8*>(sBl + bb);
      #pragma unroll
      for (int mi = 0; mi < 4; ++mi) {
        acc[mi][ni] = __builtin_amdgcn_mfma_f32_16x16x32_bf16(ah[mi], bh, acc[mi][ni], 0, 0, 0);
        acc[mi][ni] = __builtin_amdgcn_mfma_f32_16x16x32_bf16(al[mi], bh, acc[mi][ni], 0, 0, 0);
        acc[mi][ni] = __builtin_amdgcn_mfma_f32_16x16x32_bf16(ah[mi], bl, acc[mi][ni], 0, 0, 0);
      }
    }
    __syncthreads();
  }
  #pragma unroll
  for (int mi = 0; mi < 4; ++mi) {
    #pragma unroll
    for (int ni = 0; ni < 4; ++ni) {
      int row0 = m0 + wr * 64 + mi * 16 + kg * 4;
      int col  = n0 + wc * 64 + ni * 16 + lr;
      float b = HAS_BIAS ? bias[col] : 0.0f;
      #pragma unroll
      for (int i = 0; i < 4; ++i) {
        float v = acc[mi][ni][i] + b;
        if (ACT == 1) v = 0.5f * v * (1.0f + erff(v * 0.7071067811865476f));
        size_t o = (size_t)(row0 + i) * N + col;
        if (OUTMODE == 0) {
          C[o] = v;
        } else {
          ushort_t h, l;
          split_bf16(v, h, l);
          CH[o] = h; CL[o] = l;
        }
      }
    }
  }
}

// ---------------- legacy bf16x3 GEMM with in-kernel f32 conversion (sims only) ----------------
template<int BROWS, int WM, int WN, int ACT, bool HAS_BIAS, bool HAS_SCALE>
__global__ __launch_bounds__(256) void gemm_bt(const float* __restrict__ A,
                                               const float* __restrict__ BT,
                                               const float* __restrict__ bias,
                                               const float* __restrict__ scl,
                                               float* __restrict__ C,
                                               int M, int N, int K) {
  constexpr int BCOLS = WN * 64;
  __shared__ __align__(16) char sAh[BROWS * 64];
  __shared__ __align__(16) char sAl[BROWS * 64];
  __shared__ __align__(16) char sBh[BCOLS * 64];
  __shared__ __align__(16) char sBl[BCOLS * 64];
  int t = threadIdx.x;
  int m0 = blockIdx.y * BROWS, n0 = blockIdx.x * BCOLS;
  int wid = t >> 6, lane = t & 63;
  int wr = wid / WN, wc = wid % WN;
  int lr = lane & 15, kg = lane >> 4;
  f32x4 acc[4][4] = {};
  for (int k0 = 0; k0 < K; k0 += 32) {
    stage_bf16x3<BROWS / 32>(A, K, m0, k0, M - 1, sAh, sAl, t);
    stage_bf16x3<BCOLS / 32>(BT, K, n0, k0, N - 1, sBh, sBl, t);
    __syncthreads();
    bf16x8 ah[4], al[4];
    #pragma unroll
    for (int mi = 0; mi < 4; ++mi) {
      int row = wr * 64 + mi * 16 + lr;
      int ab = swz16(row, kg);
      ah[mi] = *reinterpret_cast<const bf16x8*>(sAh + ab);
      al[mi] = *reinterpret_cast<const bf16x8*>(sAl + ab);
    }
    #pragma unroll
    for (int ni = 0; ni < 4; ++ni) {
      int rb = wc * 64 + ni * 16 + lr;
      int bb = swz16(rb, kg);
      bf16x8 bh = *reinterpret_cast<const bf16x8*>(sBh + bb);
      bf16x8 bl = *reinterpret_cast<const bf16x8*>(sBl + bb);
      #pragma unroll
      for (int mi = 0; mi < 4; ++mi) {
        acc[mi][ni] = __builtin_amdgcn_mfma_f32_16x16x32_bf16(ah[mi], bh, acc[mi][ni], 0, 0, 0);
        acc[mi][ni] = __builtin_amdgcn_mfma_f32_16x16x32_bf16(al[mi], bh, acc[mi][ni], 0, 0, 0);
        acc[mi][ni] = __builtin_amdgcn_mfma_f32_16x16x32_bf16(ah[mi], bl, acc[mi][ni], 0, 0, 0);
      }
    }
    __syncthreads();
  }
  #pragma unroll
  for (int mi = 0; mi < 4; ++mi) {
    #pragma unroll
    for (int ni = 0; ni < 4; ++ni) {
      int row0 = m0 + wr * 64 + mi * 16 + kg * 4;
      int col  = n0 + wc * 64 + ni * 16 + lr;
      if (col < N) {
        float b = HAS_BIAS ? bias[col] : 0.0f;
        float s = HAS_SCALE ? scl[col] : 1.0f;
        #pragma unroll
        for (int i = 0; i < 4; ++i) {
          float v = acc[mi][ni][i];
          if (HAS_SCALE) v *= s;
          if (HAS_BIAS) v += b;
          if (ACT == 1) v = 0.5f * v * (1.0f + erff(v * 0.7071067811865476f));
          C[(size_t)(row0 + i) * N + col] = v;
        }
      }
    }
  }
}

// ---------------- weight transpose + bf16 hi/lo split ----------------
__global__ __launch_bounds__(256) void transcvt_kernel(const float* __restrict__ src,
                                                       ushort_t* __restrict__ dh,
                                                       ushort_t* __restrict__ dl,
                                                       int R, int C) {
  __shared__ float tile[32][33];
  int c0 = blockIdx.x * 32, r0 = blockIdx.y * 32;
  int x = threadIdx.x & 31, y4 = (threadIdx.x >> 5) * 4;
  #pragma unroll
  for (int i = 0; i < 4; ++i) {
    tile[y4 + i][x] = src[(size_t)(r0 + y4 + i) * C + c0 + x];
  }
  __syncthreads();
  #pragma unroll
  for (int i = 0; i < 4; ++i) {
    float v = tile[x][y4 + i];
    ushort_t h, l;
    split_bf16(v, h, l);
    size_t o = (size_t)(c0 + y4 + i) * R + r0 + x;
    dh[o] = h; dl[o] = l;
  }
}

// ---------------- embedding + positional encoding ----------------
__global__ __launch_bounds__(256) void embed_kernel(const int* __restrict__ ids,
                                                    const float* __restrict__ emb,
                                                    float* __restrict__ x,
                                                    ushort_t* __restrict__ xh,
                                                    ushort_t* __restrict__ xl) {
  int row = blockIdx.x;
  int d = threadIdx.x;
  int s = row & (S_ - 1);
  int tok = ids[row];
  int d2 = d & ~1;
  float div = expf((float)d2 * (-9.210340371976184f / 256.0f));
  float ang = (float)s * div;
  float pe = (d & 1) ? cosf(ang) : sinf(ang);
  float v = emb[(size_t)tok * D_ + d] * 16.0f + pe;
  size_t o = (size_t)row * D_ + d;
  x[o] = v;
  ushort_t h, l;
  split_bf16(v, h, l);
  xh[o] = h; xl[o] = l;
}

// ---------------- MFMA flash attention (bf16x3, swapped-operand structure) ----------------
// Block = (b,h), 4 waves; wave w owns q rows [64w, 64w+64). KV tile = 32 keys.
// S^T = K.Q^T so the S-accumulator's C-layout (4 consecutive KEYS per lane reg)
// packs directly into P[q][key] LDS via 8B writes; PV^T = V^T.P reads P back as
// B-fragments with ds_read_b128. All LDS pitches 80B (16B-aligned, 2-way banks).
__global__ __launch_bounds__(256) void attn_kernel(const float* __restrict__ qkv,
                                                   ushort_t* __restrict__ ctxh,
                                                   ushort_t* __restrict__ ctxl) {
  __shared__ __align__(16) ushort_t sKh[32][40];
  __shared__ __align__(16) ushort_t sKl[32][40];
  __shared__ __align__(16) ushort_t sVh[32][40];   // V^T: [dh][key]
  __shared__ __align__(16) ushort_t sVl[32][40];
  __shared__ __align__(16) ushort_t sPh[4][64][40]; // per-wave P: [q_local][key]
  __shared__ __align__(16) ushort_t sPl[4][64][40];

  const int bh = blockIdx.x;
  const int b = bh >> 3, h = bh & 7;
  const int t = threadIdx.x;
  const int w = t >> 6, lane = t & 63;
  const int lr = lane & 15, g = lane >> 4;

  const float* __restrict__ base = qkv + (size_t)(b * S_) * 768 + h * 32;

  // Q as B-operand fragments (col q = 64w + ni*16 + lr, k dh = g*8 + j), pre-scaled.
  bf16x8 qh[4], ql[4];
  #pragma unroll
  for (int ni = 0; ni < 4; ++ni) {
    const float* qp = base + (size_t)(w * 64 + ni * 16 + lr) * 768 + g * 8;
    union { bf16x8 v; ushort_t u[8]; } Hh, Ll;
    #pragma unroll
    for (int j = 0; j < 8; ++j) {
      float qv = qp[j] * 0.17677669529663687f;  // 1/sqrt(32)
      split_bf16(qv, Hh.u[j], Ll.u[j]);
    }
    qh[ni] = Hh.v; ql[ni] = Ll.v;
  }

  f32x4 oacc[2][4] = {};
  float mrow[4] = {-3.0e38f, -3.0e38f, -3.0e38f, -3.0e38f};
  float lsum[4] = {0.f, 0.f, 0.f, 0.f};

  for (int kt = 0; kt < 8; ++kt) {
    __syncthreads();  // protect K/V from overwrite while prior tile in use
    {
      // stage K tile: thread (key=t>>3, c4=t&7) loads K[key][c4*4..+3]
      int key = t >> 3, c4 = t & 7;
      const float4 kv = *reinterpret_cast<const float4*>(
          base + (size_t)(kt * 32 + key) * 768 + 256 + c4 * 4);
      float kvv[4] = {kv.x, kv.y, kv.z, kv.w};
      ushort_t hk[4], lk[4];
      #pragma unroll
      for (int j = 0; j < 4; ++j) split_bf16(kvv[j], hk[j], lk[j]);
      *reinterpret_cast<uint2*>(&sKh[key][c4 * 4]) =
          make_uint2((unsigned)hk[0] | ((unsigned)hk[1] << 16),
                     (unsigned)hk[2] | ((unsigned)hk[3] << 16));
      *reinterpret_cast<uint2*>(&sKl[key][c4 * 4]) =
          make_uint2((unsigned)lk[0] | ((unsigned)lk[1] << 16),
                     (unsigned)lk[2] | ((unsigned)lk[3] << 16));
      // stage V^T: thread (dh=t&31, kq=t>>5) loads V[kq*4+kk][dh] -> VT[dh][kq*4..+3]
      int dh = t & 31, kq = t >> 5;
      ushort_t hv[4], lv[4];
      #pragma unroll
      for (int kk = 0; kk < 4; ++kk) {
        float vv = base[(size_t)(kt * 32 + kq * 4 + kk) * 768 + 512 + dh];
        split_bf16(vv, hv[kk], lv[kk]);
      }
      *reinterpret_cast<uint2*>(&sVh[dh][kq * 4]) =
          make_uint2((unsigned)hv[0] | ((unsigned)hv[1] << 16),
                     (unsigned)hv[2] | ((unsigned)hv[3] << 16));
      *reinterpret_cast<uint2*>(&sVl[dh][kq * 4]) =
          make_uint2((unsigned)lv[0] | ((unsigned)lv[1] << 16),
                     (unsigned)lv[2] | ((unsigned)lv[3] << 16));
    }
    __syncthreads();

    // ---- S^T = K.Q^T : D[key = x*16 + g*4 + i][q = ni*16 + lr] ----
    f32x4 sacc[2][4] = {};
    bf16x8 kfh[2], kfl[2];
    #pragma unroll
    for (int x = 0; x < 2; ++x) {
      kfh[x] = *reinterpret_cast<const bf16x8*>(&sKh[x * 16 + lr][g * 8]);
      kfl[x] = *reinterpret_cast<const bf16x8*>(&sKl[x * 16 + lr][g * 8]);
    }
    #pragma unroll
    for (int x = 0; x < 2; ++x) {
      #pragma unroll
      for (int ni = 0; ni < 4; ++ni) {
        sacc[x][ni] = __builtin_amdgcn_mfma_f32_16x16x32_bf16(kfh[x], qh[ni], sacc[x][ni], 0, 0, 0);
        sacc[x][ni] = __builtin_amdgcn_mfma_f32_16x16x32_bf16(kfl[x], qh[ni], sacc[x][ni], 0, 0, 0);
        sacc[x][ni] = __builtin_amdgcn_mfma_f32_16x16x32_bf16(kfh[x], ql[ni], sacc[x][ni], 0, 0, 0);
      }
    }

    // ---- online softmax per q-column; P -> LDS (packed 4-key 8B writes) ----
    #pragma unroll
    for (int ni = 0; ni < 4; ++ni) {
      float tm = sacc[0][ni][0];
      tm = fmaxf(tm, sacc[0][ni][1]); tm = fmaxf(tm, sacc[0][ni][2]); tm = fmaxf(tm, sacc[0][ni][3]);
      tm = fmaxf(tm, sacc[1][ni][0]); tm = fmaxf(tm, sacc[1][ni][1]);
      tm = fmaxf(tm, sacc[1][ni][2]); tm = fmaxf(tm, sacc[1][ni][3]);
      tm = fmaxf(tm, __shfl_xor(tm, 16));
      tm = fmaxf(tm, __shfl_xor(tm, 32));
      float mn = fmaxf(mrow[ni], tm);
      float sc = __expf(mrow[ni] - mn);    // exactly 1.0f when max unchanged
      mrow[ni] = mn;
      float ps = 0.f;
      #pragma unroll
      for (int x = 0; x < 2; ++x) {
        ushort_t ph[4], pl[4];
        #pragma unroll
        for (int i = 0; i < 4; ++i) {
          float p = __expf(sacc[x][ni][i] - mn);
          ps += p;
          split_bf16(p, ph[i], pl[i]);
        }
        *reinterpret_cast<uint2*>(&sPh[w][ni * 16 + lr][x * 16 + g * 4]) =
            make_uint2((unsigned)ph[0] | ((unsigned)ph[1] << 16),
                       (unsigned)ph[2] | ((unsigned)ph[3] << 16));
        *reinterpret_cast<uint2*>(&sPl[w][ni * 16 + lr][x * 16 + g * 4]) =
            make_uint2((unsigned)pl[0] | ((unsigned)pl[1] << 16),
                       (unsigned)pl[2] | ((unsigned)pl[3] << 16));
      }
      ps += __shfl_xor(ps, 16);
      ps += __shfl_xor(ps, 32);
      lsum[ni] = lsum[ni] * sc + ps;
      #pragma unroll
      for (int mt = 0; mt < 2; ++mt)
        #pragma unroll
        for (int i = 0; i < 4; ++i) oacc[mt][ni][i] *= sc;
    }

    // ---- O^T += V^T . P  (wave-local P; compiler orders ds_write->ds_read) ----
    bf16x8 pbh[4], pbl[4];
    #pragma unroll
    for (int ni = 0; ni < 4; ++ni) {
      pbh[ni] = *reinterpret_cast<const bf16x8*>(&sPh[w][ni * 16 + lr][g * 8]);
      pbl[ni] = *reinterpret_cast<const bf16x8*>(&sPl[w][ni * 16 + lr][g * 8]);
    }
    #pragma unroll
    for (int mt = 0; mt < 2; ++mt) {
      bf16x8 vfh = *reinterpret_cast<const bf16x8*>(&sVh[mt * 16 + lr][g * 8]);
      bf16x8 vfl = *reinterpret_cast<const bf16x8*>(&sVl[mt * 16 + lr][g * 8]);
      #pragma unroll
      for (int ni = 0; ni < 4; ++ni) {
        oacc[mt][ni] = __builtin_amdgcn_mfma_f32_16x16x32_bf16(vfh, pbh[ni], oacc[mt][ni], 0, 0, 0);
        oacc[mt][ni] = __builtin_amdgcn_mfma_f32_16x16x32_bf16(vfl, pbh[ni], oacc[mt][ni], 0, 0, 0);
        oacc[mt][ni] = __builtin_amdgcn_mfma_f32_16x16x32_bf16(vfh, pbl[ni], oacc[mt][ni], 0, 0, 0);
      }
    }
  }

  // ---- finalize: /l, write ctx bf16 pairs (4 consecutive dh packed per 8B) ----
  #pragma unroll
  for (int ni = 0; ni < 4; ++ni) {
    float inv = 1.0f / lsum[ni];
    int q = w * 64 + ni * 16 + lr;
    size_t rowo = (size_t)(b * S_ + q) * D_ + h * 32;
    #pragma unroll
    for (int mt = 0; mt < 2; ++mt) {
      ushort_t hh[4], ll[4];
      #pragma unroll
      for (int i = 0; i < 4; ++i) {
        float v = oacc[mt][ni][i] * inv;
        split_bf16(v, hh[i], ll[i]);
      }
      int col = mt * 16 + g * 4;
      *reinterpret_cast<uint2*>(&ctxh[rowo + col]) =
          make_uint2((unsigned)hh[0] | ((unsigned)hh[1] << 16),
                     (unsigned)hh[2] | ((unsigned)hh[3] << 16));
      *reinterpret_cast<uint2*>(&ctxl[rowo + col]) =
          make_uint2((unsigned)ll[0] | ((unsigned)ll[1] << 16),
                     (unsigned)ll[2] | ((unsigned)ll[3] << 16));
    }
  }
}

// ---------------- residual add + layernorm ----------------
template<bool PAIRS>
__global__ __launch_bounds__(256) void addln_kernel(const float* __restrict__ x,
                                                    const float* __restrict__ y,
                                                    const float* __restrict__ gam,
                                                    const float* __restrict__ bet,
                                                    float* __restrict__ out,
                                                    ushort_t* __restrict__ oh,
                                                    ushort_t* __restrict__ ol) {
  __shared__ float sh[8];
  int row = blockIdx.x, d = threadIdx.x;
  float v = x[(size_t)row * D_ + d];
  if (y) v += y[(size_t)row * D_ + d];
  float mean = blockReduceSum256(v, sh) * (1.0f / D_);
  float diff = v - mean;
  float var = blockReduceSum256(diff * diff, sh) * (1.0f / D_);
  float r = diff * rsqrtf(var + 1e-5f) * gam[d] + bet[d];
  size_t o = (size_t)row * D_ + d;
  out[o] = r;
  if (PAIRS) {
    ushort_t h, l;
    split_bf16(r, h, l);
    oh[o] = h; ol[o] = l;
  }
}

// ---------------- masked mean pool ----------------
__global__ __launch_bounds__(256) void pooled_kernel(const float* __restrict__ hidden,
                                                     const float* __restrict__ mask,
                                                     float* __restrict__ pooled) {
  int b = blockIdx.x, d = threadIdx.x;
  float s = 0.0f, msum = 0.0f;
  for (int t = 0; t < S_; ++t) {
    float mk = mask[b * S_ + t];
    s += hidden[(size_t)(b * S_ + t) * D_ + d] * mk;
    msum += mk;
  }
  pooled[b * D_ + d] = s / (msum + 1e-8f);
}

// ---------------- normalize pooled queries ----------------
__global__ __launch_bounds__(256) void qnorm_kernel(const float* __restrict__ pooled,
                                                    float* __restrict__ qn) {
  __shared__ float sh[8];
  int b = blockIdx.x, d = threadIdx.x;
  float v = pooled[b * D_ + d];
  float ss = blockReduceSum256(v * v, sh);
  qn[b * D_ + d] = v / fmaxf(sqrtf(ss), 1e-8f);
}

// ---------------- per-key inverse norms ----------------
__global__ __launch_bounds__(64) void invnorm_kernel(const float* __restrict__ keys,
                                                     float* __restrict__ invn) {
  int row = blockIdx.x, t = threadIdx.x;
  float4 v = *reinterpret_cast<const float4*>(keys + (size_t)row * D_ + t * 4);
  float ss = v.x * v.x + v.y * v.y + v.z * v.z + v.w * v.w;
  #pragma unroll
  for (int o = 32; o; o >>= 1) ss += __shfl_down(ss, o);
  if (t == 0) invn[row] = 1.0f / fmaxf(sqrtf(ss), 1e-8f);
}

// ================= threshold top-k (exact, no iterative extraction over data) ==========
__global__ __launch_bounds__(256) void chunkmax_kernel(const float* __restrict__ sims,
                                                       unsigned long long* __restrict__ chm) {
  __shared__ unsigned long long wk[4];
  int row = blockIdx.x >> 7, c = blockIdx.x & 127;
  int t = threadIdx.x;
  int base = c * CHA_;
  int end = base + CHA_; if (end > MEM_) end = MEM_;
  const float* src = sims + (size_t)row * MEM_;
  unsigned long long best = 0ull;
  for (int i = base + t; i < end; i += 256) {
    unsigned long long key =
        ((unsigned long long)f2key(src[i]) << 32) | (unsigned int)~(unsigned int)i;
    best = ullmax(best, key);
  }
  #pragma unroll
  for (int o = 32; o; o >>= 1) best = ullmax(best, __shfl_down(best, o));
  int lane = t & 63, w = t >> 6;
  if (lane == 0) wk[w] = best;
  __syncthreads();
  if (t == 0) chm[row * NCHA_ + c] = ullmax(ullmax(wk[0], wk[1]), ullmax(wk[2], wk[3]));
}

__global__ __launch_bounds__(128) void tau_kernel(const unsigned long long* __restrict__ chm,
                                                  const int* __restrict__ topk,
                                                  unsigned long long* __restrict__ tau,
                                                  unsigned int* __restrict__ cnt) {
  __shared__ unsigned long long keys[NCHA_];
  int row = blockIdx.x, t = threadIdx.x;
  int k = *topk; if (k > 64) k = 64; if (k < 1) k = 1;
  keys[t] = chm[row * NCHA_ + t];
  __syncthreads();
  unsigned long long mine = keys[t];
  int rank = 0;
  for (int j = 0; j < NCHA_; ++j) rank += (keys[j] > mine) ? 1 : 0;
  if (rank == k - 1) tau[row] = mine;
  if (t == 0) cnt[row] = 0u;
}

__global__ __launch_bounds__(256) void collect_kernel(const float* __restrict__ sims,
                                                      const unsigned long long* __restrict__ tau,
                                                      unsigned long long* __restrict__ cand,
                                                      unsigned int* __restrict__ cnt) {
  int row = blockIdx.x >> 7, c = blockIdx.x & 127;
  int t = threadIdx.x;
  unsigned long long tv = tau[row];
  int base = c * CHA_;
  int end = base + CHA_; if (end > MEM_) end = MEM_;
  const float* src = sims + (size_t)row * MEM_;
  for (int i = base + t; i < end; i += 256) {
    unsigned long long key =
        ((unsigned long long)f2key(src[i]) << 32) | (unsigned int)~(unsigned int)i;
    if (key >= tv) {
      unsigned int pos = atomicAdd(&cnt[row], 1u);
      if (pos < CAP_) cand[(size_t)row * CAP_ + pos] = key;
    }
  }
}

__global__ __launch_bounds__(256) void final_topk(const unsigned long long* __restrict__ cand,
                                                  const unsigned int* __restrict__ cnt,
                                                  const int* __restrict__ topk,
                                                  float* __restrict__ topv,
                                                  int* __restrict__ topi) {
  __shared__ unsigned long long buf[CAP_];
  __shared__ unsigned long long wk[4];
  int row = blockIdx.x, t = threadIdx.x;
  int k = *topk; if (k > 64) k = 64; if (k < 1) k = 1;
  int n = (int)cnt[row]; if (n > CAP_) n = CAP_;
  for (int i = t; i < n; i += 256) buf[i] = cand[(size_t)row * CAP_ + i];
  __syncthreads();
  int lane = t & 63, w = t >> 6;
  for (int iter = 0; iter < k; ++iter) {
    unsigned long long best = 0ull;
    for (int i = t; i < n; i += 256) best = ullmax(best, buf[i]);
    #pragma unroll
    for (int o = 32; o; o >>= 1) best = ullmax(best, __shfl_down(best, o));
    if (lane == 0) wk[w] = best;
    __syncthreads();
    best = ullmax(ullmax(wk[0], wk[1]), ullmax(wk[2], wk[3]));
    if (t == 0) {
      topv[row * 64 + iter] = key2f((unsigned int)(best >> 32));
      topi[row * 64 + iter] = (int)~(unsigned int)best;
    }
    for (int i = t; i < n; i += 256) if (buf[i] == best) buf[i] = 0ull;
    __syncthreads();
  }
}

// ---------------- weighted aggregate of retrieved values ----------------
__global__ __launch_bounds__(256) void retrieve_kernel(const float* __restrict__ topv,
                                                       const int* __restrict__ topi,
                                                       const int* __restrict__ topk,
                                                       const float* __restrict__ vals,
                                                       const float* __restrict__ conf,
                                                       float* __restrict__ retr) {
  int b = blockIdx.x, d = threadIdx.x;
  int k = *topk; if (k > 64) k = 64; if (k < 1) k = 1;
  float acc = 0.0f, wsum = 0.0f;
  for (int i = 0; i < k; ++i) {
    int idx = topi[b * 64 + i];
    float w = fmaxf(conf[idx], 1e-4f) * topv[b * 64 + i];
    wsum += w;
    acc += w * vals[(size_t)idx * D_ + d];
  }
  retr[b * D_ + d] = acc / (wsum + 1e-8f);
}

// ---------------- gate MLP + fuse + classifier ----------------
__global__ __launch_bounds__(256) void head_kernel(const float* __restrict__ pooled,
                                                   const float* __restrict__ retr,
                                                   const float* __restrict__ gw1,
                                                   const float* __restrict__ gb1,
                                                   const float* __restrict__ gw2,
                                                   const float* __restrict__ gb2,
                                                   const float* __restrict__ cw,
                                                   const float* __restrict__ cb,
                                                   float* __restrict__ out) {
  __shared__ float pl[D_], hh[D_], fu[D_], sh[8];
  int b = blockIdx.x, d = threadIdx.x;
  pl[d] = pooled[b * D_ + d];
  __syncthreads();
  float a = gb1[d];
  for (int e = 0; e < D_; ++e) a += pl[e] * gw1[e * D_ + d];
  hh[d] = fmaxf(a, 0.0f);
  float gsum = blockReduceSum256(hh[d] * gw2[d], sh);
  float g = 1.0f / (1.0f + expf(-(gsum + gb2[0])));
  fu[d] = g * retr[b * D_ + d] + (1.0f - g) * pl[d];
  __syncthreads();
  if (d < 16) {
    float o = cb[d];
    for (int e = 0; e < D_; ++e) o += fu[e] * cw[e * 16 + d];
    out[b * 16 + d] = o;
  }
}

// ---------------- launcher ----------------
extern "C" void kernel_launch(void* const* d_in, const int* in_sizes, int n_in,
                              void* d_out, int out_size, void* d_ws, size_t ws_size,
                              hipStream_t stream) {
  const int*   ids   = (const int*)d_in[0];
  const float* mask  = (const float*)d_in[1];
  const int*   topk  = (const int*)d_in[2];
  const float* emb   = (const float*)d_in[3];
  const float* qkv_w = (const float*)d_in[4];
  const float* qkv_b = (const float*)d_in[5];
  const float* out_w = (const float*)d_in[6];
  const float* out_b = (const float*)d_in[7];
  const float* ln1_s = (const float*)d_in[8];
  const float* ln1_b = (const float*)d_in[9];
  const float* ff_w1 = (const float*)d_in[10];
  const float* ff_b1 = (const float*)d_in[11];
  const float* ff_w2 = (const float*)d_in[12];
  const float* ff_b2 = (const float*)d_in[13];
  const float* ln2_s = (const float*)d_in[14];
  const float* ln2_b = (const float*)d_in[15];
  const float* lnf_s = (const float*)d_in[16];
  const float* lnf_b = (const float*)d_in[17];
  const float* gw1   = (const float*)d_in[18];
  const float* gb1   = (const float*)d_in[19];
  const float* gw2   = (const float*)d_in[20];
  const float* gb2   = (const float*)d_in[21];
  const float* cw    = (const float*)d_in[22];
  const float* cb    = (const float*)d_in[23];
  const float* mkeys = (const float*)d_in[24];
  const float* mvals = (const float*)d_in[25];
  const float* mconf = (const float*)d_in[26];
  float* out = (float*)d_out;

  // ---- workspace layout ----
  float* ws   = (float*)d_ws;
  float* X    = ws;                                   //  4,194,304 f
  float* Y    = X + 4194304;                          //  4,194,304 f
  float* R    = Y + 4194304;                          // 16,777,216 f (qkv f32 / ff1 pairs / sims)
  ushort_t* XH   = (ushort_t*)(R + 16777216);         //  4,194,304 sh
  ushort_t* XL   = XH + 4194304;
  ushort_t* CTXH = XL + 4194304;
  ushort_t* CTXL = CTXH + 4194304;
  ushort_t* WP   = CTXL + 4194304;                    //  3,145,728 sh (weight pairs)
  float* POOL = (float*)(WP + 3145728);               //  16384 f
  float* QN   = POOL + 16384;
  float* INVN = QN + 16384;                           //  200,000 f
  float* TOPV = INVN + 200000;                        //  4096 f
  int*   TOPI = (int*)(TOPV + 4096);
  float* RETR = (float*)(TOPI + 4096);                //  16384 f
  unsigned long long* CANDK = (unsigned long long*)(RETR + 16384);  // 64*2048 u64
  unsigned long long* CHM   = CANDK + (size_t)B_ * CAP_;            // 64*128 u64
  unsigned long long* TAU   = CHM + B_ * NCHA_;                     // 64 u64
  unsigned int*       CNT   = (unsigned int*)(TAU + B_);            // 64 u32

  // aliases over R (lifetimes disjoint)
  float*    QKVOUT = R;                  // [16384][768] f32
  ushort_t* BIGH   = (ushort_t*)R;       // [16384][1024] bf16 hi
  ushort_t* BIGL   = BIGH + 16777216;    // [16384][1024] bf16 lo
  float*    SIMS   = R;                  // [64][200000] f32

  const size_t LW = 1572864;  // per-layer weight-pair stride (shorts)
  #define WPTR(l, off) (WP + (size_t)(l) * LW + (off))

  // ---- weight prep: transpose + bf16 hi/lo split (once) ----
  for (int l = 0; l < 2; ++l) {
    transcvt_kernel<<<dim3(24, 8), 256, 0, stream>>>(qkv_w + (size_t)l * 196608,
                                                     WPTR(l, 0), WPTR(l, 196608), 256, 768);
    transcvt_kernel<<<dim3(8, 8), 256, 0, stream>>>(out_w + (size_t)l * 65536,
                                                    WPTR(l, 393216), WPTR(l, 458752), 256, 256);
    transcvt_kernel<<<dim3(32, 8), 256, 0, stream>>>(ff_w1 + (size_t)l * 262144,
                                                     WPTR(l, 524288), WPTR(l, 786432), 256, 1024);
    transcvt_kernel<<<dim3(8, 32), 256, 0, stream>>>(ff_w2 + (size_t)l * 262144,
                                                     WPTR(l, 1048576), WPTR(l, 1310720), 1024, 256);
  }

  embed_kernel<<<ROWS_, 256, 0, stream>>>(ids, emb, X, XH, XL);

  for (int l = 0; l < 2; ++l) {
    gemm16<0, true, 0><<<dim3(6, 128), 256, 0, stream>>>(
        XH, XL, WPTR(l, 0), WPTR(l, 196608), qkv_b + l * 768,
        QKVOUT, nullptr, nullptr, ROWS_, 768, 256);
    attn_kernel<<<B_ * H_, 256, 0, stream>>>(QKVOUT, CTXH, CTXL);
    gemm16<0, true, 0><<<dim3(2, 128), 256, 0, stream>>>(
        CTXH, CTXL, WPTR(l, 393216), WPTR(l, 458752), out_b + l * 256,
        Y, nullptr, nullptr, ROWS_, 256, 256);
    addln_kernel<true><<<ROWS_, 256, 0, stream>>>(X, Y, ln1_s + l * 256, ln1_b + l * 256,
                                                  X, XH, XL);
    gemm16<1, true, 1><<<dim3(8, 128), 256, 0, stream>>>(
        XH, XL, WPTR(l, 524288), WPTR(l, 786432), ff_b1 + l * 1024,
        nullptr, BIGH, BIGL, ROWS_, 1024, 256);
    gemm16<0, true, 0><<<dim3(2, 128), 256, 0, stream>>>(
        BIGH, BIGL, WPTR(l, 1048576), WPTR(l, 1310720), ff_b2 + l * 256,
        Y, nullptr, nullptr, ROWS_, 256, 1024);
    addln_kernel<true><<<ROWS_, 256, 0, stream>>>(X, Y, ln2_s + l * 256, ln2_b + l * 256,
                                                  X, XH, XL);
  }

  addln_kernel<false><<<ROWS_, 256, 0, stream>>>(X, nullptr, lnf_s, lnf_b, Y, nullptr, nullptr);
  pooled_kernel<<<B_, 256, 0, stream>>>(Y, mask, POOL);
  qnorm_kernel<<<B_, 256, 0, stream>>>(POOL, QN);
  invnorm_kernel<<<MEM_, 64, 0, stream>>>(mkeys, INVN);
  gemm_bt<64, 1, 4, 0, false, true><<<dim3((MEM_ + 255) / 256, 1), 256, 0, stream>>>(
      QN, mkeys, nullptr, INVN, SIMS, 64, MEM_, 256);

  chunkmax_kernel<<<B_ * NCHA_, 256, 0, stream>>>(SIMS, CHM);
  tau_kernel<<<B_, 128, 0, stream>>>(CHM, topk, TAU, CNT);
  collect_kernel<<<B_ * NCHA_, 256, 0, stream>>>(SIMS, TAU, CANDK, CNT);
  final_topk<<<B_, 256, 0, stream>>>(CANDK, CNT, topk, TOPV, TOPI);

  retrieve_kernel<<<B_, 256, 0, stream>>>(TOPV, TOPI, topk, mvals, mconf, RETR);
  head_kernel<<<B_, 256, 0, stream>>>(POOL, RETR, gw1, gb1, gw2, gb2, cw, cb, out);
  #undef WPTR
}

// Round 7
// 720.756 us; speedup vs baseline: 11.2451x; 1.0163x over previous
//
#include <hip/hip_runtime.h>
#include <math.h>

// ---------------- constants ----------------
#define B_   64
#define S_   256
#define D_   256
#define H_   8
#define DH_  32
#define FF_  1024
#define MEM_ 200000
#define ROWS_ (B_ * S_)   // 16384
#define NCHB_ 782         // sims blocks per row = chunk-max slots (ceil(MEM/256))
#define NCHA_ 128         // collect chunking
#define CHA_  1563        // ceil(MEM_/NCHA_)
#define CAP_  2048        // candidate cap per row

typedef float f32x4 __attribute__((ext_vector_type(4)));
typedef __bf16 bf16x8 __attribute__((ext_vector_type(8)));
typedef unsigned short ushort_t;
typedef unsigned long long u64_t;

// ---------------- helpers ----------------
__device__ __forceinline__ float blockReduceSum256(float v, float* sh) {
  #pragma unroll
  for (int o = 32; o; o >>= 1) v += __shfl_down(v, o);
  int lane = threadIdx.x & 63, w = threadIdx.x >> 6;
  __syncthreads();
  if (lane == 0) sh[w] = v;
  __syncthreads();
  return sh[0] + sh[1] + sh[2] + sh[3];
}

__device__ __forceinline__ unsigned int f2key(float f) {
  unsigned int b = __float_as_uint(f);
  return (b & 0x80000000u) ? ~b : (b | 0x80000000u);
}
__device__ __forceinline__ float key2f(unsigned int u) {
  unsigned int b = (u & 0x80000000u) ? (u & 0x7FFFFFFFu) : ~u;
  return __uint_as_float(b);
}
__device__ __forceinline__ u64_t ullmax(u64_t a, u64_t b) { return a > b ? a : b; }

__device__ __forceinline__ ushort_t f32_bf16_rn(float x) {
  unsigned int u = __float_as_uint(x);
  u += 0x7FFFu + ((u >> 16) & 1u);
  return (ushort_t)(u >> 16);
}
__device__ __forceinline__ float bf16_f32(ushort_t h) {
  return __uint_as_float((unsigned int)h << 16);
}
__device__ __forceinline__ void split_bf16(float v, ushort_t& h, ushort_t& l) {
  h = f32_bf16_rn(v);
  l = f32_bf16_rn(v - bf16_f32(h));
}

// swizzled byte offsets into a [R][32] bf16 LDS tile
__device__ __forceinline__ int swz8(int row, int kq) {
  return row * 64 + ((((kq >> 1) ^ ((row >> 1) & 3)) << 4)) + (kq & 1) * 8;
}
__device__ __forceinline__ int swz16(int row, int kg) {
  return row * 64 + (((kg ^ ((row >> 1) & 3)) << 4));
}

// direct global->LDS 16B copy
__device__ __forceinline__ void gload_lds16(const void* gsrc, void* ldst) {
  __builtin_amdgcn_global_load_lds(
      (const __attribute__((address_space(1))) unsigned int*)gsrc,
      (__attribute__((address_space(3))) unsigned int*)(unsigned int)(unsigned long long)ldst,
      16, 0, 0);
}

// stage a [128 x 32] bf16 tile from linear global into swizzled LDS (pre-swizzled source)
__device__ __forceinline__ void stage16(const ushort_t* __restrict__ G, int ldg,
                                        int base_row, int k0, char* lds, int t) {
  #pragma unroll
  for (int r = 0; r < 2; ++r) {
    int idx = r * 256 + t;
    int row = idx >> 2, kg = idx & 3;
    int kg_g = kg ^ ((row >> 1) & 3);
    const void* src = G + (size_t)(base_row + row) * ldg + k0 + kg_g * 8;
    void* dst = lds + (size_t)(idx & ~63) * 16;
    gload_lds16(src, dst);
  }
}

// f32->bf16-pair staging (sims A side)
template<int NITER>
__device__ __forceinline__ void stage_bf16x3(const float* __restrict__ G, int ldg,
                                             int base_row, int k0, int max_row,
                                             char* __restrict__ sh, char* __restrict__ sl,
                                             int t) {
  #pragma unroll
  for (int r = 0; r < NITER; ++r) {
    int idx = r * 256 + t;
    int row = idx >> 3, kq = idx & 7;
    int gr = base_row + row; if (gr > max_row) gr = max_row;
    const float4 v = *reinterpret_cast<const float4*>(G + (size_t)gr * ldg + k0 + kq * 4);
    float vv[4] = {v.x, v.y, v.z, v.w};
    ushort_t h[4], l[4];
    #pragma unroll
    for (int j = 0; j < 4; ++j) split_bf16(vv[j], h[j], l[j]);
    uint2 hp = make_uint2((unsigned)h[0] | ((unsigned)h[1] << 16),
                          (unsigned)h[2] | ((unsigned)h[3] << 16));
    uint2 lp = make_uint2((unsigned)l[0] | ((unsigned)l[1] << 16),
                          (unsigned)l[2] | ((unsigned)l[3] << 16));
    int b8 = swz8(row, kq);
    *reinterpret_cast<uint2*>(sh + b8) = hp;
    *reinterpret_cast<uint2*>(sl + b8) = lp;
  }
}

// ---------------- bf16x3 MFMA GEMM on pre-split hi/lo inputs ----------------
template<int ACT, bool HAS_BIAS, int OUTMODE>
__global__ __launch_bounds__(256) void gemm16(const ushort_t* __restrict__ AH,
                                              const ushort_t* __restrict__ AL,
                                              const ushort_t* __restrict__ BH,
                                              const ushort_t* __restrict__ BL,
                                              const float* __restrict__ bias,
                                              float* __restrict__ C,
                                              ushort_t* __restrict__ CH,
                                              ushort_t* __restrict__ CL,
                                              int M, int N, int K) {
  __shared__ __align__(16) char sAh[128 * 64];
  __shared__ __align__(16) char sAl[128 * 64];
  __shared__ __align__(16) char sBh[128 * 64];
  __shared__ __align__(16) char sBl[128 * 64];
  int t = threadIdx.x;
  int m0 = blockIdx.y * 128, n0 = blockIdx.x * 128;
  int wid = t >> 6, lane = t & 63;
  int wr = wid >> 1, wc = wid & 1;
  int lr = lane & 15, kg = lane >> 4;
  f32x4 acc[4][4] = {};
  for (int k0 = 0; k0 < K; k0 += 32) {
    stage16(AH, K, m0, k0, sAh, t);
    stage16(AL, K, m0, k0, sAl, t);
    stage16(BH, K, n0, k0, sBh, t);
    stage16(BL, K, n0, k0, sBl, t);
    __syncthreads();
    bf16x8 ah[4], al[4];
    #pragma unroll
    for (int mi = 0; mi < 4; ++mi) {
      int row = wr * 64 + mi * 16 + lr;
      int ab = swz16(row, kg);
      ah[mi] = *reinterpret_cast<const bf16x8*>(sAh + ab);
      al[mi] = *reinterpret_cast<const bf16x8*>(sAl + ab);
    }
    #pragma unroll
    for (int ni = 0; ni < 4; ++ni) {
      int rb = wc * 64 + ni * 16 + lr;
      int bb = swz16(rb, kg);
      bf16x8 bh = *reinterpret_cast<const bf16x8*>(sBh + bb);
      bf16x8 bl = *reinterpret_cast<const bf16x8*>(sBl + bb);
      #pragma unroll
      for (int mi = 0; mi < 4; ++mi) {
        acc[mi][ni] = __builtin_amdgcn_mfma_f32_16x16x32_bf16(ah[mi], bh, acc[mi][ni], 0, 0, 0);
        acc[mi][ni] = __builtin_amdgcn_mfma_f32_16x16x32_bf16(al[mi], bh, acc[mi][ni], 0, 0, 0);
        acc[mi][ni] = __builtin_amdgcn_mfma_f32_16x16x32_bf16(ah[mi], bl, acc[mi][ni], 0, 0, 0);
      }
    }
    __syncthreads();
  }
  #pragma unroll
  for (int mi = 0; mi < 4; ++mi) {
    #pragma unroll
    for (int ni = 0; ni < 4; ++ni) {
      int row0 = m0 + wr * 64 + mi * 16 + kg * 4;
      int col  = n0 + wc * 64 + ni * 16 + lr;
      float b = HAS_BIAS ? bias[col] : 0.0f;
      #pragma unroll
      for (int i = 0; i < 4; ++i) {
        float v = acc[mi][ni][i] + b;
        if (ACT == 1) v = 0.5f * v * (1.0f + erff(v * 0.7071067811865476f));
        size_t o = (size_t)(row0 + i) * N + col;
        if (OUTMODE == 0) {
          C[o] = v;
        } else {
          ushort_t h, l;
          split_bf16(v, h, l);
          CH[o] = h; CL[o] = l;
        }
      }
    }
  }
}

// ---------------- sims GEMM: [64,MEM] = QN @ keys^T with fused invnorm + chunk-max ----------------
// 64 rows x 256 cols per block, 4 waves (each 64q x 64key). Per-key sumsq accumulated
// deterministically in psum[row][8] during B staging; invn applied in epilogue; per-block
// per-q chunk max written to CHM[q][block] (no separate invnorm / chunkmax passes).
__global__ __launch_bounds__(256) void sims_gemm(const float* __restrict__ QN,
                                                 const float* __restrict__ keys,
                                                 float* __restrict__ sims,
                                                 u64_t* __restrict__ chm) {
  __shared__ __align__(16) char sAh[64 * 64];
  __shared__ __align__(16) char sAl[64 * 64];
  __shared__ __align__(16) char sBh[256 * 64];
  __shared__ __align__(16) char sBl[256 * 64];
  __shared__ float psum[256][8];
  __shared__ u64_t wmaxl[4][64];
  int t = threadIdx.x;
  int n0 = blockIdx.x * 256;
  int wid = t >> 6, lane = t & 63;
  int lr = lane & 15, kg = lane >> 4;
  // zero my psum slots (thread-owned across all K-steps; no barrier needed)
  #pragma unroll
  for (int r = 0; r < 8; ++r) {
    int idx = r * 256 + t;
    psum[idx >> 3][idx & 7] = 0.0f;
  }
  f32x4 acc[4][4] = {};
  for (int k0 = 0; k0 < 256; k0 += 32) {
    stage_bf16x3<2>(QN, 256, 0, k0, 63, sAh, sAl, t);
    // B staging with sumsq partials
    #pragma unroll
    for (int r = 0; r < 8; ++r) {
      int idx = r * 256 + t;
      int row = idx >> 3, kq = idx & 7;
      int gr = n0 + row; if (gr > MEM_ - 1) gr = MEM_ - 1;
      const float4 v = *reinterpret_cast<const float4*>(keys + (size_t)gr * 256 + k0 + kq * 4);
      psum[row][kq] += v.x * v.x + v.y * v.y + v.z * v.z + v.w * v.w;
      float vv[4] = {v.x, v.y, v.z, v.w};
      ushort_t h[4], l[4];
      #pragma unroll
      for (int j = 0; j < 4; ++j) split_bf16(vv[j], h[j], l[j]);
      int b8 = swz8(row, kq);
      *reinterpret_cast<uint2*>(sBh + b8) =
          make_uint2((unsigned)h[0] | ((unsigned)h[1] << 16),
                     (unsigned)h[2] | ((unsigned)h[3] << 16));
      *reinterpret_cast<uint2*>(sBl + b8) =
          make_uint2((unsigned)l[0] | ((unsigned)l[1] << 16),
                     (unsigned)l[2] | ((unsigned)l[3] << 16));
    }
    __syncthreads();
    bf16x8 ah[4], al[4];
    #pragma unroll
    for (int mi = 0; mi < 4; ++mi) {
      int ab = swz16(mi * 16 + lr, kg);
      ah[mi] = *reinterpret_cast<const bf16x8*>(sAh + ab);
      al[mi] = *reinterpret_cast<const bf16x8*>(sAl + ab);
    }
    #pragma unroll
    for (int ni = 0; ni < 4; ++ni) {
      int bb = swz16(wid * 64 + ni * 16 + lr, kg);
      bf16x8 bh = *reinterpret_cast<const bf16x8*>(sBh + bb);
      bf16x8 bl = *reinterpret_cast<const bf16x8*>(sBl + bb);
      #pragma unroll
      for (int mi = 0; mi < 4; ++mi) {
        acc[mi][ni] = __builtin_amdgcn_mfma_f32_16x16x32_bf16(ah[mi], bh, acc[mi][ni], 0, 0, 0);
        acc[mi][ni] = __builtin_amdgcn_mfma_f32_16x16x32_bf16(al[mi], bh, acc[mi][ni], 0, 0, 0);
        acc[mi][ni] = __builtin_amdgcn_mfma_f32_16x16x32_bf16(ah[mi], bl, acc[mi][ni], 0, 0, 0);
      }
    }
    __syncthreads();
  }
  // epilogue: invn per col (my 4 cols), write sims, accumulate per-q chunk max
  float invn[4];
  #pragma unroll
  for (int ni = 0; ni < 4; ++ni) {
    int trow = wid * 64 + ni * 16 + lr;
    float ss = 0.f;
    #pragma unroll
    for (int kq = 0; kq < 8; ++kq) ss += psum[trow][kq];
    invn[ni] = 1.0f / fmaxf(sqrtf(ss), 1e-8f);
  }
  u64_t bq[4][4];
  #pragma unroll
  for (int mi = 0; mi < 4; ++mi)
    #pragma unroll
    for (int i = 0; i < 4; ++i) bq[mi][i] = 0ull;
  #pragma unroll
  for (int ni = 0; ni < 4; ++ni) {
    int col = n0 + wid * 64 + ni * 16 + lr;
    if (col < MEM_) {
      #pragma unroll
      for (int mi = 0; mi < 4; ++mi) {
        int q = mi * 16 + kg * 4;
        #pragma unroll
        for (int i = 0; i < 4; ++i) {
          float v = acc[mi][ni][i] * invn[ni];
          sims[(size_t)(q + i) * MEM_ + col] = v;
          u64_t key = ((u64_t)f2key(v) << 32) | (unsigned int)~(unsigned int)col;
          bq[mi][i] = ullmax(bq[mi][i], key);
        }
      }
    }
  }
  #pragma unroll
  for (int mi = 0; mi < 4; ++mi)
    #pragma unroll
    for (int i = 0; i < 4; ++i) {
      u64_t m = bq[mi][i];
      m = ullmax(m, __shfl_xor(m, 1));
      m = ullmax(m, __shfl_xor(m, 2));
      m = ullmax(m, __shfl_xor(m, 4));
      m = ullmax(m, __shfl_xor(m, 8));
      if (lr == 0) wmaxl[wid][mi * 16 + kg * 4 + i] = m;
    }
  __syncthreads();
  if (t < 64) {
    u64_t m = ullmax(ullmax(wmaxl[0][t], wmaxl[1][t]), ullmax(wmaxl[2][t], wmaxl[3][t]));
    chm[(size_t)t * NCHB_ + blockIdx.x] = m;
  }
}

// ---------------- all weight transposes + bf16 hi/lo split in ONE launch ----------------
__global__ __launch_bounds__(256) void transcvt_all(const float* __restrict__ qkv_w,
                                                    const float* __restrict__ out_w,
                                                    const float* __restrict__ ff_w1,
                                                    const float* __restrict__ ff_w2,
                                                    ushort_t* __restrict__ WP) {
  __shared__ float tile[32][33];
  int idx = blockIdx.x;
  int l = idx / 768, r = idx % 768;
  const float* src; ushort_t *dh, *dl; int R, C, bx, by;
  ushort_t* base = WP + (size_t)l * 1572864;
  if (r < 192)      { src = qkv_w + (size_t)l * 196608; dh = base;           dl = base + 196608;  R = 256;  C = 768;  bx = r % 24;        by = r / 24; }
  else if (r < 256) { src = out_w + (size_t)l * 65536;  dh = base + 393216;  dl = base + 458752;  R = 256;  C = 256;  bx = (r - 192) % 8; by = (r - 192) / 8; }
  else if (r < 512) { src = ff_w1 + (size_t)l * 262144; dh = base + 524288;  dl = base + 786432;  R = 256;  C = 1024; bx = (r - 256) % 32; by = (r - 256) / 32; }
  else              { src = ff_w2 + (size_t)l * 262144; dh = base + 1048576; dl = base + 1310720; R = 1024; C = 256;  bx = (r - 512) % 8; by = (r - 512) / 8; }
  int c0 = bx * 32, r0 = by * 32;
  int x = threadIdx.x & 31, y4 = (threadIdx.x >> 5) * 4;
  #pragma unroll
  for (int i = 0; i < 4; ++i) tile[y4 + i][x] = src[(size_t)(r0 + y4 + i) * C + c0 + x];
  __syncthreads();
  #pragma unroll
  for (int i = 0; i < 4; ++i) {
    float v = tile[x][y4 + i];
    ushort_t h, l2;
    split_bf16(v, h, l2);
    size_t o = (size_t)(c0 + y4 + i) * R + r0 + x;
    dh[o] = h; dl[o] = l2;
  }
}

// ---------------- embedding + positional encoding ----------------
__global__ __launch_bounds__(256) void embed_kernel(const int* __restrict__ ids,
                                                    const float* __restrict__ emb,
                                                    float* __restrict__ x,
                                                    ushort_t* __restrict__ xh,
                                                    ushort_t* __restrict__ xl) {
  int row = blockIdx.x;
  int d = threadIdx.x;
  int s = row & (S_ - 1);
  int tok = ids[row];
  int d2 = d & ~1;
  float div = expf((float)d2 * (-9.210340371976184f / 256.0f));
  float ang = (float)s * div;
  float pe = (d & 1) ? cosf(ang) : sinf(ang);
  float v = emb[(size_t)tok * D_ + d] * 16.0f + pe;
  size_t o = (size_t)row * D_ + d;
  x[o] = v;
  ushort_t h, l;
  split_bf16(v, h, l);
  xh[o] = h; xl[o] = l;
}

// ---------------- MFMA flash attention (bf16x3, swapped-operand structure) ----------------
__global__ __launch_bounds__(256) void attn_kernel(const float* __restrict__ qkv,
                                                   ushort_t* __restrict__ ctxh,
                                                   ushort_t* __restrict__ ctxl) {
  __shared__ __align__(16) ushort_t sKh[32][40];
  __shared__ __align__(16) ushort_t sKl[32][40];
  __shared__ __align__(16) ushort_t sVh[32][40];
  __shared__ __align__(16) ushort_t sVl[32][40];
  __shared__ __align__(16) ushort_t sPh[4][64][40];
  __shared__ __align__(16) ushort_t sPl[4][64][40];

  const int bh = blockIdx.x;
  const int b = bh >> 3, h = bh & 7;
  const int t = threadIdx.x;
  const int w = t >> 6, lane = t & 63;
  const int lr = lane & 15, g = lane >> 4;

  const float* __restrict__ base = qkv + (size_t)(b * S_) * 768 + h * 32;

  bf16x8 qh[4], ql[4];
  #pragma unroll
  for (int ni = 0; ni < 4; ++ni) {
    const float* qp = base + (size_t)(w * 64 + ni * 16 + lr) * 768 + g * 8;
    union { bf16x8 v; ushort_t u[8]; } Hh, Ll;
    #pragma unroll
    for (int j = 0; j < 8; ++j) {
      float qv = qp[j] * 0.17677669529663687f;
      split_bf16(qv, Hh.u[j], Ll.u[j]);
    }
    qh[ni] = Hh.v; ql[ni] = Ll.v;
  }

  f32x4 oacc[2][4] = {};
  float mrow[4] = {-3.0e38f, -3.0e38f, -3.0e38f, -3.0e38f};
  float lsum[4] = {0.f, 0.f, 0.f, 0.f};

  for (int kt = 0; kt < 8; ++kt) {
    __syncthreads();
    {
      int key = t >> 3, c4 = t & 7;
      const float4 kv = *reinterpret_cast<const float4*>(
          base + (size_t)(kt * 32 + key) * 768 + 256 + c4 * 4);
      float kvv[4] = {kv.x, kv.y, kv.z, kv.w};
      ushort_t hk[4], lk[4];
      #pragma unroll
      for (int j = 0; j < 4; ++j) split_bf16(kvv[j], hk[j], lk[j]);
      *reinterpret_cast<uint2*>(&sKh[key][c4 * 4]) =
          make_uint2((unsigned)hk[0] | ((unsigned)hk[1] << 16),
                     (unsigned)hk[2] | ((unsigned)hk[3] << 16));
      *reinterpret_cast<uint2*>(&sKl[key][c4 * 4]) =
          make_uint2((unsigned)lk[0] | ((unsigned)lk[1] << 16),
                     (unsigned)lk[2] | ((unsigned)lk[3] << 16));
      int dh = t & 31, kq = t >> 5;
      ushort_t hv[4], lv[4];
      #pragma unroll
      for (int kk = 0; kk < 4; ++kk) {
        float vv = base[(size_t)(kt * 32 + kq * 4 + kk) * 768 + 512 + dh];
        split_bf16(vv, hv[kk], lv[kk]);
      }
      *reinterpret_cast<uint2*>(&sVh[dh][kq * 4]) =
          make_uint2((unsigned)hv[0] | ((unsigned)hv[1] << 16),
                     (unsigned)hv[2] | ((unsigned)hv[3] << 16));
      *reinterpret_cast<uint2*>(&sVl[dh][kq * 4]) =
          make_uint2((unsigned)lv[0] | ((unsigned)lv[1] << 16),
                     (unsigned)lv[2] | ((unsigned)lv[3] << 16));
    }
    __syncthreads();

    f32x4 sacc[2][4] = {};
    bf16x8 kfh[2], kfl[2];
    #pragma unroll
    for (int x = 0; x < 2; ++x) {
      kfh[x] = *reinterpret_cast<const bf16x8*>(&sKh[x * 16 + lr][g * 8]);
      kfl[x] = *reinterpret_cast<const bf16x8*>(&sKl[x * 16 + lr][g * 8]);
    }
    #pragma unroll
    for (int x = 0; x < 2; ++x) {
      #pragma unroll
      for (int ni = 0; ni < 4; ++ni) {
        sacc[x][ni] = __builtin_amdgcn_mfma_f32_16x16x32_bf16(kfh[x], qh[ni], sacc[x][ni], 0, 0, 0);
        sacc[x][ni] = __builtin_amdgcn_mfma_f32_16x16x32_bf16(kfl[x], qh[ni], sacc[x][ni], 0, 0, 0);
        sacc[x][ni] = __builtin_amdgcn_mfma_f32_16x16x32_bf16(kfh[x], ql[ni], sacc[x][ni], 0, 0, 0);
      }
    }

    #pragma unroll
    for (int ni = 0; ni < 4; ++ni) {
      float tm = sacc[0][ni][0];
      tm = fmaxf(tm, sacc[0][ni][1]); tm = fmaxf(tm, sacc[0][ni][2]); tm = fmaxf(tm, sacc[0][ni][3]);
      tm = fmaxf(tm, sacc[1][ni][0]); tm = fmaxf(tm, sacc[1][ni][1]);
      tm = fmaxf(tm, sacc[1][ni][2]); tm = fmaxf(tm, sacc[1][ni][3]);
      tm = fmaxf(tm, __shfl_xor(tm, 16));
      tm = fmaxf(tm, __shfl_xor(tm, 32));
      float mn = fmaxf(mrow[ni], tm);
      float sc = __expf(mrow[ni] - mn);
      mrow[ni] = mn;
      float ps = 0.f;
      #pragma unroll
      for (int x = 0; x < 2; ++x) {
        ushort_t ph[4], pl[4];
        #pragma unroll
        for (int i = 0; i < 4; ++i) {
          float p = __expf(sacc[x][ni][i] - mn);
          ps += p;
          split_bf16(p, ph[i], pl[i]);
        }
        *reinterpret_cast<uint2*>(&sPh[w][ni * 16 + lr][x * 16 + g * 4]) =
            make_uint2((unsigned)ph[0] | ((unsigned)ph[1] << 16),
                       (unsigned)ph[2] | ((unsigned)ph[3] << 16));
        *reinterpret_cast<uint2*>(&sPl[w][ni * 16 + lr][x * 16 + g * 4]) =
            make_uint2((unsigned)pl[0] | ((unsigned)pl[1] << 16),
                       (unsigned)pl[2] | ((unsigned)pl[3] << 16));
      }
      ps += __shfl_xor(ps, 16);
      ps += __shfl_xor(ps, 32);
      lsum[ni] = lsum[ni] * sc + ps;
      #pragma unroll
      for (int mt = 0; mt < 2; ++mt)
        #pragma unroll
        for (int i = 0; i < 4; ++i) oacc[mt][ni][i] *= sc;
    }

    bf16x8 pbh[4], pbl[4];
    #pragma unroll
    for (int ni = 0; ni < 4; ++ni) {
      pbh[ni] = *reinterpret_cast<const bf16x8*>(&sPh[w][ni * 16 + lr][g * 8]);
      pbl[ni] = *reinterpret_cast<const bf16x8*>(&sPl[w][ni * 16 + lr][g * 8]);
    }
    #pragma unroll
    for (int mt = 0; mt < 2; ++mt) {
      bf16x8 vfh = *reinterpret_cast<const bf16x8*>(&sVh[mt * 16 + lr][g * 8]);
      bf16x8 vfl = *reinterpret_cast<const bf16x8*>(&sVl[mt * 16 + lr][g * 8]);
      #pragma unroll
      for (int ni = 0; ni < 4; ++ni) {
        oacc[mt][ni] = __builtin_amdgcn_mfma_f32_16x16x32_bf16(vfh, pbh[ni], oacc[mt][ni], 0, 0, 0);
        oacc[mt][ni] = __builtin_amdgcn_mfma_f32_16x16x32_bf16(vfl, pbh[ni], oacc[mt][ni], 0, 0, 0);
        oacc[mt][ni] = __builtin_amdgcn_mfma_f32_16x16x32_bf16(vfh, pbl[ni], oacc[mt][ni], 0, 0, 0);
      }
    }
  }

  #pragma unroll
  for (int ni = 0; ni < 4; ++ni) {
    float inv = 1.0f / lsum[ni];
    int q = w * 64 + ni * 16 + lr;
    size_t rowo = (size_t)(b * S_ + q) * D_ + h * 32;
    #pragma unroll
    for (int mt = 0; mt < 2; ++mt) {
      ushort_t hh[4], ll[4];
      #pragma unroll
      for (int i = 0; i < 4; ++i) {
        float v = oacc[mt][ni][i] * inv;
        split_bf16(v, hh[i], ll[i]);
      }
      int col = mt * 16 + g * 4;
      *reinterpret_cast<uint2*>(&ctxh[rowo + col]) =
          make_uint2((unsigned)hh[0] | ((unsigned)hh[1] << 16),
                     (unsigned)hh[2] | ((unsigned)hh[3] << 16));
      *reinterpret_cast<uint2*>(&ctxl[rowo + col]) =
          make_uint2((unsigned)ll[0] | ((unsigned)ll[1] << 16),
                     (unsigned)ll[2] | ((unsigned)ll[3] << 16));
    }
  }
}

// ---------------- residual add + layernorm ----------------
template<bool PAIRS>
__global__ __launch_bounds__(256) void addln_kernel(const float* __restrict__ x,
                                                    const float* __restrict__ y,
                                                    const float* __restrict__ gam,
                                                    const float* __restrict__ bet,
                                                    float* __restrict__ out,
                                                    ushort_t* __restrict__ oh,
                                                    ushort_t* __restrict__ ol) {
  __shared__ float sh[8];
  int row = blockIdx.x, d = threadIdx.x;
  float v = x[(size_t)row * D_ + d];
  if (y) v += y[(size_t)row * D_ + d];
  float mean = blockReduceSum256(v, sh) * (1.0f / D_);
  float diff = v - mean;
  float var = blockReduceSum256(diff * diff, sh) * (1.0f / D_);
  float r = diff * rsqrtf(var + 1e-5f) * gam[d] + bet[d];
  size_t o = (size_t)row * D_ + d;
  out[o] = r;
  if (PAIRS) {
    ushort_t h, l;
    split_bf16(r, h, l);
    oh[o] = h; ol[o] = l;
  }
}

// ---------------- masked mean pool + query normalize (fused) ----------------
__global__ __launch_bounds__(256) void pooledqnorm_kernel(const float* __restrict__ hidden,
                                                          const float* __restrict__ mask,
                                                          float* __restrict__ pooled,
                                                          float* __restrict__ qn) {
  __shared__ float sh[8];
  int b = blockIdx.x, d = threadIdx.x;
  float s = 0.0f, msum = 0.0f;
  for (int t = 0; t < S_; ++t) {
    float mk = mask[b * S_ + t];
    s += hidden[(size_t)(b * S_ + t) * D_ + d] * mk;
    msum += mk;
  }
  float pv = s / (msum + 1e-8f);
  pooled[b * D_ + d] = pv;
  float ss = blockReduceSum256(pv * pv, sh);
  qn[b * D_ + d] = pv / fmaxf(sqrtf(ss), 1e-8f);
}

// ---------------- tau: k-th largest of 782 chunk maxima per row ----------------
__global__ __launch_bounds__(256) void tau_kernel(const u64_t* __restrict__ chm,
                                                  const int* __restrict__ topk,
                                                  u64_t* __restrict__ tau,
                                                  unsigned int* __restrict__ cnt) {
  __shared__ u64_t keys[NCHB_];
  int row = blockIdx.x, t = threadIdx.x;
  int k = *topk; if (k > 64) k = 64; if (k < 1) k = 1;
  for (int i = t; i < NCHB_; i += 256) keys[i] = chm[(size_t)row * NCHB_ + i];
  __syncthreads();
  u64_t mine[4]; int rank[4] = {0, 0, 0, 0};
  #pragma unroll
  for (int o = 0; o < 4; ++o) {
    int i = o * 256 + t;
    mine[o] = (i < NCHB_) ? keys[i] : 0ull;
  }
  for (int j = 0; j < NCHB_; ++j) {
    u64_t kj = keys[j];
    #pragma unroll
    for (int o = 0; o < 4; ++o) rank[o] += (kj > mine[o]) ? 1 : 0;
  }
  #pragma unroll
  for (int o = 0; o < 4; ++o) {
    int i = o * 256 + t;
    if (i < NCHB_ && rank[o] == k - 1) tau[row] = mine[o];
  }
  if (t == 0) cnt[row] = 0u;
}

// ---------------- collect: gather all keys >= tau ----------------
__global__ __launch_bounds__(256) void collect_kernel(const float* __restrict__ sims,
                                                      const u64_t* __restrict__ tau,
                                                      u64_t* __restrict__ cand,
                                                      unsigned int* __restrict__ cnt) {
  int row = blockIdx.x >> 7, c = blockIdx.x & 127;
  int t = threadIdx.x;
  u64_t tv = tau[row];
  int base = c * CHA_;
  int end = base + CHA_; if (end > MEM_) end = MEM_;
  const float* src = sims + (size_t)row * MEM_;
  for (int i = base + t; i < end; i += 256) {
    u64_t key = ((u64_t)f2key(src[i]) << 32) | (unsigned int)~(unsigned int)i;
    if (key >= tv) {
      unsigned int pos = atomicAdd(&cnt[row], 1u);
      if (pos < CAP_) cand[(size_t)row * CAP_ + pos] = key;
    }
  }
}

// ---------------- tail: final top-k + retrieve + gate/classifier (fused) ----------------
__global__ __launch_bounds__(256) void tail_kernel(const u64_t* __restrict__ cand,
                                                   const unsigned int* __restrict__ cnt,
                                                   const int* __restrict__ topk,
                                                   const float* __restrict__ vals,
                                                   const float* __restrict__ conf,
                                                   const float* __restrict__ pooled,
                                                   const float* __restrict__ gw1,
                                                   const float* __restrict__ gb1,
                                                   const float* __restrict__ gw2,
                                                   const float* __restrict__ gb2,
                                                   const float* __restrict__ cw,
                                                   const float* __restrict__ cb,
                                                   float* __restrict__ out) {
  __shared__ u64_t buf[CAP_];
  __shared__ u64_t wk[4];
  __shared__ float tv[64];
  __shared__ int ti[64];
  __shared__ float pl[D_], hh[D_], fu[D_], sh[8];
  int b = blockIdx.x, t = threadIdx.x;
  int k = *topk; if (k > 64) k = 64; if (k < 1) k = 1;
  int n = (int)cnt[b]; if (n > CAP_) n = CAP_;
  for (int i = t; i < n; i += 256) buf[i] = cand[(size_t)b * CAP_ + i];
  __syncthreads();
  int lane = t & 63, w = t >> 6;
  for (int iter = 0; iter < k; ++iter) {
    u64_t best = 0ull;
    for (int i = t; i < n; i += 256) best = ullmax(best, buf[i]);
    #pragma unroll
    for (int o = 32; o; o >>= 1) best = ullmax(best, __shfl_down(best, o));
    if (lane == 0) wk[w] = best;
    __syncthreads();
    best = ullmax(ullmax(wk[0], wk[1]), ullmax(wk[2], wk[3]));
    if (t == 0) {
      tv[iter] = key2f((unsigned int)(best >> 32));
      ti[iter] = (int)~(unsigned int)best;
    }
    for (int i = t; i < n; i += 256) if (buf[i] == best) buf[i] = 0ull;
    __syncthreads();
  }
  // retrieve
  int d = t;
  float acc = 0.0f, wsum = 0.0f;
  for (int i = 0; i < k; ++i) {
    int idx = ti[i];
    float wgt = fmaxf(conf[idx], 1e-4f) * tv[i];
    wsum += wgt;
    acc += wgt * vals[(size_t)idx * D_ + d];
  }
  float retr = acc / (wsum + 1e-8f);
  // gate + fuse + classifier
  pl[d] = pooled[b * D_ + d];
  __syncthreads();
  float a = gb1[d];
  for (int e = 0; e < D_; ++e) a += pl[e] * gw1[e * D_ + d];
  hh[d] = fmaxf(a, 0.0f);
  float gsum = blockReduceSum256(hh[d] * gw2[d], sh);
  float g = 1.0f / (1.0f + expf(-(gsum + gb2[0])));
  fu[d] = g * retr + (1.0f - g) * pl[d];
  __syncthreads();
  if (d < 16) {
    float o = cb[d];
    for (int e = 0; e < D_; ++e) o += fu[e] * cw[e * 16 + d];
    out[b * 16 + d] = o;
  }
}

// ---------------- launcher ----------------
extern "C" void kernel_launch(void* const* d_in, const int* in_sizes, int n_in,
                              void* d_out, int out_size, void* d_ws, size_t ws_size,
                              hipStream_t stream) {
  const int*   ids   = (const int*)d_in[0];
  const float* mask  = (const float*)d_in[1];
  const int*   topk  = (const int*)d_in[2];
  const float* emb   = (const float*)d_in[3];
  const float* qkv_w = (const float*)d_in[4];
  const float* qkv_b = (const float*)d_in[5];
  const float* out_w = (const float*)d_in[6];
  const float* out_b = (const float*)d_in[7];
  const float* ln1_s = (const float*)d_in[8];
  const float* ln1_b = (const float*)d_in[9];
  const float* ff_w1 = (const float*)d_in[10];
  const float* ff_b1 = (const float*)d_in[11];
  const float* ff_w2 = (const float*)d_in[12];
  const float* ff_b2 = (const float*)d_in[13];
  const float* ln2_s = (const float*)d_in[14];
  const float* ln2_b = (const float*)d_in[15];
  const float* lnf_s = (const float*)d_in[16];
  const float* lnf_b = (const float*)d_in[17];
  const float* gw1   = (const float*)d_in[18];
  const float* gb1   = (const float*)d_in[19];
  const float* gw2   = (const float*)d_in[20];
  const float* gb2   = (const float*)d_in[21];
  const float* cw    = (const float*)d_in[22];
  const float* cb    = (const float*)d_in[23];
  const float* mkeys = (const float*)d_in[24];
  const float* mvals = (const float*)d_in[25];
  const float* mconf = (const float*)d_in[26];
  float* out = (float*)d_out;

  // ---- workspace layout ----
  float* ws   = (float*)d_ws;
  float* X    = ws;                                   //  4,194,304 f
  float* Y    = X + 4194304;                          //  4,194,304 f
  float* R    = Y + 4194304;                          // 16,777,216 f
  ushort_t* XH   = (ushort_t*)(R + 16777216);
  ushort_t* XL   = XH + 4194304;
  ushort_t* CTXH = XL + 4194304;
  ushort_t* CTXL = CTXH + 4194304;
  ushort_t* WP   = CTXL + 4194304;                    //  3,145,728 sh
  float* POOL = (float*)(WP + 3145728);               //  16384 f
  float* QN   = POOL + 16384;                         //  16384 f
  u64_t* CANDK = (u64_t*)(QN + 16384);                //  64*2048 u64
  u64_t* CHM   = CANDK + (size_t)B_ * CAP_;           //  64*782 u64
  u64_t* TAU   = CHM + (size_t)B_ * NCHB_;            //  64 u64
  unsigned int* CNT = (unsigned int*)(TAU + B_);      //  64 u32

  // aliases over R (lifetimes disjoint)
  float*    QKVOUT = R;                  // [16384][768] f32
  ushort_t* BIGH   = (ushort_t*)R;       // [16384][1024] bf16 hi
  ushort_t* BIGL   = BIGH + 16777216;    // [16384][1024] bf16 lo
  float*    SIMS   = R;                  // [64][200000] f32

  const size_t LW = 1572864;
  #define WPTR(l, off) (WP + (size_t)(l) * LW + (off))

  transcvt_all<<<1536, 256, 0, stream>>>(qkv_w, out_w, ff_w1, ff_w2, WP);
  embed_kernel<<<ROWS_, 256, 0, stream>>>(ids, emb, X, XH, XL);

  for (int l = 0; l < 2; ++l) {
    gemm16<0, true, 0><<<dim3(6, 128), 256, 0, stream>>>(
        XH, XL, WPTR(l, 0), WPTR(l, 196608), qkv_b + l * 768,
        QKVOUT, nullptr, nullptr, ROWS_, 768, 256);
    attn_kernel<<<B_ * H_, 256, 0, stream>>>(QKVOUT, CTXH, CTXL);
    gemm16<0, true, 0><<<dim3(2, 128), 256, 0, stream>>>(
        CTXH, CTXL, WPTR(l, 393216), WPTR(l, 458752), out_b + l * 256,
        Y, nullptr, nullptr, ROWS_, 256, 256);
    addln_kernel<true><<<ROWS_, 256, 0, stream>>>(X, Y, ln1_s + l * 256, ln1_b + l * 256,
                                                  X, XH, XL);
    gemm16<1, true, 1><<<dim3(8, 128), 256, 0, stream>>>(
        XH, XL, WPTR(l, 524288), WPTR(l, 786432), ff_b1 + l * 1024,
        nullptr, BIGH, BIGL, ROWS_, 1024, 256);
    gemm16<0, true, 0><<<dim3(2, 128), 256, 0, stream>>>(
        BIGH, BIGL, WPTR(l, 1048576), WPTR(l, 1310720), ff_b2 + l * 256,
        Y, nullptr, nullptr, ROWS_, 256, 1024);
    addln_kernel<true><<<ROWS_, 256, 0, stream>>>(X, Y, ln2_s + l * 256, ln2_b + l * 256,
                                                  X, XH, XL);
  }

  addln_kernel<false><<<ROWS_, 256, 0, stream>>>(X, nullptr, lnf_s, lnf_b, Y, nullptr, nullptr);
  pooledqnorm_kernel<<<B_, 256, 0, stream>>>(Y, mask, POOL, QN);
  sims_gemm<<<NCHB_, 256, 0, stream>>>(QN, mkeys, SIMS, CHM);
  tau_kernel<<<B_, 256, 0, stream>>>(CHM, topk, TAU, CNT);
  collect_kernel<<<B_ * NCHA_, 256, 0, stream>>>(SIMS, TAU, CANDK, CNT);
  tail_kernel<<<B_, 256, 0, stream>>>(CANDK, CNT, topk, mvals, mconf, POOL,
                                      gw1, gb1, gw2, gb2, cw, cb, out);
  #undef WPTR
}

// Round 8
// 718.392 us; speedup vs baseline: 11.2821x; 1.0033x over previous
//
#include <hip/hip_runtime.h>
#include <math.h>

// ---------------- constants ----------------
#define B_   64
#define S_   256
#define D_   256
#define H_   8
#define DH_  32
#define FF_  1024
#define MEM_ 200000
#define ROWS_ (B_ * S_)   // 16384
#define NCHB_ 1563        // sims blocks per row = chunk-max slots (ceil(MEM/128))
#define NCHA_ 128         // collect chunking
#define CHA_  1563        // ceil(MEM_/NCHA_)
#define CAP_  2048        // candidate cap per row

typedef float f32x4 __attribute__((ext_vector_type(4)));
typedef __bf16 bf16x8 __attribute__((ext_vector_type(8)));
typedef unsigned short ushort_t;
typedef unsigned long long u64_t;

// ---------------- helpers ----------------
__device__ __forceinline__ float blockReduceSum256(float v, float* sh) {
  #pragma unroll
  for (int o = 32; o; o >>= 1) v += __shfl_down(v, o);
  int lane = threadIdx.x & 63, w = threadIdx.x >> 6;
  __syncthreads();
  if (lane == 0) sh[w] = v;
  __syncthreads();
  return sh[0] + sh[1] + sh[2] + sh[3];
}

__device__ __forceinline__ unsigned int f2key(float f) {
  unsigned int b = __float_as_uint(f);
  return (b & 0x80000000u) ? ~b : (b | 0x80000000u);
}
__device__ __forceinline__ float key2f(unsigned int u) {
  unsigned int b = (u & 0x80000000u) ? (u & 0x7FFFFFFFu) : ~u;
  return __uint_as_float(b);
}
__device__ __forceinline__ u64_t ullmax(u64_t a, u64_t b) { return a > b ? a : b; }

__device__ __forceinline__ ushort_t f32_bf16_rn(float x) {
  unsigned int u = __float_as_uint(x);
  u += 0x7FFFu + ((u >> 16) & 1u);
  return (ushort_t)(u >> 16);
}
__device__ __forceinline__ float bf16_f32(ushort_t h) {
  return __uint_as_float((unsigned int)h << 16);
}
__device__ __forceinline__ void split_bf16(float v, ushort_t& h, ushort_t& l) {
  h = f32_bf16_rn(v);
  l = f32_bf16_rn(v - bf16_f32(h));
}

// swizzled byte offsets into a [R][32] bf16 LDS tile
__device__ __forceinline__ int swz8(int row, int kq) {
  return row * 64 + ((((kq >> 1) ^ ((row >> 1) & 3)) << 4)) + (kq & 1) * 8;
}
__device__ __forceinline__ int swz16(int row, int kg) {
  return row * 64 + (((kg ^ ((row >> 1) & 3)) << 4));
}

// direct global->LDS 16B copy
__device__ __forceinline__ void gload_lds16(const void* gsrc, void* ldst) {
  __builtin_amdgcn_global_load_lds(
      (const __attribute__((address_space(1))) unsigned int*)gsrc,
      (__attribute__((address_space(3))) unsigned int*)(unsigned int)(unsigned long long)ldst,
      16, 0, 0);
}

// stage a [NIT*64 x 32] bf16 tile from linear global into swizzled LDS (pre-swizzled source)
template<int NIT>
__device__ __forceinline__ void stage16(const ushort_t* __restrict__ G, int ldg,
                                        int base_row, int k0, char* lds, int t) {
  #pragma unroll
  for (int r = 0; r < NIT; ++r) {
    int idx = r * 256 + t;
    int row = idx >> 2, kg = idx & 3;
    int kg_g = kg ^ ((row >> 1) & 3);
    const void* src = G + (size_t)(base_row + row) * ldg + k0 + kg_g * 8;
    void* dst = lds + (size_t)(idx & ~63) * 16;
    gload_lds16(src, dst);
  }
}

// ---------------- bf16x3 MFMA GEMM on pre-split hi/lo inputs ----------------
template<int ACT, bool HAS_BIAS, int OUTMODE>
__global__ __launch_bounds__(256) void gemm16(const ushort_t* __restrict__ AH,
                                              const ushort_t* __restrict__ AL,
                                              const ushort_t* __restrict__ BH,
                                              const ushort_t* __restrict__ BL,
                                              const float* __restrict__ bias,
                                              float* __restrict__ C,
                                              ushort_t* __restrict__ CH,
                                              ushort_t* __restrict__ CL,
                                              int M, int N, int K) {
  __shared__ __align__(16) char sAh[128 * 64];
  __shared__ __align__(16) char sAl[128 * 64];
  __shared__ __align__(16) char sBh[128 * 64];
  __shared__ __align__(16) char sBl[128 * 64];
  int t = threadIdx.x;
  int m0 = blockIdx.y * 128, n0 = blockIdx.x * 128;
  int wid = t >> 6, lane = t & 63;
  int wr = wid >> 1, wc = wid & 1;
  int lr = lane & 15, kg = lane >> 4;
  f32x4 acc[4][4] = {};
  for (int k0 = 0; k0 < K; k0 += 32) {
    stage16<2>(AH, K, m0, k0, sAh, t);
    stage16<2>(AL, K, m0, k0, sAl, t);
    stage16<2>(BH, K, n0, k0, sBh, t);
    stage16<2>(BL, K, n0, k0, sBl, t);
    __syncthreads();
    bf16x8 ah[4], al[4];
    #pragma unroll
    for (int mi = 0; mi < 4; ++mi) {
      int row = wr * 64 + mi * 16 + lr;
      int ab = swz16(row, kg);
      ah[mi] = *reinterpret_cast<const bf16x8*>(sAh + ab);
      al[mi] = *reinterpret_cast<const bf16x8*>(sAl + ab);
    }
    #pragma unroll
    for (int ni = 0; ni < 4; ++ni) {
      int rb = wc * 64 + ni * 16 + lr;
      int bb = swz16(rb, kg);
      bf16x8 bh = *reinterpret_cast<const bf16x8*>(sBh + bb);
      bf16x8 bl = *reinterpret_cast<const bf16x8*>(sBl + bb);
      #pragma unroll
      for (int mi = 0; mi < 4; ++mi) {
        acc[mi][ni] = __builtin_amdgcn_mfma_f32_16x16x32_bf16(ah[mi], bh, acc[mi][ni], 0, 0, 0);
        acc[mi][ni] = __builtin_amdgcn_mfma_f32_16x16x32_bf16(al[mi], bh, acc[mi][ni], 0, 0, 0);
        acc[mi][ni] = __builtin_amdgcn_mfma_f32_16x16x32_bf16(ah[mi], bl, acc[mi][ni], 0, 0, 0);
      }
    }
    __syncthreads();
  }
  #pragma unroll
  for (int mi = 0; mi < 4; ++mi) {
    #pragma unroll
    for (int ni = 0; ni < 4; ++ni) {
      int row0 = m0 + wr * 64 + mi * 16 + kg * 4;
      int col  = n0 + wc * 64 + ni * 16 + lr;
      float b = HAS_BIAS ? bias[col] : 0.0f;
      #pragma unroll
      for (int i = 0; i < 4; ++i) {
        float v = acc[mi][ni][i] + b;
        if (ACT == 1) v = 0.5f * v * (1.0f + erff(v * 0.7071067811865476f));
        size_t o = (size_t)(row0 + i) * N + col;
        if (OUTMODE == 0) {
          C[o] = v;
        } else {
          ushort_t h, l;
          split_bf16(v, h, l);
          CH[o] = h; CL[o] = l;
        }
      }
    }
  }
}

// ---------------- sims GEMM v2: [64,MEM] = QN @ keys^T, fused invnorm + chunk-max ----------------
// 128 cols/block, 1563 blocks, 4 waves (each 64q x 32 cols, acc[4][2]).
// QN pre-split to bf16 pairs -> A staged via global_load_lds (no VALU).
// Per-key sumsq in REGISTERS ps[4] (statically indexed; (row,kq) slot fixed per thread
// across K-steps), dumped to LDS once at the end with a linear conflict-free pattern.
__global__ __launch_bounds__(256) void sims_gemm(const ushort_t* __restrict__ QNH,
                                                 const ushort_t* __restrict__ QNL,
                                                 const float* __restrict__ keys,
                                                 float* __restrict__ sims,
                                                 u64_t* __restrict__ chm) {
  __shared__ __align__(16) char sAh[64 * 64];
  __shared__ __align__(16) char sAl[64 * 64];
  __shared__ __align__(16) char sBh[128 * 64];
  __shared__ __align__(16) char sBl[128 * 64];
  __shared__ float psum[128][8];   // written ONCE in epilogue (linear, conflict-free)
  __shared__ u64_t wmax[4][64];
  int t = threadIdx.x;
  int n0 = blockIdx.x * 128;
  int w = t >> 6, lane = t & 63;
  int lr = lane & 15, kg = lane >> 4;
  float ps[4] = {0.f, 0.f, 0.f, 0.f};
  f32x4 acc[4][2] = {};
  for (int k0 = 0; k0 < 256; k0 += 32) {
    stage16<1>(QNH, 256, 0, k0, sAh, t);
    stage16<1>(QNL, 256, 0, k0, sAl, t);
    // B staging with register sumsq partials (thread owns slot (row = r*32 + t>>3, kq = t&7))
    #pragma unroll
    for (int r = 0; r < 4; ++r) {
      int idx = r * 256 + t;
      int row = idx >> 3, kq = idx & 7;
      int gr = n0 + row; if (gr > MEM_ - 1) gr = MEM_ - 1;
      const float4 v = *reinterpret_cast<const float4*>(keys + (size_t)gr * 256 + k0 + kq * 4);
      ps[r] += v.x * v.x + v.y * v.y + v.z * v.z + v.w * v.w;
      float vv[4] = {v.x, v.y, v.z, v.w};
      ushort_t h[4], l[4];
      #pragma unroll
      for (int j = 0; j < 4; ++j) split_bf16(vv[j], h[j], l[j]);
      int b8 = swz8(row, kq);
      *reinterpret_cast<uint2*>(sBh + b8) =
          make_uint2((unsigned)h[0] | ((unsigned)h[1] << 16),
                     (unsigned)h[2] | ((unsigned)h[3] << 16));
      *reinterpret_cast<uint2*>(sBl + b8) =
          make_uint2((unsigned)l[0] | ((unsigned)l[1] << 16),
                     (unsigned)l[2] | ((unsigned)l[3] << 16));
    }
    __syncthreads();
    bf16x8 ah[4], al[4];
    #pragma unroll
    for (int mi = 0; mi < 4; ++mi) {
      int ab = swz16(mi * 16 + lr, kg);
      ah[mi] = *reinterpret_cast<const bf16x8*>(sAh + ab);
      al[mi] = *reinterpret_cast<const bf16x8*>(sAl + ab);
    }
    #pragma unroll
    for (int ni = 0; ni < 2; ++ni) {
      int bb = swz16(w * 32 + ni * 16 + lr, kg);
      bf16x8 bh = *reinterpret_cast<const bf16x8*>(sBh + bb);
      bf16x8 bl = *reinterpret_cast<const bf16x8*>(sBl + bb);
      #pragma unroll
      for (int mi = 0; mi < 4; ++mi) {
        acc[mi][ni] = __builtin_amdgcn_mfma_f32_16x16x32_bf16(ah[mi], bh, acc[mi][ni], 0, 0, 0);
        acc[mi][ni] = __builtin_amdgcn_mfma_f32_16x16x32_bf16(al[mi], bh, acc[mi][ni], 0, 0, 0);
        acc[mi][ni] = __builtin_amdgcn_mfma_f32_16x16x32_bf16(ah[mi], bl, acc[mi][ni], 0, 0, 0);
      }
    }
    __syncthreads();
  }
  // dump register psum -> LDS (offset = idx, perfectly linear across threads)
  #pragma unroll
  for (int r = 0; r < 4; ++r) {
    int idx = r * 256 + t;
    psum[idx >> 3][idx & 7] = ps[r];
  }
  __syncthreads();
  float invn[2];
  #pragma unroll
  for (int ni = 0; ni < 2; ++ni) {
    int crow = w * 32 + ni * 16 + lr;
    float ss = 0.f;
    #pragma unroll
    for (int kq = 0; kq < 8; ++kq) ss += psum[crow][kq];
    invn[ni] = 1.0f / fmaxf(sqrtf(ss), 1e-8f);
  }
  u64_t bq[4][4];
  #pragma unroll
  for (int mi = 0; mi < 4; ++mi)
    #pragma unroll
    for (int i = 0; i < 4; ++i) bq[mi][i] = 0ull;
  #pragma unroll
  for (int ni = 0; ni < 2; ++ni) {
    int col = n0 + w * 32 + ni * 16 + lr;
    if (col < MEM_) {
      #pragma unroll
      for (int mi = 0; mi < 4; ++mi) {
        int q = mi * 16 + kg * 4;
        #pragma unroll
        for (int i = 0; i < 4; ++i) {
          float v = acc[mi][ni][i] * invn[ni];
          sims[(size_t)(q + i) * MEM_ + col] = v;
          u64_t key = ((u64_t)f2key(v) << 32) | (unsigned int)~(unsigned int)col;
          bq[mi][i] = ullmax(bq[mi][i], key);
        }
      }
    }
  }
  #pragma unroll
  for (int mi = 0; mi < 4; ++mi)
    #pragma unroll
    for (int i = 0; i < 4; ++i) {
      u64_t m = bq[mi][i];
      m = ullmax(m, __shfl_xor(m, 1));
      m = ullmax(m, __shfl_xor(m, 2));
      m = ullmax(m, __shfl_xor(m, 4));
      m = ullmax(m, __shfl_xor(m, 8));
      if (lr == 0) wmax[w][mi * 16 + kg * 4 + i] = m;
    }
  __syncthreads();
  if (t < 64) {
    u64_t m = ullmax(ullmax(wmax[0][t], wmax[1][t]), ullmax(wmax[2][t], wmax[3][t]));
    chm[(size_t)t * NCHB_ + blockIdx.x] = m;
  }
}

// ---------------- all weight transposes + bf16 hi/lo split in ONE launch ----------------
__global__ __launch_bounds__(256) void transcvt_all(const float* __restrict__ qkv_w,
                                                    const float* __restrict__ out_w,
                                                    const float* __restrict__ ff_w1,
                                                    const float* __restrict__ ff_w2,
                                                    ushort_t* __restrict__ WP) {
  __shared__ float tile[32][33];
  int idx = blockIdx.x;
  int l = idx / 768, r = idx % 768;
  const float* src; ushort_t *dh, *dl; int R, C, bx, by;
  ushort_t* base = WP + (size_t)l * 1572864;
  if (r < 192)      { src = qkv_w + (size_t)l * 196608; dh = base;           dl = base + 196608;  R = 256;  C = 768;  bx = r % 24;        by = r / 24; }
  else if (r < 256) { src = out_w + (size_t)l * 65536;  dh = base + 393216;  dl = base + 458752;  R = 256;  C = 256;  bx = (r - 192) % 8; by = (r - 192) / 8; }
  else if (r < 512) { src = ff_w1 + (size_t)l * 262144; dh = base + 524288;  dl = base + 786432;  R = 256;  C = 1024; bx = (r - 256) % 32; by = (r - 256) / 32; }
  else              { src = ff_w2 + (size_t)l * 262144; dh = base + 1048576; dl = base + 1310720; R = 1024; C = 256;  bx = (r - 512) % 8; by = (r - 512) / 8; }
  int c0 = bx * 32, r0 = by * 32;
  int x = threadIdx.x & 31, y4 = (threadIdx.x >> 5) * 4;
  #pragma unroll
  for (int i = 0; i < 4; ++i) tile[y4 + i][x] = src[(size_t)(r0 + y4 + i) * C + c0 + x];
  __syncthreads();
  #pragma unroll
  for (int i = 0; i < 4; ++i) {
    float v = tile[x][y4 + i];
    ushort_t h, l2;
    split_bf16(v, h, l2);
    size_t o = (size_t)(c0 + y4 + i) * R + r0 + x;
    dh[o] = h; dl[o] = l2;
  }
}

// ---------------- embedding + positional encoding ----------------
__global__ __launch_bounds__(256) void embed_kernel(const int* __restrict__ ids,
                                                    const float* __restrict__ emb,
                                                    float* __restrict__ x,
                                                    ushort_t* __restrict__ xh,
                                                    ushort_t* __restrict__ xl) {
  int row = blockIdx.x;
  int d = threadIdx.x;
  int s = row & (S_ - 1);
  int tok = ids[row];
  int d2 = d & ~1;
  float div = expf((float)d2 * (-9.210340371976184f / 256.0f));
  float ang = (float)s * div;
  float pe = (d & 1) ? cosf(ang) : sinf(ang);
  float v = emb[(size_t)tok * D_ + d] * 16.0f + pe;
  size_t o = (size_t)row * D_ + d;
  x[o] = v;
  ushort_t h, l;
  split_bf16(v, h, l);
  xh[o] = h; xl[o] = l;
}

// ---------------- MFMA flash attention (bf16x3, swapped-operand structure) ----------------
__global__ __launch_bounds__(256) void attn_kernel(const float* __restrict__ qkv,
                                                   ushort_t* __restrict__ ctxh,
                                                   ushort_t* __restrict__ ctxl) {
  __shared__ __align__(16) ushort_t sKh[32][40];
  __shared__ __align__(16) ushort_t sKl[32][40];
  __shared__ __align__(16) ushort_t sVh[32][40];
  __shared__ __align__(16) ushort_t sVl[32][40];
  __shared__ __align__(16) ushort_t sPh[4][64][40];
  __shared__ __align__(16) ushort_t sPl[4][64][40];

  const int bh = blockIdx.x;
  const int b = bh >> 3, h = bh & 7;
  const int t = threadIdx.x;
  const int w = t >> 6, lane = t & 63;
  const int lr = lane & 15, g = lane >> 4;

  const float* __restrict__ base = qkv + (size_t)(b * S_) * 768 + h * 32;

  bf16x8 qh[4], ql[4];
  #pragma unroll
  for (int ni = 0; ni < 4; ++ni) {
    const float* qp = base + (size_t)(w * 64 + ni * 16 + lr) * 768 + g * 8;
    union { bf16x8 v; ushort_t u[8]; } Hh, Ll;
    #pragma unroll
    for (int j = 0; j < 8; ++j) {
      float qv = qp[j] * 0.17677669529663687f;
      split_bf16(qv, Hh.u[j], Ll.u[j]);
    }
    qh[ni] = Hh.v; ql[ni] = Ll.v;
  }

  f32x4 oacc[2][4] = {};
  float mrow[4] = {-3.0e38f, -3.0e38f, -3.0e38f, -3.0e38f};
  float lsum[4] = {0.f, 0.f, 0.f, 0.f};

  for (int kt = 0; kt < 8; ++kt) {
    __syncthreads();
    {
      int key = t >> 3, c4 = t & 7;
      const float4 kv = *reinterpret_cast<const float4*>(
          base + (size_t)(kt * 32 + key) * 768 + 256 + c4 * 4);
      float kvv[4] = {kv.x, kv.y, kv.z, kv.w};
      ushort_t hk[4], lk[4];
      #pragma unroll
      for (int j = 0; j < 4; ++j) split_bf16(kvv[j], hk[j], lk[j]);
      *reinterpret_cast<uint2*>(&sKh[key][c4 * 4]) =
          make_uint2((unsigned)hk[0] | ((unsigned)hk[1] << 16),
                     (unsigned)hk[2] | ((unsigned)hk[3] << 16));
      *reinterpret_cast<uint2*>(&sKl[key][c4 * 4]) =
          make_uint2((unsigned)lk[0] | ((unsigned)lk[1] << 16),
                     (unsigned)lk[2] | ((unsigned)lk[3] << 16));
      int dh = t & 31, kq = t >> 5;
      ushort_t hv[4], lv[4];
      #pragma unroll
      for (int kk = 0; kk < 4; ++kk) {
        float vv = base[(size_t)(kt * 32 + kq * 4 + kk) * 768 + 512 + dh];
        split_bf16(vv, hv[kk], lv[kk]);
      }
      *reinterpret_cast<uint2*>(&sVh[dh][kq * 4]) =
          make_uint2((unsigned)hv[0] | ((unsigned)hv[1] << 16),
                     (unsigned)hv[2] | ((unsigned)hv[3] << 16));
      *reinterpret_cast<uint2*>(&sVl[dh][kq * 4]) =
          make_uint2((unsigned)lv[0] | ((unsigned)lv[1] << 16),
                     (unsigned)lv[2] | ((unsigned)lv[3] << 16));
    }
    __syncthreads();

    f32x4 sacc[2][4] = {};
    bf16x8 kfh[2], kfl[2];
    #pragma unroll
    for (int x = 0; x < 2; ++x) {
      kfh[x] = *reinterpret_cast<const bf16x8*>(&sKh[x * 16 + lr][g * 8]);
      kfl[x] = *reinterpret_cast<const bf16x8*>(&sKl[x * 16 + lr][g * 8]);
    }
    #pragma unroll
    for (int x = 0; x < 2; ++x) {
      #pragma unroll
      for (int ni = 0; ni < 4; ++ni) {
        sacc[x][ni] = __builtin_amdgcn_mfma_f32_16x16x32_bf16(kfh[x], qh[ni], sacc[x][ni], 0, 0, 0);
        sacc[x][ni] = __builtin_amdgcn_mfma_f32_16x16x32_bf16(kfl[x], qh[ni], sacc[x][ni], 0, 0, 0);
        sacc[x][ni] = __builtin_amdgcn_mfma_f32_16x16x32_bf16(kfh[x], ql[ni], sacc[x][ni], 0, 0, 0);
      }
    }

    #pragma unroll
    for (int ni = 0; ni < 4; ++ni) {
      float tm = sacc[0][ni][0];
      tm = fmaxf(tm, sacc[0][ni][1]); tm = fmaxf(tm, sacc[0][ni][2]); tm = fmaxf(tm, sacc[0][ni][3]);
      tm = fmaxf(tm, sacc[1][ni][0]); tm = fmaxf(tm, sacc[1][ni][1]);
      tm = fmaxf(tm, sacc[1][ni][2]); tm = fmaxf(tm, sacc[1][ni][3]);
      tm = fmaxf(tm, __shfl_xor(tm, 16));
      tm = fmaxf(tm, __shfl_xor(tm, 32));
      float mn = fmaxf(mrow[ni], tm);
      float sc = __expf(mrow[ni] - mn);
      mrow[ni] = mn;
      float ps = 0.f;
      #pragma unroll
      for (int x = 0; x < 2; ++x) {
        ushort_t ph[4], pl[4];
        #pragma unroll
        for (int i = 0; i < 4; ++i) {
          float p = __expf(sacc[x][ni][i] - mn);
          ps += p;
          split_bf16(p, ph[i], pl[i]);
        }
        *reinterpret_cast<uint2*>(&sPh[w][ni * 16 + lr][x * 16 + g * 4]) =
            make_uint2((unsigned)ph[0] | ((unsigned)ph[1] << 16),
                       (unsigned)ph[2] | ((unsigned)ph[3] << 16));
        *reinterpret_cast<uint2*>(&sPl[w][ni * 16 + lr][x * 16 + g * 4]) =
            make_uint2((unsigned)pl[0] | ((unsigned)pl[1] << 16),
                       (unsigned)pl[2] | ((unsigned)pl[3] << 16));
      }
      ps += __shfl_xor(ps, 16);
      ps += __shfl_xor(ps, 32);
      lsum[ni] = lsum[ni] * sc + ps;
      #pragma unroll
      for (int mt = 0; mt < 2; ++mt)
        #pragma unroll
        for (int i = 0; i < 4; ++i) oacc[mt][ni][i] *= sc;
    }

    bf16x8 pbh[4], pbl[4];
    #pragma unroll
    for (int ni = 0; ni < 4; ++ni) {
      pbh[ni] = *reinterpret_cast<const bf16x8*>(&sPh[w][ni * 16 + lr][g * 8]);
      pbl[ni] = *reinterpret_cast<const bf16x8*>(&sPl[w][ni * 16 + lr][g * 8]);
    }
    #pragma unroll
    for (int mt = 0; mt < 2; ++mt) {
      bf16x8 vfh = *reinterpret_cast<const bf16x8*>(&sVh[mt * 16 + lr][g * 8]);
      bf16x8 vfl = *reinterpret_cast<const bf16x8*>(&sVl[mt * 16 + lr][g * 8]);
      #pragma unroll
      for (int ni = 0; ni < 4; ++ni) {
        oacc[mt][ni] = __builtin_amdgcn_mfma_f32_16x16x32_bf16(vfh, pbh[ni], oacc[mt][ni], 0, 0, 0);
        oacc[mt][ni] = __builtin_amdgcn_mfma_f32_16x16x32_bf16(vfl, pbh[ni], oacc[mt][ni], 0, 0, 0);
        oacc[mt][ni] = __builtin_amdgcn_mfma_f32_16x16x32_bf16(vfh, pbl[ni], oacc[mt][ni], 0, 0, 0);
      }
    }
  }

  #pragma unroll
  for (int ni = 0; ni < 4; ++ni) {
    float inv = 1.0f / lsum[ni];
    int q = w * 64 + ni * 16 + lr;
    size_t rowo = (size_t)(b * S_ + q) * D_ + h * 32;
    #pragma unroll
    for (int mt = 0; mt < 2; ++mt) {
      ushort_t hh[4], ll[4];
      #pragma unroll
      for (int i = 0; i < 4; ++i) {
        float v = oacc[mt][ni][i] * inv;
        split_bf16(v, hh[i], ll[i]);
      }
      int col = mt * 16 + g * 4;
      *reinterpret_cast<uint2*>(&ctxh[rowo + col]) =
          make_uint2((unsigned)hh[0] | ((unsigned)hh[1] << 16),
                     (unsigned)hh[2] | ((unsigned)hh[3] << 16));
      *reinterpret_cast<uint2*>(&ctxl[rowo + col]) =
          make_uint2((unsigned)ll[0] | ((unsigned)ll[1] << 16),
                     (unsigned)ll[2] | ((unsigned)ll[3] << 16));
    }
  }
}

// ---------------- residual add + layernorm ----------------
template<bool PAIRS>
__global__ __launch_bounds__(256) void addln_kernel(const float* __restrict__ x,
                                                    const float* __restrict__ y,
                                                    const float* __restrict__ gam,
                                                    const float* __restrict__ bet,
                                                    float* __restrict__ out,
                                                    ushort_t* __restrict__ oh,
                                                    ushort_t* __restrict__ ol) {
  __shared__ float sh[8];
  int row = blockIdx.x, d = threadIdx.x;
  float v = x[(size_t)row * D_ + d];
  if (y) v += y[(size_t)row * D_ + d];
  float mean = blockReduceSum256(v, sh) * (1.0f / D_);
  float diff = v - mean;
  float var = blockReduceSum256(diff * diff, sh) * (1.0f / D_);
  float r = diff * rsqrtf(var + 1e-5f) * gam[d] + bet[d];
  size_t o = (size_t)row * D_ + d;
  out[o] = r;
  if (PAIRS) {
    ushort_t h, l;
    split_bf16(r, h, l);
    oh[o] = h; ol[o] = l;
  }
}

// ---------------- masked mean pool + query normalize (fused; bf16-pair qn out) ----------------
__global__ __launch_bounds__(256) void pooledqnorm_kernel(const float* __restrict__ hidden,
                                                          const float* __restrict__ mask,
                                                          float* __restrict__ pooled,
                                                          ushort_t* __restrict__ qnh,
                                                          ushort_t* __restrict__ qnl) {
  __shared__ float sh[8];
  int b = blockIdx.x, d = threadIdx.x;
  float s = 0.0f, msum = 0.0f;
  for (int t = 0; t < S_; ++t) {
    float mk = mask[b * S_ + t];
    s += hidden[(size_t)(b * S_ + t) * D_ + d] * mk;
    msum += mk;
  }
  float pv = s / (msum + 1e-8f);
  pooled[b * D_ + d] = pv;
  float ss = blockReduceSum256(pv * pv, sh);
  float qv = pv / fmaxf(sqrtf(ss), 1e-8f);
  ushort_t h, l;
  split_bf16(qv, h, l);
  qnh[b * D_ + d] = h;
  qnl[b * D_ + d] = l;
}

// ---------------- tau: k-th largest of 1563 chunk maxima per row ----------------
__global__ __launch_bounds__(256) void tau_kernel(const u64_t* __restrict__ chm,
                                                  const int* __restrict__ topk,
                                                  u64_t* __restrict__ tau,
                                                  unsigned int* __restrict__ cnt) {
  __shared__ u64_t keys[NCHB_];
  int row = blockIdx.x, t = threadIdx.x;
  int k = *topk; if (k > 64) k = 64; if (k < 1) k = 1;
  for (int i = t; i < NCHB_; i += 256) keys[i] = chm[(size_t)row * NCHB_ + i];
  __syncthreads();
  u64_t mine[7]; int rank[7] = {0, 0, 0, 0, 0, 0, 0};
  #pragma unroll
  for (int o = 0; o < 7; ++o) {
    int i = o * 256 + t;
    mine[o] = (i < NCHB_) ? keys[i] : 0ull;
  }
  for (int j = 0; j < NCHB_; ++j) {
    u64_t kj = keys[j];
    #pragma unroll
    for (int o = 0; o < 7; ++o) rank[o] += (kj > mine[o]) ? 1 : 0;
  }
  #pragma unroll
  for (int o = 0; o < 7; ++o) {
    int i = o * 256 + t;
    if (i < NCHB_ && rank[o] == k - 1) tau[row] = mine[o];
  }
  if (t == 0) cnt[row] = 0u;
}

// ---------------- collect: gather all keys >= tau ----------------
__global__ __launch_bounds__(256) void collect_kernel(const float* __restrict__ sims,
                                                      const u64_t* __restrict__ tau,
                                                      u64_t* __restrict__ cand,
                                                      unsigned int* __restrict__ cnt) {
  int row = blockIdx.x >> 7, c = blockIdx.x & 127;
  int t = threadIdx.x;
  u64_t tv = tau[row];
  int base = c * CHA_;
  int end = base + CHA_; if (end > MEM_) end = MEM_;
  const float* src = sims + (size_t)row * MEM_;
  for (int i = base + t; i < end; i += 256) {
    u64_t key = ((u64_t)f2key(src[i]) << 32) | (unsigned int)~(unsigned int)i;
    if (key >= tv) {
      unsigned int pos = atomicAdd(&cnt[row], 1u);
      if (pos < CAP_) cand[(size_t)row * CAP_ + pos] = key;
    }
  }
}

// ---------------- tail: final top-k + retrieve + gate/classifier (fused) ----------------
__global__ __launch_bounds__(256) void tail_kernel(const u64_t* __restrict__ cand,
                                                   const unsigned int* __restrict__ cnt,
                                                   const int* __restrict__ topk,
                                                   const float* __restrict__ vals,
                                                   const float* __restrict__ conf,
                                                   const float* __restrict__ pooled,
                                                   const float* __restrict__ gw1,
                                                   const float* __restrict__ gb1,
                                                   const float* __restrict__ gw2,
                                                   const float* __restrict__ gb2,
                                                   const float* __restrict__ cw,
                                                   const float* __restrict__ cb,
                                                   float* __restrict__ out) {
  __shared__ u64_t buf[CAP_];
  __shared__ u64_t wk[4];
  __shared__ float tv[64];
  __shared__ int ti[64];
  __shared__ float pl[D_], hh[D_], fu[D_], sh[8];
  int b = blockIdx.x, t = threadIdx.x;
  int k = *topk; if (k > 64) k = 64; if (k < 1) k = 1;
  int n = (int)cnt[b]; if (n > CAP_) n = CAP_;
  for (int i = t; i < n; i += 256) buf[i] = cand[(size_t)b * CAP_ + i];
  __syncthreads();
  int lane = t & 63, w = t >> 6;
  for (int iter = 0; iter < k; ++iter) {
    u64_t best = 0ull;
    for (int i = t; i < n; i += 256) best = ullmax(best, buf[i]);
    #pragma unroll
    for (int o = 32; o; o >>= 1) best = ullmax(best, __shfl_down(best, o));
    if (lane == 0) wk[w] = best;
    __syncthreads();
    best = ullmax(ullmax(wk[0], wk[1]), ullmax(wk[2], wk[3]));
    if (t == 0) {
      tv[iter] = key2f((unsigned int)(best >> 32));
      ti[iter] = (int)~(unsigned int)best;
    }
    for (int i = t; i < n; i += 256) if (buf[i] == best) buf[i] = 0ull;
    __syncthreads();
  }
  int d = t;
  float acc = 0.0f, wsum = 0.0f;
  for (int i = 0; i < k; ++i) {
    int idx = ti[i];
    float wgt = fmaxf(conf[idx], 1e-4f) * tv[i];
    wsum += wgt;
    acc += wgt * vals[(size_t)idx * D_ + d];
  }
  float retr = acc / (wsum + 1e-8f);
  pl[d] = pooled[b * D_ + d];
  __syncthreads();
  float a = gb1[d];
  for (int e = 0; e < D_; ++e) a += pl[e] * gw1[e * D_ + d];
  hh[d] = fmaxf(a, 0.0f);
  float gsum = blockReduceSum256(hh[d] * gw2[d], sh);
  float g = 1.0f / (1.0f + expf(-(gsum + gb2[0])));
  fu[d] = g * retr + (1.0f - g) * pl[d];
  __syncthreads();
  if (d < 16) {
    float o = cb[d];
    for (int e = 0; e < D_; ++e) o += fu[e] * cw[e * 16 + d];
    out[b * 16 + d] = o;
  }
}

// ---------------- launcher ----------------
extern "C" void kernel_launch(void* const* d_in, const int* in_sizes, int n_in,
                              void* d_out, int out_size, void* d_ws, size_t ws_size,
                              hipStream_t stream) {
  const int*   ids   = (const int*)d_in[0];
  const float* mask  = (const float*)d_in[1];
  const int*   topk  = (const int*)d_in[2];
  const float* emb   = (const float*)d_in[3];
  const float* qkv_w = (const float*)d_in[4];
  const float* qkv_b = (const float*)d_in[5];
  const float* out_w = (const float*)d_in[6];
  const float* out_b = (const float*)d_in[7];
  const float* ln1_s = (const float*)d_in[8];
  const float* ln1_b = (const float*)d_in[9];
  const float* ff_w1 = (const float*)d_in[10];
  const float* ff_b1 = (const float*)d_in[11];
  const float* ff_w2 = (const float*)d_in[12];
  const float* ff_b2 = (const float*)d_in[13];
  const float* ln2_s = (const float*)d_in[14];
  const float* ln2_b = (const float*)d_in[15];
  const float* lnf_s = (const float*)d_in[16];
  const float* lnf_b = (const float*)d_in[17];
  const float* gw1   = (const float*)d_in[18];
  const float* gb1   = (const float*)d_in[19];
  const float* gw2   = (const float*)d_in[20];
  const float* gb2   = (const float*)d_in[21];
  const float* cw    = (const float*)d_in[22];
  const float* cb    = (const float*)d_in[23];
  const float* mkeys = (const float*)d_in[24];
  const float* mvals = (const float*)d_in[25];
  const float* mconf = (const float*)d_in[26];
  float* out = (float*)d_out;

  // ---- workspace layout ----
  float* ws   = (float*)d_ws;
  float* X    = ws;                                   //  4,194,304 f
  float* Y    = X + 4194304;                          //  4,194,304 f
  float* R    = Y + 4194304;                          // 16,777,216 f
  ushort_t* XH   = (ushort_t*)(R + 16777216);
  ushort_t* XL   = XH + 4194304;
  ushort_t* CTXH = XL + 4194304;
  ushort_t* CTXL = CTXH + 4194304;
  ushort_t* WP   = CTXL + 4194304;                    //  3,145,728 sh
  float* POOL = (float*)(WP + 3145728);               //  16384 f
  ushort_t* QNH = (ushort_t*)(POOL + 16384);          //  16384 sh
  ushort_t* QNL = QNH + 16384;                        //  16384 sh
  u64_t* CANDK = (u64_t*)(QNL + 16384);               //  64*2048 u64
  u64_t* CHM   = CANDK + (size_t)B_ * CAP_;           //  64*1563 u64
  u64_t* TAU   = CHM + (size_t)B_ * NCHB_;            //  64 u64
  unsigned int* CNT = (unsigned int*)(TAU + B_);      //  64 u32

  // aliases over R (lifetimes disjoint)
  float*    QKVOUT = R;                  // [16384][768] f32
  ushort_t* BIGH   = (ushort_t*)R;       // [16384][1024] bf16 hi
  ushort_t* BIGL   = BIGH + 16777216;    // [16384][1024] bf16 lo
  float*    SIMS   = R;                  // [64][200000] f32

  const size_t LW = 1572864;
  #define WPTR(l, off) (WP + (size_t)(l) * LW + (off))

  transcvt_all<<<1536, 256, 0, stream>>>(qkv_w, out_w, ff_w1, ff_w2, WP);
  embed_kernel<<<ROWS_, 256, 0, stream>>>(ids, emb, X, XH, XL);

  for (int l = 0; l < 2; ++l) {
    gemm16<0, true, 0><<<dim3(6, 128), 256, 0, stream>>>(
        XH, XL, WPTR(l, 0), WPTR(l, 196608), qkv_b + l * 768,
        QKVOUT, nullptr, nullptr, ROWS_, 768, 256);
    attn_kernel<<<B_ * H_, 256, 0, stream>>>(QKVOUT, CTXH, CTXL);
    gemm16<0, true, 0><<<dim3(2, 128), 256, 0, stream>>>(
        CTXH, CTXL, WPTR(l, 393216), WPTR(l, 458752), out_b + l * 256,
        Y, nullptr, nullptr, ROWS_, 256, 256);
    addln_kernel<true><<<ROWS_, 256, 0, stream>>>(X, Y, ln1_s + l * 256, ln1_b + l * 256,
                                                  X, XH, XL);
    gemm16<1, true, 1><<<dim3(8, 128), 256, 0, stream>>>(
        XH, XL, WPTR(l, 524288), WPTR(l, 786432), ff_b1 + l * 1024,
        nullptr, BIGH, BIGL, ROWS_, 1024, 256);
    gemm16<0, true, 0><<<dim3(2, 128), 256, 0, stream>>>(
        BIGH, BIGL, WPTR(l, 1048576), WPTR(l, 1310720), ff_b2 + l * 256,
        Y, nullptr, nullptr, ROWS_, 256, 1024);
    addln_kernel<true><<<ROWS_, 256, 0, stream>>>(X, Y, ln2_s + l * 256, ln2_b + l * 256,
                                                  X, XH, XL);
  }

  addln_kernel<false><<<ROWS_, 256, 0, stream>>>(X, nullptr, lnf_s, lnf_b, Y, nullptr, nullptr);
  pooledqnorm_kernel<<<B_, 256, 0, stream>>>(Y, mask, POOL, QNH, QNL);
  sims_gemm<<<NCHB_, 256, 0, stream>>>(QNH, QNL, mkeys, SIMS, CHM);
  tau_kernel<<<B_, 256, 0, stream>>>(CHM, topk, TAU, CNT);
  collect_kernel<<<B_ * NCHA_, 256, 0, stream>>>(SIMS, TAU, CANDK, CNT);
  tail_kernel<<<B_, 256, 0, stream>>>(CANDK, CNT, topk, mvals, mconf, POOL,
                                      gw1, gb1, gw2, gb2, cw, cb, out);
  #undef WPTR
}